// Round 13
// baseline (436.809 us; speedup 1.0000x reference)
//
#include <hip/hip_runtime.h>
#include <hip/hip_bf16.h>
#include <cstdint>
#include <cstddef>

// ---------------------------------------------------------------------------
// MeshMultiHeadHodgeLaplaceAttention  (b=2, n=2048, m=6144, k=4096, D=256, H=8)
//
//   up:   T1 = d_1 @ eV ; *f_hval ; T2 = d_1^T @ T1s ; (*einv_hval in combine)
//   down: Y0 = eV*e_hval ; T3 = d_0^T @ Y0 ; *1/(v_hval+eps) ; T4 = d_0 @ T3s
//   out = (T2*einv_hval + T4) @ W_o
//
// Precision: v_hval replicates numpy fp32 bit-exactly; P1 + output GEMM
// split-bf16; T1..T4 plain bf16 (validated R10-R12, absmax=256).
//
// R13: prep_all occupancy fix - smem 24576->12288 (vproj 4 rows/block,
// weight transpose two-phase through one 9KB buffer), non-temporal stores
// for the 300 MB of d-matrix bf16 output. Rest identical to R12.
// ---------------------------------------------------------------------------

typedef __attribute__((ext_vector_type(4))) float f32x4;
typedef __attribute__((ext_vector_type(4))) unsigned short u16x4;
typedef __attribute__((ext_vector_type(8))) unsigned short u16x8;
typedef __attribute__((ext_vector_type(8))) __bf16 bf16x8;

static __device__ __forceinline__ unsigned short f2bf(float f) {
  uint32_t u = __builtin_bit_cast(uint32_t, f);
  uint32_t r = (u + 0x7FFFu + ((u >> 16) & 1u)) >> 16;  // RNE
  return (unsigned short)r;
}
static __device__ __forceinline__ float bf2f(unsigned short h) {
  return __builtin_bit_cast(float, (uint32_t)h << 16);
}
template <typename T>
static __device__ __forceinline__ void nts(T* p, T v) {
  __builtin_nontemporal_store(v, p);
}

// ---------------------------------------------------------------------------
// Dual-job plain-bf16 GEMM. Per job: C[M x gy*128] = A(bf16 [M][K]) *
// B(bf16 [N][K]); split-K z = batch*S + split; 128x128 tile, reg-prefetch.
// ---------------------------------------------------------------------------
struct GJob {
  const unsigned short* Ah; const unsigned short* Bh; float* C;
  int K, ldA, ldB, S, gx, gy;
  long long sA, sB, sC;
};

template <bool XFAST>
__global__ __launch_bounds__(256) void gemm_dual(GJob j0, GJob j1, int nb0) {
  const bool first = (int)blockIdx.x < nb0;
  GJob J = first ? j0 : j1;
  const int b = first ? blockIdx.x : blockIdx.x - nb0;
  const int per = J.gx * J.gy;
  const int z = b / per;
  const int wid = b - z * per;
  const int batch = z / J.S, split = z - batch * J.S;
  const unsigned short* Ah = J.Ah + (long long)batch * J.sA;
  const unsigned short* Bh = J.Bh + (long long)batch * J.sB;
  float* C = J.C + (long long)z * J.sC;

  const int nwg = per;
  const int q = nwg >> 3, r = nwg & 7;
  const int xcd = wid & 7, posn = wid >> 3;
  const int swz = (xcd < r ? xcd * (q + 1) : r * (q + 1) + (xcd - r) * q) + posn;
  int mt, nt;
  if constexpr (XFAST) { mt = swz % J.gx; nt = swz / J.gx; }
  else                 { mt = swz / J.gy; nt = swz - mt * J.gy; }
  const int m0 = mt * 128, n0 = nt * 128;
  const int NC = J.gy << 7;
  const int kLen = J.K / J.S, k0base = split * kLen;

  __shared__ unsigned short lds[2][128][40];

  const int t = threadIdx.x;
  const int w4 = t >> 6, lane = t & 63;
  const int wr = w4 >> 1, wc = w4 & 1;
  const int lr = lane & 15, kq = lane >> 4;
  const int rowV = t >> 2, c8V = (t & 3) * 8;

  u16x8 rA[2], rB[2];
  auto LOAD = [&](int kb) {
    #pragma unroll
    for (int a = 0; a < 2; ++a) {
      rA[a] = *(const u16x8*)(Ah + (size_t)(m0 + rowV + 64 * a) * J.ldA + kb + c8V);
      rB[a] = *(const u16x8*)(Bh + (size_t)(n0 + rowV + 64 * a) * J.ldB + kb + c8V);
    }
  };
  auto STORE = [&]() {
    #pragma unroll
    for (int a = 0; a < 2; ++a) {
      *(u16x8*)&lds[0][rowV + 64 * a][c8V] = rA[a];
      *(u16x8*)&lds[1][rowV + 64 * a][c8V] = rB[a];
    }
  };

  f32x4 acc[4][4] = {};
  LOAD(k0base);
  for (int kk = 0; kk < kLen; kk += 32) {
    STORE();
    __syncthreads();
    if (kk + 32 < kLen) LOAD(k0base + kk + 32);

    bf16x8 ah[4], bh[4];
    #pragma unroll
    for (int i = 0; i < 4; ++i) {
      ah[i] = __builtin_bit_cast(bf16x8, *(const u16x8*)&lds[0][wr * 64 + i * 16 + lr][kq * 8]);
      bh[i] = __builtin_bit_cast(bf16x8, *(const u16x8*)&lds[1][wc * 64 + i * 16 + lr][kq * 8]);
    }
    #pragma unroll
    for (int i = 0; i < 4; ++i)
      #pragma unroll
      for (int j = 0; j < 4; ++j)
        acc[i][j] = __builtin_amdgcn_mfma_f32_16x16x32_bf16(ah[i], bh[j], acc[i][j], 0, 0, 0);
    __syncthreads();
  }

  #pragma unroll
  for (int i = 0; i < 4; ++i)
    #pragma unroll
    for (int j = 0; j < 4; ++j) {
      float* cp = C + (size_t)(m0 + wr * 64 + i * 16 + kq * 4) * NC + n0 + wc * 64 + j * 16 + lr;
      #pragma unroll
      for (int qq = 0; qq < 4; ++qq) cp[(size_t)qq * NC] = acc[i][j][qq];
    }
}

// ---------------------------------------------------------------------------
// gemm_ws: projection GEMMs. A fp32 [M][K] cvt-in-staging; B bf16 hi(/lo).
// ---------------------------------------------------------------------------
template <bool SPLIT>
__global__ __launch_bounds__(256) void gemm_ws(
    const float* __restrict__ Af,
    const unsigned short* __restrict__ Bh, const unsigned short* __restrict__ Bl,
    float* __restrict__ C, int K, int ldA, int ldB,
    long long sA, long long sB, long long sC) {
  const int gx = gridDim.x, gy = gridDim.y;
  const int nwg = gx * gy;
  const int wid = blockIdx.x + gx * blockIdx.y;
  const int q = nwg >> 3, r = nwg & 7;
  const int xcd = wid & 7, posn = wid >> 3;
  const int swz = (xcd < r ? xcd * (q + 1) : r * (q + 1) + (xcd - r) * q) + posn;
  const int mt = swz / gy;
  const int m0 = mt * 128, n0 = (swz - mt * gy) * 128;
  const int NC = gy << 7;

  constexpr int NBUF = SPLIT ? 4 : 2;
  __shared__ unsigned short lds[NBUF][128][40];

  const int t = threadIdx.x;
  const int w4 = t >> 6, lane = t & 63;
  const int wr = w4 >> 1, wc = w4 & 1;
  const int lr = lane & 15, kq = lane >> 4;
  const int rowA8 = t >> 3, qdA = (t & 7) * 4;
  const int rowV = t >> 2, c8V = (t & 3) * 8;

  f32x4 rAf[4];
  u16x8 rBh[2], rBl[2];

  auto LOAD = [&](int kb) {
    #pragma unroll
    for (int a = 0; a < 4; ++a)
      rAf[a] = *(const f32x4*)(Af + (size_t)(m0 + rowA8 + 32 * a) * ldA + kb + qdA);
    #pragma unroll
    for (int a = 0; a < 2; ++a) {
      rBh[a] = *(const u16x8*)(Bh + (size_t)(n0 + rowV + 64 * a) * ldB + kb + c8V);
      if constexpr (SPLIT)
        rBl[a] = *(const u16x8*)(Bl + (size_t)(n0 + rowV + 64 * a) * ldB + kb + c8V);
    }
  };
  auto STORE = [&]() {
    #pragma unroll
    for (int a = 0; a < 4; ++a) {
      f32x4 v = rAf[a];
      u16x4 h = {f2bf(v[0]), f2bf(v[1]), f2bf(v[2]), f2bf(v[3])};
      *(u16x4*)&lds[0][rowA8 + 32 * a][qdA] = h;
      if constexpr (SPLIT) {
        u16x4 l = {f2bf(v[0] - bf2f(h[0])), f2bf(v[1] - bf2f(h[1])),
                   f2bf(v[2] - bf2f(h[2])), f2bf(v[3] - bf2f(h[3]))};
        *(u16x4*)&lds[2][rowA8 + 32 * a][qdA] = l;
      }
    }
    #pragma unroll
    for (int a = 0; a < 2; ++a) {
      *(u16x8*)&lds[1][rowV + 64 * a][c8V] = rBh[a];
      if constexpr (SPLIT) *(u16x8*)&lds[3][rowV + 64 * a][c8V] = rBl[a];
    }
  };

  f32x4 acc[4][4] = {};
  LOAD(0);
  for (int kk = 0; kk < K; kk += 32) {
    STORE();
    __syncthreads();
    if (kk + 32 < K) LOAD(kk + 32);

    bf16x8 ah[4], bh[4], al[4], bl[4];
    #pragma unroll
    for (int i = 0; i < 4; ++i) {
      ah[i] = __builtin_bit_cast(bf16x8, *(const u16x8*)&lds[0][wr * 64 + i * 16 + lr][kq * 8]);
      bh[i] = __builtin_bit_cast(bf16x8, *(const u16x8*)&lds[1][wc * 64 + i * 16 + lr][kq * 8]);
      if constexpr (SPLIT) {
        al[i] = __builtin_bit_cast(bf16x8, *(const u16x8*)&lds[2][wr * 64 + i * 16 + lr][kq * 8]);
        bl[i] = __builtin_bit_cast(bf16x8, *(const u16x8*)&lds[3][wc * 64 + i * 16 + lr][kq * 8]);
      }
    }
    #pragma unroll
    for (int i = 0; i < 4; ++i)
      #pragma unroll
      for (int j = 0; j < 4; ++j) {
        acc[i][j] = __builtin_amdgcn_mfma_f32_16x16x32_bf16(ah[i], bh[j], acc[i][j], 0, 0, 0);
        if constexpr (SPLIT) {
          acc[i][j] = __builtin_amdgcn_mfma_f32_16x16x32_bf16(ah[i], bl[j], acc[i][j], 0, 0, 0);
          acc[i][j] = __builtin_amdgcn_mfma_f32_16x16x32_bf16(al[i], bh[j], acc[i][j], 0, 0, 0);
        }
      }
    __syncthreads();
  }

  #pragma unroll
  for (int i = 0; i < 4; ++i)
    #pragma unroll
    for (int j = 0; j < 4; ++j) {
      float* cp = C + (size_t)(m0 + wr * 64 + i * 16 + kq * 4) * NC + n0 + wc * 64 + j * 16 + lr;
      #pragma unroll
      for (int qq = 0; qq < 4; ++qq) cp[(size_t)qq * NC] = acc[i][j][qq];
    }
}

// ---------------------------------------------------------------------------
// Output GEMM with fused combine: A[r][c] = (T4p 2-slab sum) +
// (T2p 2-slab sum)*einv_hval;  C = A @ W_o (split hi/lo). M=12288,N=256,K=256.
// ---------------------------------------------------------------------------
__global__ __launch_bounds__(256) void gemm_out(
    const float* __restrict__ T2p, const float* __restrict__ T4p,
    const float* __restrict__ hEi, const unsigned short* __restrict__ Bh,
    const unsigned short* __restrict__ Bl, float* __restrict__ C) {
  const int gx = gridDim.x, gy = gridDim.y;
  const int nwg = gx * gy;
  const int wid = blockIdx.x + gx * blockIdx.y;
  const int q = nwg >> 3, r = nwg & 7;
  const int xcd = wid & 7, posn = wid >> 3;
  const int swz = (xcd < r ? xcd * (q + 1) : r * (q + 1) + (xcd - r) * q) + posn;
  const int mt = swz / gy;
  const int m0 = mt * 128, n0 = (swz - mt * gy) * 128;

  __shared__ unsigned short lds[4][128][40];
  const int t = threadIdx.x;
  const int w4 = t >> 6, lane = t & 63;
  const int wr = w4 >> 1, wc = w4 & 1;
  const int lr = lane & 15, kq = lane >> 4;
  const long long slab = 6144LL * 256;

  f32x4 acc[4][4] = {};

  for (int kb = 0; kb < 256; kb += 32) {
    #pragma unroll
    for (int a = 0; a < 4; ++a) {
      int idx = t + 256 * a;
      int row = idx >> 3, qd = (idx & 7) * 4;
      int rg = m0 + row;
      int b = rg >= 6144;
      int pos = rg - b * 6144;
      int ck = kb + qd;
      float s = hEi[((size_t)b * 8 + (ck >> 5)) * 6144 + pos];
      const float* b2 = T2p + ((long long)(b * 2) * 6144 + pos) * 256 + ck;
      const float* b4 = T4p + ((long long)(b * 2) * 6144 + pos) * 256 + ck;
      f32x4 t2 = *(const f32x4*)b2 + *(const f32x4*)(b2 + slab);
      f32x4 t4 = *(const f32x4*)b4 + *(const f32x4*)(b4 + slab);
      f32x4 v = t4 + t2 * s;
      u16x4 h = {f2bf(v[0]), f2bf(v[1]), f2bf(v[2]), f2bf(v[3])};
      *(u16x4*)&lds[0][row][qd] = h;
      u16x4 l = {f2bf(v[0] - bf2f(h[0])), f2bf(v[1] - bf2f(h[1])),
                 f2bf(v[2] - bf2f(h[2])), f2bf(v[3] - bf2f(h[3]))};
      *(u16x4*)&lds[2][row][qd] = l;
    }
    #pragma unroll
    for (int a = 0; a < 2; ++a) {
      int idx = t + 256 * a;
      int row = idx >> 2, c8 = (idx & 3) * 8;
      *(u16x8*)&lds[1][row][c8] = *(const u16x8*)(Bh + (size_t)(n0 + row) * 256 + kb + c8);
      *(u16x8*)&lds[3][row][c8] = *(const u16x8*)(Bl + (size_t)(n0 + row) * 256 + kb + c8);
    }
    __syncthreads();

    bf16x8 ah[4], bh[4], al[4], bl[4];
    #pragma unroll
    for (int i = 0; i < 4; ++i) {
      ah[i] = __builtin_bit_cast(bf16x8, *(const u16x8*)&lds[0][wr * 64 + i * 16 + lr][kq * 8]);
      bh[i] = __builtin_bit_cast(bf16x8, *(const u16x8*)&lds[1][wc * 64 + i * 16 + lr][kq * 8]);
      al[i] = __builtin_bit_cast(bf16x8, *(const u16x8*)&lds[2][wr * 64 + i * 16 + lr][kq * 8]);
      bl[i] = __builtin_bit_cast(bf16x8, *(const u16x8*)&lds[3][wc * 64 + i * 16 + lr][kq * 8]);
    }
    #pragma unroll
    for (int i = 0; i < 4; ++i)
      #pragma unroll
      for (int j = 0; j < 4; ++j) {
        acc[i][j] = __builtin_amdgcn_mfma_f32_16x16x32_bf16(ah[i], bh[j], acc[i][j], 0, 0, 0);
        acc[i][j] = __builtin_amdgcn_mfma_f32_16x16x32_bf16(ah[i], bl[j], acc[i][j], 0, 0, 0);
        acc[i][j] = __builtin_amdgcn_mfma_f32_16x16x32_bf16(al[i], bh[j], acc[i][j], 0, 0, 0);
      }
    __syncthreads();
  }

  #pragma unroll
  for (int i = 0; i < 4; ++i)
    #pragma unroll
    for (int j = 0; j < 4; ++j) {
      float* cp = C + (size_t)(m0 + wr * 64 + i * 16 + kq * 4) * 256 + n0 + wc * 64 + j * 16 + lr;
      #pragma unroll
      for (int qq = 0; qq < 4; ++qq) cp[(size_t)qq * 256] = acc[i][j][qq];
    }
}

// ---------------------------------------------------------------------------
// Mega-prep kernel, 12 KB LDS: [0,1024) vproj (4 rows/block) ;
// [1024,1152) weight transposes (two-phase hi/lo) ;
// [1152,13440) d1 -> d1N + d1T ; [13440,19584) d0 -> d0N + d0T.
// ---------------------------------------------------------------------------
struct PrepArgs {
  const float* wsrc[8]; unsigned short* wh[8]; unsigned short* wl[8];
  const float* d1; unsigned short* d1T; unsigned short* d1N;
  const float* d0; unsigned short* d0T_hi; unsigned short* d0N_hi;
  const float* xv; const float* Wvq; const float* Wvk; float* hvV;
};

__global__ __launch_bounds__(256) void prep_all(PrepArgs A) {
  __shared__ __align__(16) char smem[12288];
  const int t = threadIdx.x;
  const int bid = blockIdx.x;

  if (bid < 1024) {
    // ---- vproj (np-fp32 exact, 4 rows/block; per-row math identical) ----
    float* sx = (float*)smem;
    float* sq = (float*)(smem + 4096);
    float* sk = (float*)(smem + 8192);
    const int r0 = bid * 4;
    const int j = t;
    #pragma unroll
    for (int r = 0; r < 4; ++r) sx[r * 256 + j] = A.xv[(size_t)(r0 + r) * 256 + j];
    __syncthreads();
    float qa[4] = {}, ka[4] = {};
    for (int i = 0; i < 256; ++i) {
      float wq = A.Wvq[i * 256 + j], wk = A.Wvk[i * 256 + j];
      #pragma unroll
      for (int r = 0; r < 4; ++r) {
        qa[r] = __fmaf_rn(sx[r * 256 + i], wq, qa[r]);
        ka[r] = __fmaf_rn(sx[r * 256 + i], wk, ka[r]);
      }
    }
    #pragma unroll
    for (int r = 0; r < 4; ++r) { sq[r * 256 + j] = qa[r]; sk[r * 256 + j] = ka[r]; }
    __syncthreads();
    if (j < 32) {
      const int r = j >> 3, head = j & 7;
      const float* qq = &sq[r * 256 + head * 32];
      const float* kk = &sk[r * 256 + head * 32];
      float s0 = 0.0f, s1 = 0.0f, s2 = 0.0f, s3 = 0.0f;
      #pragma unroll 1
      for (int d = 0; d < 32; d += 4) {
        s0 = __fadd_rn(s0, __fmul_rn(qq[d + 0], kk[d + 0]));
        s1 = __fadd_rn(s1, __fmul_rn(qq[d + 1], kk[d + 1]));
        s2 = __fadd_rn(s2, __fmul_rn(qq[d + 2], kk[d + 2]));
        s3 = __fadd_rn(s3, __fmul_rn(qq[d + 3], kk[d + 3]));
      }
      float p = __fadd_rn(__fadd_rn(s0, s2), __fadd_rn(s1, s3));
      float hval = __fdiv_rn(p, sqrtf(32.0f));
      float inv = __fdiv_rn(1.0f, __fadd_rn(hval, 1e-6f));
      const int row = r0 + r;
      const int b = row / 2048, pos = row - b * 2048;
      A.hvV[((size_t)b * 8 + head) * 2048 + pos] = inv;
    }
  } else if (bid < 1152) {
    // ---- weight transposes, two-phase (hi then lo) through one 9KB tile ----
    const int idx = bid - 1024;
    const int w = idx >> 4;
    const int r0 = (idx & 3) * 64, c0 = ((idx >> 2) & 3) * 64;
    const float* src = A.wsrc[w];
    unsigned short* oh = A.wh[w];
    unsigned short* ol = A.wl[w];
    unsigned short (*tile)[72] = (unsigned short (*)[72])smem;
    f32x4 v[4];
    int trs[4], tcs[4];
    #pragma unroll
    for (int a = 0; a < 4; ++a) {
      int idx2 = t + 256 * a;
      trs[a] = idx2 >> 4; tcs[a] = (idx2 & 15) * 4;
      v[a] = *(const f32x4*)(src + (size_t)(r0 + trs[a]) * 256 + c0 + tcs[a]);
    }
    #pragma unroll
    for (int a = 0; a < 4; ++a) {
      u16x4 hh = {f2bf(v[a][0]), f2bf(v[a][1]), f2bf(v[a][2]), f2bf(v[a][3])};
      *(u16x4*)&tile[trs[a]][tcs[a]] = hh;
    }
    __syncthreads();
    #pragma unroll
    for (int a = 0; a < 2; ++a) {
      int idx2 = t + 256 * a;
      int orow = idx2 >> 3, oc = (idx2 & 7) * 8;
      u16x8 vh;
      #pragma unroll
      for (int j = 0; j < 8; ++j) vh[j] = tile[oc + j][orow];
      *(u16x8*)(oh + (size_t)(c0 + orow) * 256 + r0 + oc) = vh;
    }
    if (ol) {
      __syncthreads();
      #pragma unroll
      for (int a = 0; a < 4; ++a) {
        u16x4 hh = {f2bf(v[a][0]), f2bf(v[a][1]), f2bf(v[a][2]), f2bf(v[a][3])};
        u16x4 ll = {f2bf(v[a][0] - bf2f(hh[0])), f2bf(v[a][1] - bf2f(hh[1])),
                    f2bf(v[a][2] - bf2f(hh[2])), f2bf(v[a][3] - bf2f(hh[3]))};
        *(u16x4*)&tile[trs[a]][tcs[a]] = ll;
      }
      __syncthreads();
      #pragma unroll
      for (int a = 0; a < 2; ++a) {
        int idx2 = t + 256 * a;
        int orow = idx2 >> 3, oc = (idx2 & 7) * 8;
        u16x8 vl;
        #pragma unroll
        for (int j = 0; j < 8; ++j) vl[j] = tile[oc + j][orow];
        *(u16x8*)(ol + (size_t)(c0 + orow) * 256 + r0 + oc) = vl;
      }
    }
  } else if (bid < 13440) {
    // ---- d1: [2][4096][6144] -> d1N (natural bf16, NT) + d1T (NT) ----
    const int idx = bid - 1152;
    const int x = idx & 63;
    const int rem = idx >> 6;
    const int y = rem % 96;
    const int b = rem / 96;
    const int r0 = x * 64, c0 = y * 64;
    unsigned short (*thi)[72] = (unsigned short (*)[72])smem;
    #pragma unroll
    for (int a = 0; a < 4; ++a) {
      int idx2 = t + 256 * a;
      int tr = idx2 >> 4, tc = (idx2 & 15) * 4;
      size_t off = ((size_t)b * 4096 + r0 + tr) * 6144 + c0 + tc;
      f32x4 v = *(const f32x4*)(A.d1 + off);
      u16x4 hh = {f2bf(v[0]), f2bf(v[1]), f2bf(v[2]), f2bf(v[3])};
      *(u16x4*)&thi[tr][tc] = hh;
      nts((u16x4*)(A.d1N + off), hh);
    }
    __syncthreads();
    #pragma unroll
    for (int a = 0; a < 2; ++a) {
      int idx2 = t + 256 * a;
      int orow = idx2 >> 3, oc = (idx2 & 7) * 8;
      u16x8 vh;
      #pragma unroll
      for (int j = 0; j < 8; ++j) vh[j] = thi[oc + j][orow];
      nts((u16x8*)(A.d1T + ((size_t)b * 6144 + c0 + orow) * 4096 + r0 + oc), vh);
    }
  } else {
    // ---- d0: [2][6144][2048] -> d0N (NT) + d0T (NT) ----
    const int idx = bid - 13440;
    const int x = idx % 96;
    const int rem = idx / 96;
    const int y = rem & 31;
    const int b = rem >> 5;
    const int r0 = x * 64, c0 = y * 64;
    unsigned short (*thi)[72] = (unsigned short (*)[72])smem;
    #pragma unroll
    for (int a = 0; a < 4; ++a) {
      int idx2 = t + 256 * a;
      int tr = idx2 >> 4, tc = (idx2 & 15) * 4;
      size_t off = ((size_t)b * 6144 + r0 + tr) * 2048 + c0 + tc;
      f32x4 v = *(const f32x4*)(A.d0 + off);
      u16x4 hh = {f2bf(v[0]), f2bf(v[1]), f2bf(v[2]), f2bf(v[3])};
      *(u16x4*)&thi[tr][tc] = hh;
      nts((u16x4*)(A.d0N_hi + off), hh);
    }
    __syncthreads();
    #pragma unroll
    for (int a = 0; a < 2; ++a) {
      int idx2 = t + 256 * a;
      int orow = idx2 >> 3, oc = (idx2 & 7) * 8;
      u16x8 vh;
      #pragma unroll
      for (int j = 0; j < 8; ++j) vh[j] = thi[oc + j][orow];
      nts((u16x8*)(A.d0T_hi + ((size_t)b * 2048 + c0 + orow) * 6144 + r0 + oc), vh);
    }
  }
}

// ---------------------------------------------------------------------------
// Fused eVT (unscaled bf16) + Y0T (scaled bf16) from P1 cols 512..767.
// ---------------------------------------------------------------------------
__global__ __launch_bounds__(256) void xpose_ev(
    const float* __restrict__ P1, unsigned short* __restrict__ eVT,
    unsigned short* __restrict__ yhi, const float* __restrict__ hE) {
  __shared__ unsigned short te[64][72], th[64][72];
  const int b = blockIdx.z;
  const int r0 = blockIdx.x * 64, c0 = blockIdx.y * 64;
  const int t = threadIdx.x;
  #pragma unroll
  for (int a = 0; a < 4; ++a) {
    int idx = t + 256 * a;
    int tr = idx >> 4, tc = (idx & 15) * 4;
    f32x4 v = *(const f32x4*)(P1 + ((size_t)b * 6144 + r0 + tr) * 1280 + 512 + c0 + tc);
    u16x4 eh = {f2bf(v[0]), f2bf(v[1]), f2bf(v[2]), f2bf(v[3])};
    *(u16x4*)&te[tr][tc] = eh;
    float s = hE[((size_t)b * 8 + ((c0 + tc) >> 5)) * 6144 + r0 + tr];
    f32x4 y = v * s;
    u16x4 hh = {f2bf(y[0]), f2bf(y[1]), f2bf(y[2]), f2bf(y[3])};
    *(u16x4*)&th[tr][tc] = hh;
  }
  __syncthreads();
  #pragma unroll
  for (int a = 0; a < 2; ++a) {
    int idx = t + 256 * a;
    int orow = idx >> 3, oc = (idx & 7) * 8;
    u16x8 ve, vh;
    #pragma unroll
    for (int j = 0; j < 8; ++j) {
      ve[j] = te[oc + j][orow];
      vh[j] = th[oc + j][orow];
    }
    size_t o = ((size_t)b * 256 + c0 + orow) * 6144 + r0 + oc;
    *(u16x8*)(eVT + o) = ve;
    *(u16x8*)(yhi + o) = vh;
  }
}

// ---------------------------------------------------------------------------
// Merged rsc_cvt (sum S slabs ascending, scale, cvt bf16).
// ---------------------------------------------------------------------------
static __device__ __forceinline__ void rsc_body(
    const float* in, unsigned short* out_hi, const float* h,
    int S, int R, int P, int bid, int nblk) {
  const long long qP = P >> 2;
  const long long nq = 2LL * R * qP;
  long long i = (long long)bid * 256 + threadIdx.x;
  const long long stride = (long long)nblk * 256;
  for (; i < nq; i += stride) {
    long long b = i / (R * qP);
    long long rem = i - b * (R * qP);
    int row = (int)(rem / qP);
    long long qc = rem - (long long)row * qP;
    const f32x4* base = (const f32x4*)in + ((b * S) * R + row) * qP + qc;
    f32x4 v = base[0];
    for (int s = 1; s < S; ++s) v += base[(long long)s * R * qP];
    v *= *(const f32x4*)(h + ((size_t)b * 8 + (row >> 5)) * P + (qc << 2));
    u16x4 hh = {f2bf(v[0]), f2bf(v[1]), f2bf(v[2]), f2bf(v[3])};
    ((u16x4*)out_hi)[i] = hh;
  }
}

__global__ void rsc2(const float* in1, unsigned short* o1h, const float* hF,
                     const float* in3, unsigned short* o3h, const float* hV) {
  if (blockIdx.x < 2048)
    rsc_body(in1, o1h, hF, 3, 256, 4096, blockIdx.x, 2048);
  else
    rsc_body(in3, o3h, hV, 6, 256, 2048, blockIdx.x - 2048, 1024);
}

// ---------------------------------------------------------------------------
// Merged hval dots: [0,3072) e/einv pairs from P1; [3072,5120) f pair from P3.
// ---------------------------------------------------------------------------
__global__ __launch_bounds__(256) void dots(
    const float* __restrict__ P1, float* __restrict__ hE, float* __restrict__ hEi,
    const float* __restrict__ P3, float* __restrict__ hF) {
  const int wv = threadIdx.x >> 6, lane = threadIdx.x & 63;
  if (blockIdx.x < 3072) {
    const int row = blockIdx.x * 4 + wv;
    const float* base = P1 + (size_t)row * 1280 + lane * 4;
    f32x4 qv = *(const f32x4*)(base);
    f32x4 kv = *(const f32x4*)(base + 256);
    float p = qv[0] * kv[0] + qv[1] * kv[1] + qv[2] * kv[2] + qv[3] * kv[3];
    p += __shfl_xor(p, 1); p += __shfl_xor(p, 2); p += __shfl_xor(p, 4);
    f32x4 q2 = *(const f32x4*)(base + 768);
    f32x4 k2 = *(const f32x4*)(base + 1024);
    float p2 = q2[0] * k2[0] + q2[1] * k2[1] + q2[2] * k2[2] + q2[3] * k2[3];
    p2 += __shfl_xor(p2, 1); p2 += __shfl_xor(p2, 2); p2 += __shfl_xor(p2, 4);
    if ((lane & 7) == 0) {
      const int head = lane >> 3;
      const int b = row / 6144, pos = row % 6144;
      hE[((size_t)b * 8 + head) * 6144 + pos] = p * 0.17677669529663687f;
      hEi[((size_t)b * 8 + head) * 6144 + pos] = p2 * 0.17677669529663687f;
    }
  } else {
    const int row = (blockIdx.x - 3072) * 4 + wv;
    const float* base = P3 + (size_t)row * 512 + lane * 4;
    f32x4 qv = *(const f32x4*)(base);
    f32x4 kv = *(const f32x4*)(base + 256);
    float p = qv[0] * kv[0] + qv[1] * kv[1] + qv[2] * kv[2] + qv[3] * kv[3];
    p += __shfl_xor(p, 1); p += __shfl_xor(p, 2); p += __shfl_xor(p, 4);
    if ((lane & 7) == 0) {
      const int head = lane >> 3;
      const int b = row / 4096, pos = row % 4096;
      hF[((size_t)b * 8 + head) * 4096 + pos] = p * 0.17677669529663687f;
    }
  }
}

// ---------------------------------------------------------------------------
extern "C" void kernel_launch(void* const* d_in, const int* in_sizes, int n_in,
                              void* d_out, int out_size, void* d_ws, size_t ws_size,
                              hipStream_t stream) {
  const float* x_v = (const float*)d_in[0];
  const float* x_e = (const float*)d_in[1];
  const float* x_f = (const float*)d_in[2];
  const float* d0  = (const float*)d_in[3];   // (2, 6144, 2048)
  const float* d1  = (const float*)d_in[4];   // (2, 4096, 6144)
  float* out = (float*)d_out;

  const int NV = 2048, ME = 6144, KF = 4096;
  const unsigned short* NUS = nullptr;

  char* ws = (char*)d_ws;
  size_t o = 0;
  auto alloc = [&](size_t bytes) { size_t r = o; o = (o + bytes + 255) & ~255ULL; return r; };

  unsigned short* Wcat5_hi = (unsigned short*)(ws + alloc(1280 * 256 * 2));
  unsigned short* Wcat5_lo = (unsigned short*)(ws + alloc(1280 * 256 * 2));
  unsigned short* W3_hi = (unsigned short*)(ws + alloc(512 * 256 * 2));
  unsigned short* Wo_hi = (unsigned short*)(ws + alloc(256 * 256 * 2));
  unsigned short* Wo_lo = (unsigned short*)(ws + alloc(256 * 256 * 2));
  float* pHvE  = (float*)(ws + alloc(2 * 8 * ME * 4));
  float* pHvEi = (float*)(ws + alloc(2 * 8 * ME * 4));
  float* pHvF  = (float*)(ws + alloc(2 * 8 * KF * 4));
  float* pHvV  = (float*)(ws + alloc(2 * 8 * NV * 4));
  unsigned short* d1T_hi = (unsigned short*)(ws + alloc((size_t)2 * ME * KF * 2));
  unsigned short* d1N_hi = (unsigned short*)(ws + alloc((size_t)2 * KF * ME * 2));
  unsigned short* d0T_hi = (unsigned short*)(ws + alloc((size_t)2 * NV * ME * 2));
  unsigned short* d0N_hi = (unsigned short*)(ws + alloc((size_t)2 * ME * NV * 2));
  unsigned short* eVT_hi = (unsigned short*)(ws + alloc((size_t)2 * 256 * ME * 2));
  unsigned short* Y0T_hi = (unsigned short*)(ws + alloc((size_t)2 * 256 * ME * 2));
  unsigned short* T1sT_hi = (unsigned short*)(ws + alloc((size_t)2 * 256 * KF * 2));
  unsigned short* T3sT_hi = (unsigned short*)(ws + alloc((size_t)2 * 256 * NV * 2));
  float* pP1 = (float*)(ws + alloc((size_t)12288 * 1280 * 4));
  float* pP3 = (float*)(ws + alloc((size_t)8192 * 512 * 4));
  float* pTp1 = (float*)(ws + alloc((size_t)2 * 3 * 256 * KF * 4));   // T1^T slabs
  float* pTp3 = (float*)(ws + alloc((size_t)2 * 6 * 256 * NV * 4));   // T3^T slabs
  float* pT2p = (float*)(ws + alloc((size_t)2 * 2 * ME * 256 * 4));
  float* pT4p = (float*)(ws + alloc((size_t)2 * 2 * ME * 256 * 4));

  dim3 blk(256);

  // --- mega-prep: vproj + weight transposes + d1/d0 conversions ---
  PrepArgs pa;
  pa.wsrc[0] = (const float*)d_in[7];  pa.wh[0] = Wcat5_hi;          pa.wl[0] = Wcat5_lo;
  pa.wsrc[1] = (const float*)d_in[8];  pa.wh[1] = Wcat5_hi + 65536;  pa.wl[1] = Wcat5_lo + 65536;
  pa.wsrc[2] = (const float*)d_in[11]; pa.wh[2] = Wcat5_hi + 131072; pa.wl[2] = Wcat5_lo + 131072;
  pa.wsrc[3] = (const float*)d_in[9];  pa.wh[3] = Wcat5_hi + 196608; pa.wl[3] = Wcat5_lo + 196608;
  pa.wsrc[4] = (const float*)d_in[10]; pa.wh[4] = Wcat5_hi + 262144; pa.wl[4] = Wcat5_lo + 262144;
  pa.wsrc[5] = (const float*)d_in[12]; pa.wh[5] = W3_hi;             pa.wl[5] = nullptr;
  pa.wsrc[6] = (const float*)d_in[13]; pa.wh[6] = W3_hi + 65536;     pa.wl[6] = nullptr;
  pa.wsrc[7] = (const float*)d_in[14]; pa.wh[7] = Wo_hi;             pa.wl[7] = Wo_lo;
  pa.d1 = d1; pa.d1T = d1T_hi; pa.d1N = d1N_hi;
  pa.d0 = d0; pa.d0T_hi = d0T_hi; pa.d0N_hi = d0N_hi;
  pa.xv = x_v; pa.Wvq = (const float*)d_in[5]; pa.Wvk = (const float*)d_in[6];
  pa.hvV = pHvV;
  prep_all<<<19584, blk, 0, stream>>>(pa);

  // --- projections ---
  gemm_ws<true><<<dim3(96, 10, 1), blk, 0, stream>>>(
      x_e, Wcat5_hi, Wcat5_lo, pP1, 256, 256, 256, 0, 0, 0);
  gemm_ws<false><<<dim3(64, 4, 1), blk, 0, stream>>>(
      x_f, W3_hi, NUS, pP3, 256, 256, 256, 0, 0, 0);
  dots<<<5120, blk, 0, stream>>>(pP1, pHvE, pHvEi, pP3, pHvF);
  xpose_ev<<<dim3(96, 4, 2), blk, 0, stream>>>(pP1, eVT_hi, Y0T_hi, pHvE);

  // --- T1 + T3 in one launch ---
  GJob jT1, jT3;
  jT1.Ah = eVT_hi; jT1.Bh = d1N_hi; jT1.C = pTp1;
  jT1.K = ME; jT1.ldA = ME; jT1.ldB = ME; jT1.S = 3; jT1.gx = 2; jT1.gy = 32;
  jT1.sA = 256LL * ME; jT1.sB = (long long)KF * ME; jT1.sC = 256LL * KF;
  jT3.Ah = Y0T_hi; jT3.Bh = d0T_hi; jT3.C = pTp3;
  jT3.K = ME; jT3.ldA = ME; jT3.ldB = ME; jT3.S = 6; jT3.gx = 2; jT3.gy = 16;
  jT3.sA = 256LL * ME; jT3.sB = (long long)NV * ME; jT3.sC = 256LL * NV;
  gemm_dual<true><<<768, blk, 0, stream>>>(jT1, jT3, 384);

  // --- reductions + scale + cvt ---
  rsc2<<<3072, blk, 0, stream>>>(pTp1, T1sT_hi, pHvF, pTp3, T3sT_hi, pHvV);

  // --- T2 + T4 in one launch ---
  GJob jT2, jT4;
  jT2.Ah = d1T_hi; jT2.Bh = T1sT_hi; jT2.C = pT2p;
  jT2.K = KF; jT2.ldA = KF; jT2.ldB = KF; jT2.S = 2; jT2.gx = 48; jT2.gy = 2;
  jT2.sA = (long long)ME * KF; jT2.sB = 256LL * KF; jT2.sC = (long long)ME * 256;
  jT4.Ah = d0N_hi; jT4.Bh = T3sT_hi; jT4.C = pT4p;
  jT4.K = NV; jT4.ldA = NV; jT4.ldB = NV; jT4.S = 2; jT4.gx = 48; jT4.gy = 2;
  jT4.sA = (long long)ME * NV; jT4.sB = 256LL * NV; jT4.sC = (long long)ME * 256;
  gemm_dual<false><<<768, blk, 0, stream>>>(jT2, jT4, 384);

  // --- fused combine + output projection ---
  gemm_out<<<dim3(96, 2, 1), blk, 0, stream>>>(pT2p, pT4p, pHvEi, Wo_hi, Wo_lo, out);
}

// Round 14
// 396.946 us; speedup vs baseline: 1.1004x; 1.1004x over previous
//
#include <hip/hip_runtime.h>
#include <hip/hip_bf16.h>
#include <cstdint>
#include <cstddef>

// ---------------------------------------------------------------------------
// MeshMultiHeadHodgeLaplaceAttention  (b=2, n=2048, m=6144, k=4096, D=256, H=8)
//
//   up:   T1 = d_1 @ eV ; *f_hval ; T2 = d_1^T @ T1s ; (*einv_hval in combine)
//   down: Y0 = eV*e_hval ; T3 = d_0^T @ Y0 ; *1/(v_hval+eps) ; T4 = d_0 @ T3s
//   out = (T2*einv_hval + T4) @ W_o
//
// Precision: v_hval replicates numpy fp32 bit-exactly; P1 + output GEMM
// split-bf16; T1..T4 plain bf16 (validated R10-R12, absmax=256).
//
// R14 (on R12 base; R13's NT-stores + 4-row vproj reverted as regressions):
//  - prep d-conversion tiles 128x64 -> transposed writes in 256B chunks
//    (same LDS budget, same arithmetic, same occupancy as R12).
//  - P1+P3 merged into one proj_dual launch (uniform GEMM LDS; no R11 trap).
// ---------------------------------------------------------------------------

typedef __attribute__((ext_vector_type(4))) float f32x4;
typedef __attribute__((ext_vector_type(4))) unsigned short u16x4;
typedef __attribute__((ext_vector_type(8))) unsigned short u16x8;
typedef __attribute__((ext_vector_type(8))) __bf16 bf16x8;

static __device__ __forceinline__ unsigned short f2bf(float f) {
  uint32_t u = __builtin_bit_cast(uint32_t, f);
  uint32_t r = (u + 0x7FFFu + ((u >> 16) & 1u)) >> 16;  // RNE
  return (unsigned short)r;
}
static __device__ __forceinline__ float bf2f(unsigned short h) {
  return __builtin_bit_cast(float, (uint32_t)h << 16);
}

// ---------------------------------------------------------------------------
// Dual-job plain-bf16 GEMM. Per job: C[M x gy*128] = A(bf16 [M][K]) *
// B(bf16 [N][K]); split-K z = batch*S + split; 128x128 tile, reg-prefetch.
// ---------------------------------------------------------------------------
struct GJob {
  const unsigned short* Ah; const unsigned short* Bh; float* C;
  int K, ldA, ldB, S, gx, gy;
  long long sA, sB, sC;
};

template <bool XFAST>
__global__ __launch_bounds__(256) void gemm_dual(GJob j0, GJob j1, int nb0) {
  const bool first = (int)blockIdx.x < nb0;
  GJob J = first ? j0 : j1;
  const int b = first ? blockIdx.x : blockIdx.x - nb0;
  const int per = J.gx * J.gy;
  const int z = b / per;
  const int wid = b - z * per;
  const int batch = z / J.S, split = z - batch * J.S;
  const unsigned short* Ah = J.Ah + (long long)batch * J.sA;
  const unsigned short* Bh = J.Bh + (long long)batch * J.sB;
  float* C = J.C + (long long)z * J.sC;

  const int nwg = per;
  const int q = nwg >> 3, r = nwg & 7;
  const int xcd = wid & 7, posn = wid >> 3;
  const int swz = (xcd < r ? xcd * (q + 1) : r * (q + 1) + (xcd - r) * q) + posn;
  int mt, nt;
  if constexpr (XFAST) { mt = swz % J.gx; nt = swz / J.gx; }
  else                 { mt = swz / J.gy; nt = swz - mt * J.gy; }
  const int m0 = mt * 128, n0 = nt * 128;
  const int NC = J.gy << 7;
  const int kLen = J.K / J.S, k0base = split * kLen;

  __shared__ unsigned short lds[2][128][40];

  const int t = threadIdx.x;
  const int w4 = t >> 6, lane = t & 63;
  const int wr = w4 >> 1, wc = w4 & 1;
  const int lr = lane & 15, kq = lane >> 4;
  const int rowV = t >> 2, c8V = (t & 3) * 8;

  u16x8 rA[2], rB[2];
  auto LOAD = [&](int kb) {
    #pragma unroll
    for (int a = 0; a < 2; ++a) {
      rA[a] = *(const u16x8*)(Ah + (size_t)(m0 + rowV + 64 * a) * J.ldA + kb + c8V);
      rB[a] = *(const u16x8*)(Bh + (size_t)(n0 + rowV + 64 * a) * J.ldB + kb + c8V);
    }
  };
  auto STORE = [&]() {
    #pragma unroll
    for (int a = 0; a < 2; ++a) {
      *(u16x8*)&lds[0][rowV + 64 * a][c8V] = rA[a];
      *(u16x8*)&lds[1][rowV + 64 * a][c8V] = rB[a];
    }
  };

  f32x4 acc[4][4] = {};
  LOAD(k0base);
  for (int kk = 0; kk < kLen; kk += 32) {
    STORE();
    __syncthreads();
    if (kk + 32 < kLen) LOAD(k0base + kk + 32);

    bf16x8 ah[4], bh[4];
    #pragma unroll
    for (int i = 0; i < 4; ++i) {
      ah[i] = __builtin_bit_cast(bf16x8, *(const u16x8*)&lds[0][wr * 64 + i * 16 + lr][kq * 8]);
      bh[i] = __builtin_bit_cast(bf16x8, *(const u16x8*)&lds[1][wc * 64 + i * 16 + lr][kq * 8]);
    }
    #pragma unroll
    for (int i = 0; i < 4; ++i)
      #pragma unroll
      for (int j = 0; j < 4; ++j)
        acc[i][j] = __builtin_amdgcn_mfma_f32_16x16x32_bf16(ah[i], bh[j], acc[i][j], 0, 0, 0);
    __syncthreads();
  }

  #pragma unroll
  for (int i = 0; i < 4; ++i)
    #pragma unroll
    for (int j = 0; j < 4; ++j) {
      float* cp = C + (size_t)(m0 + wr * 64 + i * 16 + kq * 4) * NC + n0 + wc * 64 + j * 16 + lr;
      #pragma unroll
      for (int qq = 0; qq < 4; ++qq) cp[(size_t)qq * NC] = acc[i][j][qq];
    }
}

// ---------------------------------------------------------------------------
// Projection GEMM body (K=256): C[M x gy*128] = A fp32 [M][256] (cvt in
// staging) * B bf16 hi(/lo) [N][256].
// ---------------------------------------------------------------------------
template <bool SPLIT>
static __device__ void proj_body(char* smem, int wid, int gx, int gy,
                                 const float* __restrict__ Af,
                                 const unsigned short* __restrict__ Bh,
                                 const unsigned short* __restrict__ Bl,
                                 float* __restrict__ C) {
  const int nwg = gx * gy;
  const int q = nwg >> 3, r = nwg & 7;
  const int xcd = wid & 7, posn = wid >> 3;
  const int swz = (xcd < r ? xcd * (q + 1) : r * (q + 1) + (xcd - r) * q) + posn;
  const int mt = swz / gy;
  const int m0 = mt * 128, n0 = (swz - mt * gy) * 128;
  const int NC = gy << 7;

  typedef unsigned short ldsrow[128][40];
  ldsrow* lds = (ldsrow*)smem;

  const int t = threadIdx.x;
  const int w4 = t >> 6, lane = t & 63;
  const int wr = w4 >> 1, wc = w4 & 1;
  const int lr = lane & 15, kq = lane >> 4;
  const int rowA8 = t >> 3, qdA = (t & 7) * 4;
  const int rowV = t >> 2, c8V = (t & 3) * 8;

  f32x4 rAf[4];
  u16x8 rBh[2], rBl[2];

  auto LOAD = [&](int kb) {
    #pragma unroll
    for (int a = 0; a < 4; ++a)
      rAf[a] = *(const f32x4*)(Af + (size_t)(m0 + rowA8 + 32 * a) * 256 + kb + qdA);
    #pragma unroll
    for (int a = 0; a < 2; ++a) {
      rBh[a] = *(const u16x8*)(Bh + (size_t)(n0 + rowV + 64 * a) * 256 + kb + c8V);
      if constexpr (SPLIT)
        rBl[a] = *(const u16x8*)(Bl + (size_t)(n0 + rowV + 64 * a) * 256 + kb + c8V);
    }
  };
  auto STORE = [&]() {
    #pragma unroll
    for (int a = 0; a < 4; ++a) {
      f32x4 v = rAf[a];
      u16x4 h = {f2bf(v[0]), f2bf(v[1]), f2bf(v[2]), f2bf(v[3])};
      *(u16x4*)&lds[0][rowA8 + 32 * a][qdA] = h;
      if constexpr (SPLIT) {
        u16x4 l = {f2bf(v[0] - bf2f(h[0])), f2bf(v[1] - bf2f(h[1])),
                   f2bf(v[2] - bf2f(h[2])), f2bf(v[3] - bf2f(h[3]))};
        *(u16x4*)&lds[2][rowA8 + 32 * a][qdA] = l;
      }
    }
    #pragma unroll
    for (int a = 0; a < 2; ++a) {
      *(u16x8*)&lds[1][rowV + 64 * a][c8V] = rBh[a];
      if constexpr (SPLIT) *(u16x8*)&lds[3][rowV + 64 * a][c8V] = rBl[a];
    }
  };

  f32x4 acc[4][4] = {};
  LOAD(0);
  for (int kk = 0; kk < 256; kk += 32) {
    STORE();
    __syncthreads();
    if (kk + 32 < 256) LOAD(kk + 32);

    bf16x8 ah[4], bh[4], al[4], bl[4];
    #pragma unroll
    for (int i = 0; i < 4; ++i) {
      ah[i] = __builtin_bit_cast(bf16x8, *(const u16x8*)&lds[0][wr * 64 + i * 16 + lr][kq * 8]);
      bh[i] = __builtin_bit_cast(bf16x8, *(const u16x8*)&lds[1][wc * 64 + i * 16 + lr][kq * 8]);
      if constexpr (SPLIT) {
        al[i] = __builtin_bit_cast(bf16x8, *(const u16x8*)&lds[2][wr * 64 + i * 16 + lr][kq * 8]);
        bl[i] = __builtin_bit_cast(bf16x8, *(const u16x8*)&lds[3][wc * 64 + i * 16 + lr][kq * 8]);
      }
    }
    #pragma unroll
    for (int i = 0; i < 4; ++i)
      #pragma unroll
      for (int j = 0; j < 4; ++j) {
        acc[i][j] = __builtin_amdgcn_mfma_f32_16x16x32_bf16(ah[i], bh[j], acc[i][j], 0, 0, 0);
        if constexpr (SPLIT) {
          acc[i][j] = __builtin_amdgcn_mfma_f32_16x16x32_bf16(ah[i], bl[j], acc[i][j], 0, 0, 0);
          acc[i][j] = __builtin_amdgcn_mfma_f32_16x16x32_bf16(al[i], bh[j], acc[i][j], 0, 0, 0);
        }
      }
    __syncthreads();
  }

  #pragma unroll
  for (int i = 0; i < 4; ++i)
    #pragma unroll
    for (int j = 0; j < 4; ++j) {
      float* cp = C + (size_t)(m0 + wr * 64 + i * 16 + kq * 4) * NC + n0 + wc * 64 + j * 16 + lr;
      #pragma unroll
      for (int qq = 0; qq < 4; ++qq) cp[(size_t)qq * NC] = acc[i][j][qq];
    }
}

// P1 (split, 960 blocks) + P3 (plain, 256 blocks) in one launch.
__global__ __launch_bounds__(256) void proj_dual(
    const float* __restrict__ xe, const unsigned short* __restrict__ W5h,
    const unsigned short* __restrict__ W5l, float* __restrict__ P1,
    const float* __restrict__ xf, const unsigned short* __restrict__ W3h,
    float* __restrict__ P3) {
  __shared__ __align__(16) unsigned short lds[4][128][40];
  if ((int)blockIdx.x < 960)
    proj_body<true>((char*)lds, blockIdx.x, 96, 10, xe, W5h, W5l, P1);
  else
    proj_body<false>((char*)lds, blockIdx.x - 960, 64, 4, xf, W3h, nullptr, P3);
}

// ---------------------------------------------------------------------------
// Output GEMM with fused combine: A[r][c] = (T4p 2-slab sum) +
// (T2p 2-slab sum)*einv_hval;  C = A @ W_o (split hi/lo). M=12288,N=256,K=256.
// ---------------------------------------------------------------------------
__global__ __launch_bounds__(256) void gemm_out(
    const float* __restrict__ T2p, const float* __restrict__ T4p,
    const float* __restrict__ hEi, const unsigned short* __restrict__ Bh,
    const unsigned short* __restrict__ Bl, float* __restrict__ C) {
  const int gx = gridDim.x, gy = gridDim.y;
  const int nwg = gx * gy;
  const int wid = blockIdx.x + gx * blockIdx.y;
  const int q = nwg >> 3, r = nwg & 7;
  const int xcd = wid & 7, posn = wid >> 3;
  const int swz = (xcd < r ? xcd * (q + 1) : r * (q + 1) + (xcd - r) * q) + posn;
  const int mt = swz / gy;
  const int m0 = mt * 128, n0 = (swz - mt * gy) * 128;

  __shared__ unsigned short lds[4][128][40];
  const int t = threadIdx.x;
  const int w4 = t >> 6, lane = t & 63;
  const int wr = w4 >> 1, wc = w4 & 1;
  const int lr = lane & 15, kq = lane >> 4;
  const long long slab = 6144LL * 256;

  f32x4 acc[4][4] = {};

  for (int kb = 0; kb < 256; kb += 32) {
    #pragma unroll
    for (int a = 0; a < 4; ++a) {
      int idx = t + 256 * a;
      int row = idx >> 3, qd = (idx & 7) * 4;
      int rg = m0 + row;
      int b = rg >= 6144;
      int pos = rg - b * 6144;
      int ck = kb + qd;
      float s = hEi[((size_t)b * 8 + (ck >> 5)) * 6144 + pos];
      const float* b2 = T2p + ((long long)(b * 2) * 6144 + pos) * 256 + ck;
      const float* b4 = T4p + ((long long)(b * 2) * 6144 + pos) * 256 + ck;
      f32x4 t2 = *(const f32x4*)b2 + *(const f32x4*)(b2 + slab);
      f32x4 t4 = *(const f32x4*)b4 + *(const f32x4*)(b4 + slab);
      f32x4 v = t4 + t2 * s;
      u16x4 h = {f2bf(v[0]), f2bf(v[1]), f2bf(v[2]), f2bf(v[3])};
      *(u16x4*)&lds[0][row][qd] = h;
      u16x4 l = {f2bf(v[0] - bf2f(h[0])), f2bf(v[1] - bf2f(h[1])),
                 f2bf(v[2] - bf2f(h[2])), f2bf(v[3] - bf2f(h[3]))};
      *(u16x4*)&lds[2][row][qd] = l;
    }
    #pragma unroll
    for (int a = 0; a < 2; ++a) {
      int idx = t + 256 * a;
      int row = idx >> 2, c8 = (idx & 3) * 8;
      *(u16x8*)&lds[1][row][c8] = *(const u16x8*)(Bh + (size_t)(n0 + row) * 256 + kb + c8);
      *(u16x8*)&lds[3][row][c8] = *(const u16x8*)(Bl + (size_t)(n0 + row) * 256 + kb + c8);
    }
    __syncthreads();

    bf16x8 ah[4], bh[4], al[4], bl[4];
    #pragma unroll
    for (int i = 0; i < 4; ++i) {
      ah[i] = __builtin_bit_cast(bf16x8, *(const u16x8*)&lds[0][wr * 64 + i * 16 + lr][kq * 8]);
      bh[i] = __builtin_bit_cast(bf16x8, *(const u16x8*)&lds[1][wc * 64 + i * 16 + lr][kq * 8]);
      al[i] = __builtin_bit_cast(bf16x8, *(const u16x8*)&lds[2][wr * 64 + i * 16 + lr][kq * 8]);
      bl[i] = __builtin_bit_cast(bf16x8, *(const u16x8*)&lds[3][wc * 64 + i * 16 + lr][kq * 8]);
    }
    #pragma unroll
    for (int i = 0; i < 4; ++i)
      #pragma unroll
      for (int j = 0; j < 4; ++j) {
        acc[i][j] = __builtin_amdgcn_mfma_f32_16x16x32_bf16(ah[i], bh[j], acc[i][j], 0, 0, 0);
        acc[i][j] = __builtin_amdgcn_mfma_f32_16x16x32_bf16(ah[i], bl[j], acc[i][j], 0, 0, 0);
        acc[i][j] = __builtin_amdgcn_mfma_f32_16x16x32_bf16(al[i], bh[j], acc[i][j], 0, 0, 0);
      }
    __syncthreads();
  }

  #pragma unroll
  for (int i = 0; i < 4; ++i)
    #pragma unroll
    for (int j = 0; j < 4; ++j) {
      float* cp = C + (size_t)(m0 + wr * 64 + i * 16 + kq * 4) * 256 + n0 + wc * 64 + j * 16 + lr;
      #pragma unroll
      for (int qq = 0; qq < 4; ++qq) cp[(size_t)qq * 256] = acc[i][j][qq];
    }
}

// ---------------------------------------------------------------------------
// Mega-prep kernel: [0,512) vproj (8 rows/block, R12) ;
// [512,640) weight transposes (R12) ;
// [640,6784) d1 conv, 128x64 tiles ; [6784,9856) d0 conv, 128x64 tiles.
// Transposed writes are 256B-chunk coalesced.
// ---------------------------------------------------------------------------
struct PrepArgs {
  const float* wsrc[8]; unsigned short* wh[8]; unsigned short* wl[8];
  const float* d1; unsigned short* d1T; unsigned short* d1N;
  const float* d0; unsigned short* d0T_hi; unsigned short* d0N_hi;
  const float* xv; const float* Wvq; const float* Wvk; float* hvV;
};

__global__ __launch_bounds__(256) void prep_all(PrepArgs A) {
  __shared__ __align__(16) char smem[24576];
  const int t = threadIdx.x;
  const int bid = blockIdx.x;

  if (bid < 512) {
    // ---- vproj (np-fp32 exact, 8 rows/block) ----
    float* sx = (float*)smem;
    float* sq = (float*)(smem + 8192);
    float* sk = (float*)(smem + 16384);
    const int r0 = bid * 8;
    const int j = t;
    #pragma unroll
    for (int r = 0; r < 8; ++r) sx[r * 256 + j] = A.xv[(size_t)(r0 + r) * 256 + j];
    __syncthreads();
    float qa[8] = {}, ka[8] = {};
    for (int i = 0; i < 256; ++i) {
      float wq = A.Wvq[i * 256 + j], wk = A.Wvk[i * 256 + j];
      #pragma unroll
      for (int r = 0; r < 8; ++r) {
        qa[r] = __fmaf_rn(sx[r * 256 + i], wq, qa[r]);
        ka[r] = __fmaf_rn(sx[r * 256 + i], wk, ka[r]);
      }
    }
    #pragma unroll
    for (int r = 0; r < 8; ++r) { sq[r * 256 + j] = qa[r]; sk[r * 256 + j] = ka[r]; }
    __syncthreads();
    if (j < 64) {
      const int r = j >> 3, head = j & 7;
      const float* qq = &sq[r * 256 + head * 32];
      const float* kk = &sk[r * 256 + head * 32];
      float s0 = 0.0f, s1 = 0.0f, s2 = 0.0f, s3 = 0.0f;
      #pragma unroll 1
      for (int d = 0; d < 32; d += 4) {
        s0 = __fadd_rn(s0, __fmul_rn(qq[d + 0], kk[d + 0]));
        s1 = __fadd_rn(s1, __fmul_rn(qq[d + 1], kk[d + 1]));
        s2 = __fadd_rn(s2, __fmul_rn(qq[d + 2], kk[d + 2]));
        s3 = __fadd_rn(s3, __fmul_rn(qq[d + 3], kk[d + 3]));
      }
      float p = __fadd_rn(__fadd_rn(s0, s2), __fadd_rn(s1, s3));
      float hval = __fdiv_rn(p, sqrtf(32.0f));
      float inv = __fdiv_rn(1.0f, __fadd_rn(hval, 1e-6f));
      const int row = r0 + r;
      const int b = row / 2048, pos = row - b * 2048;
      A.hvV[((size_t)b * 8 + head) * 2048 + pos] = inv;
    }
  } else if (bid < 640) {
    // ---- weight transposes (R12: hi+lo tiles simultaneously) ----
    const int idx = bid - 512;
    const int w = idx >> 4;
    const int r0 = (idx & 3) * 64, c0 = ((idx >> 2) & 3) * 64;
    const float* src = A.wsrc[w];
    unsigned short* oh = A.wh[w];
    unsigned short* ol = A.wl[w];
    unsigned short (*thi)[72] = (unsigned short (*)[72])smem;
    unsigned short (*tlo)[72] = (unsigned short (*)[72])(smem + 9216);
    #pragma unroll
    for (int a = 0; a < 4; ++a) {
      int idx2 = t + 256 * a;
      int tr = idx2 >> 4, tc = (idx2 & 15) * 4;
      f32x4 v = *(const f32x4*)(src + (size_t)(r0 + tr) * 256 + c0 + tc);
      u16x4 hh = {f2bf(v[0]), f2bf(v[1]), f2bf(v[2]), f2bf(v[3])};
      *(u16x4*)&thi[tr][tc] = hh;
      if (ol) {
        u16x4 ll = {f2bf(v[0] - bf2f(hh[0])), f2bf(v[1] - bf2f(hh[1])),
                    f2bf(v[2] - bf2f(hh[2])), f2bf(v[3] - bf2f(hh[3]))};
        *(u16x4*)&tlo[tr][tc] = ll;
      }
    }
    __syncthreads();
    #pragma unroll
    for (int a = 0; a < 2; ++a) {
      int idx2 = t + 256 * a;
      int orow = idx2 >> 3, oc = (idx2 & 7) * 8;
      u16x8 vh;
      #pragma unroll
      for (int j = 0; j < 8; ++j) vh[j] = thi[oc + j][orow];
      *(u16x8*)(oh + (size_t)(c0 + orow) * 256 + r0 + oc) = vh;
      if (ol) {
        u16x8 vl;
        #pragma unroll
        for (int j = 0; j < 8; ++j) vl[j] = tlo[oc + j][orow];
        *(u16x8*)(ol + (size_t)(c0 + orow) * 256 + r0 + oc) = vl;
      }
    }
  } else if (bid < 6784) {
    // ---- d1: [2][4096][6144] -> d1N + d1T, 128x64 tile ----
    const int idx = bid - 640;
    const int x = idx & 31;            // 32 face tiles of 128
    const int rem = idx >> 5;
    const int y = rem % 96;            // 96 edge tiles of 64
    const int b = rem / 96;
    const int r0 = x * 128, c0 = y * 64;
    unsigned short (*tile)[72] = (unsigned short (*)[72])smem;  // [128][72]
    #pragma unroll
    for (int a = 0; a < 8; ++a) {
      int idx2 = t + 256 * a;
      int tr = idx2 >> 4, tc = (idx2 & 15) * 4;
      size_t off = ((size_t)b * 4096 + r0 + tr) * 6144 + c0 + tc;
      f32x4 v = *(const f32x4*)(A.d1 + off);
      u16x4 hh = {f2bf(v[0]), f2bf(v[1]), f2bf(v[2]), f2bf(v[3])};
      *(u16x4*)&tile[tr][tc] = hh;
      *(u16x4*)(A.d1N + off) = hh;
    }
    __syncthreads();
    #pragma unroll
    for (int a = 0; a < 4; ++a) {
      int idx2 = t + 256 * a;
      int orow = idx2 >> 4, oc8 = (idx2 & 15) * 8;   // orow<64 cols, oc8<128 rows
      u16x8 vh;
      #pragma unroll
      for (int j = 0; j < 8; ++j) vh[j] = tile[oc8 + j][orow];
      *(u16x8*)(A.d1T + ((size_t)b * 6144 + c0 + orow) * 4096 + r0 + oc8) = vh;
    }
  } else {
    // ---- d0: [2][6144][2048] -> d0N + d0T, 128x64 tile ----
    const int idx = bid - 6784;
    const int x = idx % 48;            // 48 edge tiles of 128
    const int rem = idx / 48;
    const int y = rem & 31;            // 32 vertex tiles of 64
    const int b = rem >> 5;
    const int r0 = x * 128, c0 = y * 64;
    unsigned short (*tile)[72] = (unsigned short (*)[72])smem;
    #pragma unroll
    for (int a = 0; a < 8; ++a) {
      int idx2 = t + 256 * a;
      int tr = idx2 >> 4, tc = (idx2 & 15) * 4;
      size_t off = ((size_t)b * 6144 + r0 + tr) * 2048 + c0 + tc;
      f32x4 v = *(const f32x4*)(A.d0 + off);
      u16x4 hh = {f2bf(v[0]), f2bf(v[1]), f2bf(v[2]), f2bf(v[3])};
      *(u16x4*)&tile[tr][tc] = hh;
      *(u16x4*)(A.d0N_hi + off) = hh;
    }
    __syncthreads();
    #pragma unroll
    for (int a = 0; a < 4; ++a) {
      int idx2 = t + 256 * a;
      int orow = idx2 >> 4, oc8 = (idx2 & 15) * 8;
      u16x8 vh;
      #pragma unroll
      for (int j = 0; j < 8; ++j) vh[j] = tile[oc8 + j][orow];
      *(u16x8*)(A.d0T_hi + ((size_t)b * 2048 + c0 + orow) * 6144 + r0 + oc8) = vh;
    }
  }
}

// ---------------------------------------------------------------------------
// Fused eVT (unscaled bf16) + Y0T (scaled bf16) from P1 cols 512..767.
// ---------------------------------------------------------------------------
__global__ __launch_bounds__(256) void xpose_ev(
    const float* __restrict__ P1, unsigned short* __restrict__ eVT,
    unsigned short* __restrict__ yhi, const float* __restrict__ hE) {
  __shared__ unsigned short te[64][72], th[64][72];
  const int b = blockIdx.z;
  const int r0 = blockIdx.x * 64, c0 = blockIdx.y * 64;
  const int t = threadIdx.x;
  #pragma unroll
  for (int a = 0; a < 4; ++a) {
    int idx = t + 256 * a;
    int tr = idx >> 4, tc = (idx & 15) * 4;
    f32x4 v = *(const f32x4*)(P1 + ((size_t)b * 6144 + r0 + tr) * 1280 + 512 + c0 + tc);
    u16x4 eh = {f2bf(v[0]), f2bf(v[1]), f2bf(v[2]), f2bf(v[3])};
    *(u16x4*)&te[tr][tc] = eh;
    float s = hE[((size_t)b * 8 + ((c0 + tc) >> 5)) * 6144 + r0 + tr];
    f32x4 y = v * s;
    u16x4 hh = {f2bf(y[0]), f2bf(y[1]), f2bf(y[2]), f2bf(y[3])};
    *(u16x4*)&th[tr][tc] = hh;
  }
  __syncthreads();
  #pragma unroll
  for (int a = 0; a < 2; ++a) {
    int idx = t + 256 * a;
    int orow = idx >> 3, oc = (idx & 7) * 8;
    u16x8 ve, vh;
    #pragma unroll
    for (int j = 0; j < 8; ++j) {
      ve[j] = te[oc + j][orow];
      vh[j] = th[oc + j][orow];
    }
    size_t o = ((size_t)b * 256 + c0 + orow) * 6144 + r0 + oc;
    *(u16x8*)(eVT + o) = ve;
    *(u16x8*)(yhi + o) = vh;
  }
}

// ---------------------------------------------------------------------------
// Merged rsc_cvt (sum S slabs ascending, scale, cvt bf16).
// ---------------------------------------------------------------------------
static __device__ __forceinline__ void rsc_body(
    const float* in, unsigned short* out_hi, const float* h,
    int S, int R, int P, int bid, int nblk) {
  const long long qP = P >> 2;
  const long long nq = 2LL * R * qP;
  long long i = (long long)bid * 256 + threadIdx.x;
  const long long stride = (long long)nblk * 256;
  for (; i < nq; i += stride) {
    long long b = i / (R * qP);
    long long rem = i - b * (R * qP);
    int row = (int)(rem / qP);
    long long qc = rem - (long long)row * qP;
    const f32x4* base = (const f32x4*)in + ((b * S) * R + row) * qP + qc;
    f32x4 v = base[0];
    for (int s = 1; s < S; ++s) v += base[(long long)s * R * qP];
    v *= *(const f32x4*)(h + ((size_t)b * 8 + (row >> 5)) * P + (qc << 2));
    u16x4 hh = {f2bf(v[0]), f2bf(v[1]), f2bf(v[2]), f2bf(v[3])};
    ((u16x4*)out_hi)[i] = hh;
  }
}

__global__ void rsc2(const float* in1, unsigned short* o1h, const float* hF,
                     const float* in3, unsigned short* o3h, const float* hV) {
  if (blockIdx.x < 2048)
    rsc_body(in1, o1h, hF, 3, 256, 4096, blockIdx.x, 2048);
  else
    rsc_body(in3, o3h, hV, 6, 256, 2048, blockIdx.x - 2048, 1024);
}

// ---------------------------------------------------------------------------
// Merged hval dots: [0,3072) e/einv pairs from P1; [3072,5120) f pair from P3.
// ---------------------------------------------------------------------------
__global__ __launch_bounds__(256) void dots(
    const float* __restrict__ P1, float* __restrict__ hE, float* __restrict__ hEi,
    const float* __restrict__ P3, float* __restrict__ hF) {
  const int wv = threadIdx.x >> 6, lane = threadIdx.x & 63;
  if (blockIdx.x < 3072) {
    const int row = blockIdx.x * 4 + wv;
    const float* base = P1 + (size_t)row * 1280 + lane * 4;
    f32x4 qv = *(const f32x4*)(base);
    f32x4 kv = *(const f32x4*)(base + 256);
    float p = qv[0] * kv[0] + qv[1] * kv[1] + qv[2] * kv[2] + qv[3] * kv[3];
    p += __shfl_xor(p, 1); p += __shfl_xor(p, 2); p += __shfl_xor(p, 4);
    f32x4 q2 = *(const f32x4*)(base + 768);
    f32x4 k2 = *(const f32x4*)(base + 1024);
    float p2 = q2[0] * k2[0] + q2[1] * k2[1] + q2[2] * k2[2] + q2[3] * k2[3];
    p2 += __shfl_xor(p2, 1); p2 += __shfl_xor(p2, 2); p2 += __shfl_xor(p2, 4);
    if ((lane & 7) == 0) {
      const int head = lane >> 3;
      const int b = row / 6144, pos = row % 6144;
      hE[((size_t)b * 8 + head) * 6144 + pos] = p * 0.17677669529663687f;
      hEi[((size_t)b * 8 + head) * 6144 + pos] = p2 * 0.17677669529663687f;
    }
  } else {
    const int row = (blockIdx.x - 3072) * 4 + wv;
    const float* base = P3 + (size_t)row * 512 + lane * 4;
    f32x4 qv = *(const f32x4*)(base);
    f32x4 kv = *(const f32x4*)(base + 256);
    float p = qv[0] * kv[0] + qv[1] * kv[1] + qv[2] * kv[2] + qv[3] * kv[3];
    p += __shfl_xor(p, 1); p += __shfl_xor(p, 2); p += __shfl_xor(p, 4);
    if ((lane & 7) == 0) {
      const int head = lane >> 3;
      const int b = row / 4096, pos = row % 4096;
      hF[((size_t)b * 8 + head) * 4096 + pos] = p * 0.17677669529663687f;
    }
  }
}

// ---------------------------------------------------------------------------
extern "C" void kernel_launch(void* const* d_in, const int* in_sizes, int n_in,
                              void* d_out, int out_size, void* d_ws, size_t ws_size,
                              hipStream_t stream) {
  const float* x_v = (const float*)d_in[0];
  const float* x_e = (const float*)d_in[1];
  const float* x_f = (const float*)d_in[2];
  const float* d0  = (const float*)d_in[3];   // (2, 6144, 2048)
  const float* d1  = (const float*)d_in[4];   // (2, 4096, 6144)
  float* out = (float*)d_out;

  const int NV = 2048, ME = 6144, KF = 4096;

  char* ws = (char*)d_ws;
  size_t o = 0;
  auto alloc = [&](size_t bytes) { size_t r = o; o = (o + bytes + 255) & ~255ULL; return r; };

  unsigned short* Wcat5_hi = (unsigned short*)(ws + alloc(1280 * 256 * 2));
  unsigned short* Wcat5_lo = (unsigned short*)(ws + alloc(1280 * 256 * 2));
  unsigned short* W3_hi = (unsigned short*)(ws + alloc(512 * 256 * 2));
  unsigned short* Wo_hi = (unsigned short*)(ws + alloc(256 * 256 * 2));
  unsigned short* Wo_lo = (unsigned short*)(ws + alloc(256 * 256 * 2));
  float* pHvE  = (float*)(ws + alloc(2 * 8 * ME * 4));
  float* pHvEi = (float*)(ws + alloc(2 * 8 * ME * 4));
  float* pHvF  = (float*)(ws + alloc(2 * 8 * KF * 4));
  float* pHvV  = (float*)(ws + alloc(2 * 8 * NV * 4));
  unsigned short* d1T_hi = (unsigned short*)(ws + alloc((size_t)2 * ME * KF * 2));
  unsigned short* d1N_hi = (unsigned short*)(ws + alloc((size_t)2 * KF * ME * 2));
  unsigned short* d0T_hi = (unsigned short*)(ws + alloc((size_t)2 * NV * ME * 2));
  unsigned short* d0N_hi = (unsigned short*)(ws + alloc((size_t)2 * ME * NV * 2));
  unsigned short* eVT_hi = (unsigned short*)(ws + alloc((size_t)2 * 256 * ME * 2));
  unsigned short* Y0T_hi = (unsigned short*)(ws + alloc((size_t)2 * 256 * ME * 2));
  unsigned short* T1sT_hi = (unsigned short*)(ws + alloc((size_t)2 * 256 * KF * 2));
  unsigned short* T3sT_hi = (unsigned short*)(ws + alloc((size_t)2 * 256 * NV * 2));
  float* pP1 = (float*)(ws + alloc((size_t)12288 * 1280 * 4));
  float* pP3 = (float*)(ws + alloc((size_t)8192 * 512 * 4));
  float* pTp1 = (float*)(ws + alloc((size_t)2 * 3 * 256 * KF * 4));   // T1^T slabs
  float* pTp3 = (float*)(ws + alloc((size_t)2 * 6 * 256 * NV * 4));   // T3^T slabs
  float* pT2p = (float*)(ws + alloc((size_t)2 * 2 * ME * 256 * 4));
  float* pT4p = (float*)(ws + alloc((size_t)2 * 2 * ME * 256 * 4));

  dim3 blk(256);

  // --- mega-prep: vproj + weight transposes + d1/d0 conversions ---
  PrepArgs pa;
  pa.wsrc[0] = (const float*)d_in[7];  pa.wh[0] = Wcat5_hi;          pa.wl[0] = Wcat5_lo;
  pa.wsrc[1] = (const float*)d_in[8];  pa.wh[1] = Wcat5_hi + 65536;  pa.wl[1] = Wcat5_lo + 65536;
  pa.wsrc[2] = (const float*)d_in[11]; pa.wh[2] = Wcat5_hi + 131072; pa.wl[2] = Wcat5_lo + 131072;
  pa.wsrc[3] = (const float*)d_in[9];  pa.wh[3] = Wcat5_hi + 196608; pa.wl[3] = Wcat5_lo + 196608;
  pa.wsrc[4] = (const float*)d_in[10]; pa.wh[4] = Wcat5_hi + 262144; pa.wl[4] = Wcat5_lo + 262144;
  pa.wsrc[5] = (const float*)d_in[12]; pa.wh[5] = W3_hi;             pa.wl[5] = nullptr;
  pa.wsrc[6] = (const float*)d_in[13]; pa.wh[6] = W3_hi + 65536;     pa.wl[6] = nullptr;
  pa.wsrc[7] = (const float*)d_in[14]; pa.wh[7] = Wo_hi;             pa.wl[7] = Wo_lo;
  pa.d1 = d1; pa.d1T = d1T_hi; pa.d1N = d1N_hi;
  pa.d0 = d0; pa.d0T_hi = d0T_hi; pa.d0N_hi = d0N_hi;
  pa.xv = x_v; pa.Wvq = (const float*)d_in[5]; pa.Wvk = (const float*)d_in[6];
  pa.hvV = pHvV;
  prep_all<<<9856, blk, 0, stream>>>(pa);

  // --- projections (P1 + P3 in one launch) ---
  proj_dual<<<1216, blk, 0, stream>>>(x_e, Wcat5_hi, Wcat5_lo, pP1, x_f, W3_hi, pP3);
  dots<<<5120, blk, 0, stream>>>(pP1, pHvE, pHvEi, pP3, pHvF);
  xpose_ev<<<dim3(96, 4, 2), blk, 0, stream>>>(pP1, eVT_hi, Y0T_hi, pHvE);

  // --- T1 + T3 in one launch ---
  GJob jT1, jT3;
  jT1.Ah = eVT_hi; jT1.Bh = d1N_hi; jT1.C = pTp1;
  jT1.K = ME; jT1.ldA = ME; jT1.ldB = ME; jT1.S = 3; jT1.gx = 2; jT1.gy = 32;
  jT1.sA = 256LL * ME; jT1.sB = (long long)KF * ME; jT1.sC = 256LL * KF;
  jT3.Ah = Y0T_hi; jT3.Bh = d0T_hi; jT3.C = pTp3;
  jT3.K = ME; jT3.ldA = ME; jT3.ldB = ME; jT3.S = 6; jT3.gx = 2; jT3.gy = 16;
  jT3.sA = 256LL * ME; jT3.sB = (long long)NV * ME; jT3.sC = 256LL * NV;
  gemm_dual<true><<<768, blk, 0, stream>>>(jT1, jT3, 384);

  // --- reductions + scale + cvt ---
  rsc2<<<3072, blk, 0, stream>>>(pTp1, T1sT_hi, pHvF, pTp3, T3sT_hi, pHvV);

  // --- T2 + T4 in one launch ---
  GJob jT2, jT4;
  jT2.Ah = d1T_hi; jT2.Bh = T1sT_hi; jT2.C = pT2p;
  jT2.K = KF; jT2.ldA = KF; jT2.ldB = KF; jT2.S = 2; jT2.gx = 48; jT2.gy = 2;
  jT2.sA = (long long)ME * KF; jT2.sB = 256LL * KF; jT2.sC = (long long)ME * 256;
  jT4.Ah = d0N_hi; jT4.Bh = T3sT_hi; jT4.C = pT4p;
  jT4.K = NV; jT4.ldA = NV; jT4.ldB = NV; jT4.S = 2; jT4.gx = 48; jT4.gy = 2;
  jT4.sA = (long long)ME * NV; jT4.sB = 256LL * NV; jT4.sC = (long long)ME * 256;
  gemm_dual<false><<<768, blk, 0, stream>>>(jT2, jT4, 384);

  // --- fused combine + output projection ---
  gemm_out<<<dim3(96, 2, 1), blk, 0, stream>>>(pT2p, pT4p, pHvEi, Wo_hi, Wo_lo, out);
}

// Round 15
// 391.813 us; speedup vs baseline: 1.1148x; 1.0131x over previous
//
#include <hip/hip_runtime.h>
#include <hip/hip_bf16.h>
#include <cstdint>
#include <cstddef>

// ---------------------------------------------------------------------------
// MeshMultiHeadHodgeLaplaceAttention  (b=2, n=2048, m=6144, k=4096, D=256, H=8)
//
//   up:   T1 = d_1 @ eV ; *f_hval ; T2 = d_1^T @ T1s ; (*einv_hval in combine)
//   down: Y0 = eV*e_hval ; T3 = d_0^T @ Y0 ; *1/(v_hval+eps) ; T4 = d_0 @ T3s
//   out = (T2*einv_hval + T4) @ W_o
//
// Precision: v_hval replicates numpy fp32 bit-exactly; P1 + output GEMM
// split-bf16; T1..T4 plain bf16 (validated R10-R14, absmax=256).
//
// R15: LDS transpose tiles padded 72 -> 74 u16/row (37 dwords): the 8-row
// oc-step becomes 296 = 8 mod 32 -> 2-way bank aliasing (free) instead of
// 8-way (2.9x). Writes split into u16x2 pairs (4B-aligned odd rows).
// Applied in prep_all (weights/d1/d0) and xpose_ev. Rest identical to R14.
// ---------------------------------------------------------------------------

typedef __attribute__((ext_vector_type(4))) float f32x4;
typedef __attribute__((ext_vector_type(2))) unsigned short u16x2;
typedef __attribute__((ext_vector_type(4))) unsigned short u16x4;
typedef __attribute__((ext_vector_type(8))) unsigned short u16x8;
typedef __attribute__((ext_vector_type(8))) __bf16 bf16x8;

static __device__ __forceinline__ unsigned short f2bf(float f) {
  uint32_t u = __builtin_bit_cast(uint32_t, f);
  uint32_t r = (u + 0x7FFFu + ((u >> 16) & 1u)) >> 16;  // RNE
  return (unsigned short)r;
}
static __device__ __forceinline__ float bf2f(unsigned short h) {
  return __builtin_bit_cast(float, (uint32_t)h << 16);
}
// store u16x4 as two 4B-aligned u16x2 (rows may be only 4B-aligned)
static __device__ __forceinline__ void st4(unsigned short* p, u16x4 v) {
  *(u16x2*)p = u16x2{v[0], v[1]};
  *(u16x2*)(p + 2) = u16x2{v[2], v[3]};
}

// ---------------------------------------------------------------------------
// Dual-job plain-bf16 GEMM. Per job: C[M x gy*128] = A(bf16 [M][K]) *
// B(bf16 [N][K]); split-K z = batch*S + split; 128x128 tile, reg-prefetch.
// ---------------------------------------------------------------------------
struct GJob {
  const unsigned short* Ah; const unsigned short* Bh; float* C;
  int K, ldA, ldB, S, gx, gy;
  long long sA, sB, sC;
};

template <bool XFAST>
__global__ __launch_bounds__(256) void gemm_dual(GJob j0, GJob j1, int nb0) {
  const bool first = (int)blockIdx.x < nb0;
  GJob J = first ? j0 : j1;
  const int b = first ? blockIdx.x : blockIdx.x - nb0;
  const int per = J.gx * J.gy;
  const int z = b / per;
  const int wid = b - z * per;
  const int batch = z / J.S, split = z - batch * J.S;
  const unsigned short* Ah = J.Ah + (long long)batch * J.sA;
  const unsigned short* Bh = J.Bh + (long long)batch * J.sB;
  float* C = J.C + (long long)z * J.sC;

  const int nwg = per;
  const int q = nwg >> 3, r = nwg & 7;
  const int xcd = wid & 7, posn = wid >> 3;
  const int swz = (xcd < r ? xcd * (q + 1) : r * (q + 1) + (xcd - r) * q) + posn;
  int mt, nt;
  if constexpr (XFAST) { mt = swz % J.gx; nt = swz / J.gx; }
  else                 { mt = swz / J.gy; nt = swz - mt * J.gy; }
  const int m0 = mt * 128, n0 = nt * 128;
  const int NC = J.gy << 7;
  const int kLen = J.K / J.S, k0base = split * kLen;

  __shared__ unsigned short lds[2][128][40];

  const int t = threadIdx.x;
  const int w4 = t >> 6, lane = t & 63;
  const int wr = w4 >> 1, wc = w4 & 1;
  const int lr = lane & 15, kq = lane >> 4;
  const int rowV = t >> 2, c8V = (t & 3) * 8;

  u16x8 rA[2], rB[2];
  auto LOAD = [&](int kb) {
    #pragma unroll
    for (int a = 0; a < 2; ++a) {
      rA[a] = *(const u16x8*)(Ah + (size_t)(m0 + rowV + 64 * a) * J.ldA + kb + c8V);
      rB[a] = *(const u16x8*)(Bh + (size_t)(n0 + rowV + 64 * a) * J.ldB + kb + c8V);
    }
  };
  auto STORE = [&]() {
    #pragma unroll
    for (int a = 0; a < 2; ++a) {
      *(u16x8*)&lds[0][rowV + 64 * a][c8V] = rA[a];
      *(u16x8*)&lds[1][rowV + 64 * a][c8V] = rB[a];
    }
  };

  f32x4 acc[4][4] = {};
  LOAD(k0base);
  for (int kk = 0; kk < kLen; kk += 32) {
    STORE();
    __syncthreads();
    if (kk + 32 < kLen) LOAD(k0base + kk + 32);

    bf16x8 ah[4], bh[4];
    #pragma unroll
    for (int i = 0; i < 4; ++i) {
      ah[i] = __builtin_bit_cast(bf16x8, *(const u16x8*)&lds[0][wr * 64 + i * 16 + lr][kq * 8]);
      bh[i] = __builtin_bit_cast(bf16x8, *(const u16x8*)&lds[1][wc * 64 + i * 16 + lr][kq * 8]);
    }
    #pragma unroll
    for (int i = 0; i < 4; ++i)
      #pragma unroll
      for (int j = 0; j < 4; ++j)
        acc[i][j] = __builtin_amdgcn_mfma_f32_16x16x32_bf16(ah[i], bh[j], acc[i][j], 0, 0, 0);
    __syncthreads();
  }

  #pragma unroll
  for (int i = 0; i < 4; ++i)
    #pragma unroll
    for (int j = 0; j < 4; ++j) {
      float* cp = C + (size_t)(m0 + wr * 64 + i * 16 + kq * 4) * NC + n0 + wc * 64 + j * 16 + lr;
      #pragma unroll
      for (int qq = 0; qq < 4; ++qq) cp[(size_t)qq * NC] = acc[i][j][qq];
    }
}

// ---------------------------------------------------------------------------
// Projection GEMM body (K=256): C[M x gy*128] = A fp32 [M][256] (cvt in
// staging) * B bf16 hi(/lo) [N][256].
// ---------------------------------------------------------------------------
template <bool SPLIT>
static __device__ void proj_body(char* smem, int wid, int gx, int gy,
                                 const float* __restrict__ Af,
                                 const unsigned short* __restrict__ Bh,
                                 const unsigned short* __restrict__ Bl,
                                 float* __restrict__ C) {
  const int nwg = gx * gy;
  const int q = nwg >> 3, r = nwg & 7;
  const int xcd = wid & 7, posn = wid >> 3;
  const int swz = (xcd < r ? xcd * (q + 1) : r * (q + 1) + (xcd - r) * q) + posn;
  const int mt = swz / gy;
  const int m0 = mt * 128, n0 = (swz - mt * gy) * 128;
  const int NC = gy << 7;

  typedef unsigned short ldsrow[128][40];
  ldsrow* lds = (ldsrow*)smem;

  const int t = threadIdx.x;
  const int w4 = t >> 6, lane = t & 63;
  const int wr = w4 >> 1, wc = w4 & 1;
  const int lr = lane & 15, kq = lane >> 4;
  const int rowA8 = t >> 3, qdA = (t & 7) * 4;
  const int rowV = t >> 2, c8V = (t & 3) * 8;

  f32x4 rAf[4];
  u16x8 rBh[2], rBl[2];

  auto LOAD = [&](int kb) {
    #pragma unroll
    for (int a = 0; a < 4; ++a)
      rAf[a] = *(const f32x4*)(Af + (size_t)(m0 + rowA8 + 32 * a) * 256 + kb + qdA);
    #pragma unroll
    for (int a = 0; a < 2; ++a) {
      rBh[a] = *(const u16x8*)(Bh + (size_t)(n0 + rowV + 64 * a) * 256 + kb + c8V);
      if constexpr (SPLIT)
        rBl[a] = *(const u16x8*)(Bl + (size_t)(n0 + rowV + 64 * a) * 256 + kb + c8V);
    }
  };
  auto STORE = [&]() {
    #pragma unroll
    for (int a = 0; a < 4; ++a) {
      f32x4 v = rAf[a];
      u16x4 h = {f2bf(v[0]), f2bf(v[1]), f2bf(v[2]), f2bf(v[3])};
      *(u16x4*)&lds[0][rowA8 + 32 * a][qdA] = h;
      if constexpr (SPLIT) {
        u16x4 l = {f2bf(v[0] - bf2f(h[0])), f2bf(v[1] - bf2f(h[1])),
                   f2bf(v[2] - bf2f(h[2])), f2bf(v[3] - bf2f(h[3]))};
        *(u16x4*)&lds[2][rowA8 + 32 * a][qdA] = l;
      }
    }
    #pragma unroll
    for (int a = 0; a < 2; ++a) {
      *(u16x8*)&lds[1][rowV + 64 * a][c8V] = rBh[a];
      if constexpr (SPLIT) *(u16x8*)&lds[3][rowV + 64 * a][c8V] = rBl[a];
    }
  };

  f32x4 acc[4][4] = {};
  LOAD(0);
  for (int kk = 0; kk < 256; kk += 32) {
    STORE();
    __syncthreads();
    if (kk + 32 < 256) LOAD(kk + 32);

    bf16x8 ah[4], bh[4], al[4], bl[4];
    #pragma unroll
    for (int i = 0; i < 4; ++i) {
      ah[i] = __builtin_bit_cast(bf16x8, *(const u16x8*)&lds[0][wr * 64 + i * 16 + lr][kq * 8]);
      bh[i] = __builtin_bit_cast(bf16x8, *(const u16x8*)&lds[1][wc * 64 + i * 16 + lr][kq * 8]);
      if constexpr (SPLIT) {
        al[i] = __builtin_bit_cast(bf16x8, *(const u16x8*)&lds[2][wr * 64 + i * 16 + lr][kq * 8]);
        bl[i] = __builtin_bit_cast(bf16x8, *(const u16x8*)&lds[3][wc * 64 + i * 16 + lr][kq * 8]);
      }
    }
    #pragma unroll
    for (int i = 0; i < 4; ++i)
      #pragma unroll
      for (int j = 0; j < 4; ++j) {
        acc[i][j] = __builtin_amdgcn_mfma_f32_16x16x32_bf16(ah[i], bh[j], acc[i][j], 0, 0, 0);
        if constexpr (SPLIT) {
          acc[i][j] = __builtin_amdgcn_mfma_f32_16x16x32_bf16(ah[i], bl[j], acc[i][j], 0, 0, 0);
          acc[i][j] = __builtin_amdgcn_mfma_f32_16x16x32_bf16(al[i], bh[j], acc[i][j], 0, 0, 0);
        }
      }
    __syncthreads();
  }

  #pragma unroll
  for (int i = 0; i < 4; ++i)
    #pragma unroll
    for (int j = 0; j < 4; ++j) {
      float* cp = C + (size_t)(m0 + wr * 64 + i * 16 + kq * 4) * NC + n0 + wc * 64 + j * 16 + lr;
      #pragma unroll
      for (int qq = 0; qq < 4; ++qq) cp[(size_t)qq * NC] = acc[i][j][qq];
    }
}

// P1 (split, 960 blocks) + P3 (plain, 256 blocks) in one launch.
__global__ __launch_bounds__(256) void proj_dual(
    const float* __restrict__ xe, const unsigned short* __restrict__ W5h,
    const unsigned short* __restrict__ W5l, float* __restrict__ P1,
    const float* __restrict__ xf, const unsigned short* __restrict__ W3h,
    float* __restrict__ P3) {
  __shared__ __align__(16) unsigned short lds[4][128][40];
  if ((int)blockIdx.x < 960)
    proj_body<true>((char*)lds, blockIdx.x, 96, 10, xe, W5h, W5l, P1);
  else
    proj_body<false>((char*)lds, blockIdx.x - 960, 64, 4, xf, W3h, nullptr, P3);
}

// ---------------------------------------------------------------------------
// Output GEMM with fused combine: A[r][c] = (T4p 2-slab sum) +
// (T2p 2-slab sum)*einv_hval;  C = A @ W_o (split hi/lo). M=12288,N=256,K=256.
// ---------------------------------------------------------------------------
__global__ __launch_bounds__(256) void gemm_out(
    const float* __restrict__ T2p, const float* __restrict__ T4p,
    const float* __restrict__ hEi, const unsigned short* __restrict__ Bh,
    const unsigned short* __restrict__ Bl, float* __restrict__ C) {
  const int gx = gridDim.x, gy = gridDim.y;
  const int nwg = gx * gy;
  const int wid = blockIdx.x + gx * blockIdx.y;
  const int q = nwg >> 3, r = nwg & 7;
  const int xcd = wid & 7, posn = wid >> 3;
  const int swz = (xcd < r ? xcd * (q + 1) : r * (q + 1) + (xcd - r) * q) + posn;
  const int mt = swz / gy;
  const int m0 = mt * 128, n0 = (swz - mt * gy) * 128;

  __shared__ unsigned short lds[4][128][40];
  const int t = threadIdx.x;
  const int w4 = t >> 6, lane = t & 63;
  const int wr = w4 >> 1, wc = w4 & 1;
  const int lr = lane & 15, kq = lane >> 4;
  const long long slab = 6144LL * 256;

  f32x4 acc[4][4] = {};

  for (int kb = 0; kb < 256; kb += 32) {
    #pragma unroll
    for (int a = 0; a < 4; ++a) {
      int idx = t + 256 * a;
      int row = idx >> 3, qd = (idx & 7) * 4;
      int rg = m0 + row;
      int b = rg >= 6144;
      int pos = rg - b * 6144;
      int ck = kb + qd;
      float s = hEi[((size_t)b * 8 + (ck >> 5)) * 6144 + pos];
      const float* b2 = T2p + ((long long)(b * 2) * 6144 + pos) * 256 + ck;
      const float* b4 = T4p + ((long long)(b * 2) * 6144 + pos) * 256 + ck;
      f32x4 t2 = *(const f32x4*)b2 + *(const f32x4*)(b2 + slab);
      f32x4 t4 = *(const f32x4*)b4 + *(const f32x4*)(b4 + slab);
      f32x4 v = t4 + t2 * s;
      u16x4 h = {f2bf(v[0]), f2bf(v[1]), f2bf(v[2]), f2bf(v[3])};
      *(u16x4*)&lds[0][row][qd] = h;
      u16x4 l = {f2bf(v[0] - bf2f(h[0])), f2bf(v[1] - bf2f(h[1])),
                 f2bf(v[2] - bf2f(h[2])), f2bf(v[3] - bf2f(h[3]))};
      *(u16x4*)&lds[2][row][qd] = l;
    }
    #pragma unroll
    for (int a = 0; a < 2; ++a) {
      int idx = t + 256 * a;
      int row = idx >> 2, c8 = (idx & 3) * 8;
      *(u16x8*)&lds[1][row][c8] = *(const u16x8*)(Bh + (size_t)(n0 + row) * 256 + kb + c8);
      *(u16x8*)&lds[3][row][c8] = *(const u16x8*)(Bl + (size_t)(n0 + row) * 256 + kb + c8);
    }
    __syncthreads();

    bf16x8 ah[4], bh[4], al[4], bl[4];
    #pragma unroll
    for (int i = 0; i < 4; ++i) {
      ah[i] = __builtin_bit_cast(bf16x8, *(const u16x8*)&lds[0][wr * 64 + i * 16 + lr][kq * 8]);
      bh[i] = __builtin_bit_cast(bf16x8, *(const u16x8*)&lds[1][wc * 64 + i * 16 + lr][kq * 8]);
      al[i] = __builtin_bit_cast(bf16x8, *(const u16x8*)&lds[2][wr * 64 + i * 16 + lr][kq * 8]);
      bl[i] = __builtin_bit_cast(bf16x8, *(const u16x8*)&lds[3][wc * 64 + i * 16 + lr][kq * 8]);
    }
    #pragma unroll
    for (int i = 0; i < 4; ++i)
      #pragma unroll
      for (int j = 0; j < 4; ++j) {
        acc[i][j] = __builtin_amdgcn_mfma_f32_16x16x32_bf16(ah[i], bh[j], acc[i][j], 0, 0, 0);
        acc[i][j] = __builtin_amdgcn_mfma_f32_16x16x32_bf16(ah[i], bl[j], acc[i][j], 0, 0, 0);
        acc[i][j] = __builtin_amdgcn_mfma_f32_16x16x32_bf16(al[i], bh[j], acc[i][j], 0, 0, 0);
      }
    __syncthreads();
  }

  #pragma unroll
  for (int i = 0; i < 4; ++i)
    #pragma unroll
    for (int j = 0; j < 4; ++j) {
      float* cp = C + (size_t)(m0 + wr * 64 + i * 16 + kq * 4) * 256 + n0 + wc * 64 + j * 16 + lr;
      #pragma unroll
      for (int qq = 0; qq < 4; ++qq) cp[(size_t)qq * 256] = acc[i][j][qq];
    }
}

// ---------------------------------------------------------------------------
// Mega-prep kernel: [0,512) vproj ; [512,640) weight transposes ;
// [640,12928) d1 conv ; [12928,19072) d0 conv.  64x64 tiles with 74-u16 row
// stride (2-way bank aliasing on the transposed gather).
// ---------------------------------------------------------------------------
struct PrepArgs {
  const float* wsrc[8]; unsigned short* wh[8]; unsigned short* wl[8];
  const float* d1; unsigned short* d1T; unsigned short* d1N;
  const float* d0; unsigned short* d0T_hi; unsigned short* d0N_hi;
  const float* xv; const float* Wvq; const float* Wvk; float* hvV;
};

__global__ __launch_bounds__(256) void prep_all(PrepArgs A) {
  __shared__ __align__(16) char smem[24576];
  const int t = threadIdx.x;
  const int bid = blockIdx.x;

  if (bid < 512) {
    // ---- vproj (np-fp32 exact, 8 rows/block) ----
    float* sx = (float*)smem;
    float* sq = (float*)(smem + 8192);
    float* sk = (float*)(smem + 16384);
    const int r0 = bid * 8;
    const int j = t;
    #pragma unroll
    for (int r = 0; r < 8; ++r) sx[r * 256 + j] = A.xv[(size_t)(r0 + r) * 256 + j];
    __syncthreads();
    float qa[8] = {}, ka[8] = {};
    for (int i = 0; i < 256; ++i) {
      float wq = A.Wvq[i * 256 + j], wk = A.Wvk[i * 256 + j];
      #pragma unroll
      for (int r = 0; r < 8; ++r) {
        qa[r] = __fmaf_rn(sx[r * 256 + i], wq, qa[r]);
        ka[r] = __fmaf_rn(sx[r * 256 + i], wk, ka[r]);
      }
    }
    #pragma unroll
    for (int r = 0; r < 8; ++r) { sq[r * 256 + j] = qa[r]; sk[r * 256 + j] = ka[r]; }
    __syncthreads();
    if (j < 64) {
      const int r = j >> 3, head = j & 7;
      const float* qq = &sq[r * 256 + head * 32];
      const float* kk = &sk[r * 256 + head * 32];
      float s0 = 0.0f, s1 = 0.0f, s2 = 0.0f, s3 = 0.0f;
      #pragma unroll 1
      for (int d = 0; d < 32; d += 4) {
        s0 = __fadd_rn(s0, __fmul_rn(qq[d + 0], kk[d + 0]));
        s1 = __fadd_rn(s1, __fmul_rn(qq[d + 1], kk[d + 1]));
        s2 = __fadd_rn(s2, __fmul_rn(qq[d + 2], kk[d + 2]));
        s3 = __fadd_rn(s3, __fmul_rn(qq[d + 3], kk[d + 3]));
      }
      float p = __fadd_rn(__fadd_rn(s0, s2), __fadd_rn(s1, s3));
      float hval = __fdiv_rn(p, sqrtf(32.0f));
      float inv = __fdiv_rn(1.0f, __fadd_rn(hval, 1e-6f));
      const int row = r0 + r;
      const int b = row / 2048, pos = row - b * 2048;
      A.hvV[((size_t)b * 8 + head) * 2048 + pos] = inv;
    }
  } else if (bid < 640) {
    // ---- weight transposes (hi + lo tiles, 74-stride) ----
    const int idx = bid - 512;
    const int w = idx >> 4;
    const int r0 = (idx & 3) * 64, c0 = ((idx >> 2) & 3) * 64;
    const float* src = A.wsrc[w];
    unsigned short* oh = A.wh[w];
    unsigned short* ol = A.wl[w];
    unsigned short* thi = (unsigned short*)smem;            // [64][74] = 9472 B
    unsigned short* tlo = (unsigned short*)(smem + 9472);   // [64][74]
    #pragma unroll
    for (int a = 0; a < 4; ++a) {
      int idx2 = t + 256 * a;
      int tr = idx2 >> 4, tc = (idx2 & 15) * 4;
      f32x4 v = *(const f32x4*)(src + (size_t)(r0 + tr) * 256 + c0 + tc);
      u16x4 hh = {f2bf(v[0]), f2bf(v[1]), f2bf(v[2]), f2bf(v[3])};
      st4(&thi[tr * 74 + tc], hh);
      if (ol) {
        u16x4 ll = {f2bf(v[0] - bf2f(hh[0])), f2bf(v[1] - bf2f(hh[1])),
                    f2bf(v[2] - bf2f(hh[2])), f2bf(v[3] - bf2f(hh[3]))};
        st4(&tlo[tr * 74 + tc], ll);
      }
    }
    __syncthreads();
    #pragma unroll
    for (int a = 0; a < 2; ++a) {
      int idx2 = t + 256 * a;
      int orow = idx2 >> 3, oc = (idx2 & 7) * 8;
      u16x8 vh;
      #pragma unroll
      for (int j = 0; j < 8; ++j) vh[j] = thi[(oc + j) * 74 + orow];
      *(u16x8*)(oh + (size_t)(c0 + orow) * 256 + r0 + oc) = vh;
      if (ol) {
        u16x8 vl;
        #pragma unroll
        for (int j = 0; j < 8; ++j) vl[j] = tlo[(oc + j) * 74 + orow];
        *(u16x8*)(ol + (size_t)(c0 + orow) * 256 + r0 + oc) = vl;
      }
    }
  } else if (bid < 12928) {
    // ---- d1: [2][4096][6144] -> d1N + d1T, 64x64 tile, 74-stride ----
    const int idx = bid - 640;
    const int x = idx & 63;
    const int rem = idx >> 6;
    const int y = rem % 96;
    const int b = rem / 96;
    const int r0 = x * 64, c0 = y * 64;
    unsigned short* tile = (unsigned short*)smem;   // [64][74]
    #pragma unroll
    for (int a = 0; a < 4; ++a) {
      int idx2 = t + 256 * a;
      int tr = idx2 >> 4, tc = (idx2 & 15) * 4;
      size_t off = ((size_t)b * 4096 + r0 + tr) * 6144 + c0 + tc;
      f32x4 v = *(const f32x4*)(A.d1 + off);
      u16x4 hh = {f2bf(v[0]), f2bf(v[1]), f2bf(v[2]), f2bf(v[3])};
      st4(&tile[tr * 74 + tc], hh);
      *(u16x4*)(A.d1N + off) = hh;
    }
    __syncthreads();
    #pragma unroll
    for (int a = 0; a < 2; ++a) {
      int idx2 = t + 256 * a;
      int orow = idx2 >> 3, oc = (idx2 & 7) * 8;
      u16x8 vh;
      #pragma unroll
      for (int j = 0; j < 8; ++j) vh[j] = tile[(oc + j) * 74 + orow];
      *(u16x8*)(A.d1T + ((size_t)b * 6144 + c0 + orow) * 4096 + r0 + oc) = vh;
    }
  } else {
    // ---- d0: [2][6144][2048] -> d0N + d0T, 64x64 tile, 74-stride ----
    const int idx = bid - 12928;
    const int x = idx % 96;
    const int rem = idx / 96;
    const int y = rem & 31;
    const int b = rem >> 5;
    const int r0 = x * 64, c0 = y * 64;
    unsigned short* tile = (unsigned short*)smem;   // [64][74]
    #pragma unroll
    for (int a = 0; a < 4; ++a) {
      int idx2 = t + 256 * a;
      int tr = idx2 >> 4, tc = (idx2 & 15) * 4;
      size_t off = ((size_t)b * 6144 + r0 + tr) * 2048 + c0 + tc;
      f32x4 v = *(const f32x4*)(A.d0 + off);
      u16x4 hh = {f2bf(v[0]), f2bf(v[1]), f2bf(v[2]), f2bf(v[3])};
      st4(&tile[tr * 74 + tc], hh);
      *(u16x4*)(A.d0N_hi + off) = hh;
    }
    __syncthreads();
    #pragma unroll
    for (int a = 0; a < 2; ++a) {
      int idx2 = t + 256 * a;
      int orow = idx2 >> 3, oc = (idx2 & 7) * 8;
      u16x8 vh;
      #pragma unroll
      for (int j = 0; j < 8; ++j) vh[j] = tile[(oc + j) * 74 + orow];
      *(u16x8*)(A.d0T_hi + ((size_t)b * 2048 + c0 + orow) * 6144 + r0 + oc) = vh;
    }
  }
}

// ---------------------------------------------------------------------------
// Fused eVT (unscaled bf16) + Y0T (scaled bf16) from P1 cols 512..767.
// 74-stride tiles.
// ---------------------------------------------------------------------------
__global__ __launch_bounds__(256) void xpose_ev(
    const float* __restrict__ P1, unsigned short* __restrict__ eVT,
    unsigned short* __restrict__ yhi, const float* __restrict__ hE) {
  __shared__ __align__(16) unsigned short smem[2 * 64 * 74];
  unsigned short* te = smem;
  unsigned short* th = smem + 64 * 74;
  const int b = blockIdx.z;
  const int r0 = blockIdx.x * 64, c0 = blockIdx.y * 64;
  const int t = threadIdx.x;
  #pragma unroll
  for (int a = 0; a < 4; ++a) {
    int idx = t + 256 * a;
    int tr = idx >> 4, tc = (idx & 15) * 4;
    f32x4 v = *(const f32x4*)(P1 + ((size_t)b * 6144 + r0 + tr) * 1280 + 512 + c0 + tc);
    u16x4 eh = {f2bf(v[0]), f2bf(v[1]), f2bf(v[2]), f2bf(v[3])};
    st4(&te[tr * 74 + tc], eh);
    float s = hE[((size_t)b * 8 + ((c0 + tc) >> 5)) * 6144 + r0 + tr];
    f32x4 y = v * s;
    u16x4 hh = {f2bf(y[0]), f2bf(y[1]), f2bf(y[2]), f2bf(y[3])};
    st4(&th[tr * 74 + tc], hh);
  }
  __syncthreads();
  #pragma unroll
  for (int a = 0; a < 2; ++a) {
    int idx = t + 256 * a;
    int orow = idx >> 3, oc = (idx & 7) * 8;
    u16x8 ve, vh;
    #pragma unroll
    for (int j = 0; j < 8; ++j) {
      ve[j] = te[(oc + j) * 74 + orow];
      vh[j] = th[(oc + j) * 74 + orow];
    }
    size_t o = ((size_t)b * 256 + c0 + orow) * 6144 + r0 + oc;
    *(u16x8*)(eVT + o) = ve;
    *(u16x8*)(yhi + o) = vh;
  }
}

// ---------------------------------------------------------------------------
// Merged rsc_cvt (sum S slabs ascending, scale, cvt bf16).
// ---------------------------------------------------------------------------
static __device__ __forceinline__ void rsc_body(
    const float* in, unsigned short* out_hi, const float* h,
    int S, int R, int P, int bid, int nblk) {
  const long long qP = P >> 2;
  const long long nq = 2LL * R * qP;
  long long i = (long long)bid * 256 + threadIdx.x;
  const long long stride = (long long)nblk * 256;
  for (; i < nq; i += stride) {
    long long b = i / (R * qP);
    long long rem = i - b * (R * qP);
    int row = (int)(rem / qP);
    long long qc = rem - (long long)row * qP;
    const f32x4* base = (const f32x4*)in + ((b * S) * R + row) * qP + qc;
    f32x4 v = base[0];
    for (int s = 1; s < S; ++s) v += base[(long long)s * R * qP];
    v *= *(const f32x4*)(h + ((size_t)b * 8 + (row >> 5)) * P + (qc << 2));
    u16x4 hh = {f2bf(v[0]), f2bf(v[1]), f2bf(v[2]), f2bf(v[3])};
    ((u16x4*)out_hi)[i] = hh;
  }
}

__global__ void rsc2(const float* in1, unsigned short* o1h, const float* hF,
                     const float* in3, unsigned short* o3h, const float* hV) {
  if (blockIdx.x < 2048)
    rsc_body(in1, o1h, hF, 3, 256, 4096, blockIdx.x, 2048);
  else
    rsc_body(in3, o3h, hV, 6, 256, 2048, blockIdx.x - 2048, 1024);
}

// ---------------------------------------------------------------------------
// Merged hval dots: [0,3072) e/einv pairs from P1; [3072,5120) f pair from P3.
// ---------------------------------------------------------------------------
__global__ __launch_bounds__(256) void dots(
    const float* __restrict__ P1, float* __restrict__ hE, float* __restrict__ hEi,
    const float* __restrict__ P3, float* __restrict__ hF) {
  const int wv = threadIdx.x >> 6, lane = threadIdx.x & 63;
  if (blockIdx.x < 3072) {
    const int row = blockIdx.x * 4 + wv;
    const float* base = P1 + (size_t)row * 1280 + lane * 4;
    f32x4 qv = *(const f32x4*)(base);
    f32x4 kv = *(const f32x4*)(base + 256);
    float p = qv[0] * kv[0] + qv[1] * kv[1] + qv[2] * kv[2] + qv[3] * kv[3];
    p += __shfl_xor(p, 1); p += __shfl_xor(p, 2); p += __shfl_xor(p, 4);
    f32x4 q2 = *(const f32x4*)(base + 768);
    f32x4 k2 = *(const f32x4*)(base + 1024);
    float p2 = q2[0] * k2[0] + q2[1] * k2[1] + q2[2] * k2[2] + q2[3] * k2[3];
    p2 += __shfl_xor(p2, 1); p2 += __shfl_xor(p2, 2); p2 += __shfl_xor(p2, 4);
    if ((lane & 7) == 0) {
      const int head = lane >> 3;
      const int b = row / 6144, pos = row % 6144;
      hE[((size_t)b * 8 + head) * 6144 + pos] = p * 0.17677669529663687f;
      hEi[((size_t)b * 8 + head) * 6144 + pos] = p2 * 0.17677669529663687f;
    }
  } else {
    const int row = (blockIdx.x - 3072) * 4 + wv;
    const float* base = P3 + (size_t)row * 512 + lane * 4;
    f32x4 qv = *(const f32x4*)(base);
    f32x4 kv = *(const f32x4*)(base + 256);
    float p = qv[0] * kv[0] + qv[1] * kv[1] + qv[2] * kv[2] + qv[3] * kv[3];
    p += __shfl_xor(p, 1); p += __shfl_xor(p, 2); p += __shfl_xor(p, 4);
    if ((lane & 7) == 0) {
      const int head = lane >> 3;
      const int b = row / 4096, pos = row % 4096;
      hF[((size_t)b * 8 + head) * 4096 + pos] = p * 0.17677669529663687f;
    }
  }
}

// ---------------------------------------------------------------------------
extern "C" void kernel_launch(void* const* d_in, const int* in_sizes, int n_in,
                              void* d_out, int out_size, void* d_ws, size_t ws_size,
                              hipStream_t stream) {
  const float* x_v = (const float*)d_in[0];
  const float* x_e = (const float*)d_in[1];
  const float* x_f = (const float*)d_in[2];
  const float* d0  = (const float*)d_in[3];   // (2, 6144, 2048)
  const float* d1  = (const float*)d_in[4];   // (2, 4096, 6144)
  float* out = (float*)d_out;

  const int NV = 2048, ME = 6144, KF = 4096;

  char* ws = (char*)d_ws;
  size_t o = 0;
  auto alloc = [&](size_t bytes) { size_t r = o; o = (o + bytes + 255) & ~255ULL; return r; };

  unsigned short* Wcat5_hi = (unsigned short*)(ws + alloc(1280 * 256 * 2));
  unsigned short* Wcat5_lo = (unsigned short*)(ws + alloc(1280 * 256 * 2));
  unsigned short* W3_hi = (unsigned short*)(ws + alloc(512 * 256 * 2));
  unsigned short* Wo_hi = (unsigned short*)(ws + alloc(256 * 256 * 2));
  unsigned short* Wo_lo = (unsigned short*)(ws + alloc(256 * 256 * 2));
  float* pHvE  = (float*)(ws + alloc(2 * 8 * ME * 4));
  float* pHvEi = (float*)(ws + alloc(2 * 8 * ME * 4));
  float* pHvF  = (float*)(ws + alloc(2 * 8 * KF * 4));
  float* pHvV  = (float*)(ws + alloc(2 * 8 * NV * 4));
  unsigned short* d1T_hi = (unsigned short*)(ws + alloc((size_t)2 * ME * KF * 2));
  unsigned short* d1N_hi = (unsigned short*)(ws + alloc((size_t)2 * KF * ME * 2));
  unsigned short* d0T_hi = (unsigned short*)(ws + alloc((size_t)2 * NV * ME * 2));
  unsigned short* d0N_hi = (unsigned short*)(ws + alloc((size_t)2 * ME * NV * 2));
  unsigned short* eVT_hi = (unsigned short*)(ws + alloc((size_t)2 * 256 * ME * 2));
  unsigned short* Y0T_hi = (unsigned short*)(ws + alloc((size_t)2 * 256 * ME * 2));
  unsigned short* T1sT_hi = (unsigned short*)(ws + alloc((size_t)2 * 256 * KF * 2));
  unsigned short* T3sT_hi = (unsigned short*)(ws + alloc((size_t)2 * 256 * NV * 2));
  float* pP1 = (float*)(ws + alloc((size_t)12288 * 1280 * 4));
  float* pP3 = (float*)(ws + alloc((size_t)8192 * 512 * 4));
  float* pTp1 = (float*)(ws + alloc((size_t)2 * 3 * 256 * KF * 4));   // T1^T slabs
  float* pTp3 = (float*)(ws + alloc((size_t)2 * 6 * 256 * NV * 4));   // T3^T slabs
  float* pT2p = (float*)(ws + alloc((size_t)2 * 2 * ME * 256 * 4));
  float* pT4p = (float*)(ws + alloc((size_t)2 * 2 * ME * 256 * 4));

  dim3 blk(256);

  // --- mega-prep: vproj + weight transposes + d1/d0 conversions ---
  PrepArgs pa;
  pa.wsrc[0] = (const float*)d_in[7];  pa.wh[0] = Wcat5_hi;          pa.wl[0] = Wcat5_lo;
  pa.wsrc[1] = (const float*)d_in[8];  pa.wh[1] = Wcat5_hi + 65536;  pa.wl[1] = Wcat5_lo + 65536;
  pa.wsrc[2] = (const float*)d_in[11]; pa.wh[2] = Wcat5_hi + 131072; pa.wl[2] = Wcat5_lo + 131072;
  pa.wsrc[3] = (const float*)d_in[9];  pa.wh[3] = Wcat5_hi + 196608; pa.wl[3] = Wcat5_lo + 196608;
  pa.wsrc[4] = (const float*)d_in[10]; pa.wh[4] = Wcat5_hi + 262144; pa.wl[4] = Wcat5_lo + 262144;
  pa.wsrc[5] = (const float*)d_in[12]; pa.wh[5] = W3_hi;             pa.wl[5] = nullptr;
  pa.wsrc[6] = (const float*)d_in[13]; pa.wh[6] = W3_hi + 65536;     pa.wl[6] = nullptr;
  pa.wsrc[7] = (const float*)d_in[14]; pa.wh[7] = Wo_hi;             pa.wl[7] = Wo_lo;
  pa.d1 = d1; pa.d1T = d1T_hi; pa.d1N = d1N_hi;
  pa.d0 = d0; pa.d0T_hi = d0T_hi; pa.d0N_hi = d0N_hi;
  pa.xv = x_v; pa.Wvq = (const float*)d_in[5]; pa.Wvk = (const float*)d_in[6];
  pa.hvV = pHvV;
  prep_all<<<19072, blk, 0, stream>>>(pa);

  // --- projections (P1 + P3 in one launch) ---
  proj_dual<<<1216, blk, 0, stream>>>(x_e, Wcat5_hi, Wcat5_lo, pP1, x_f, W3_hi, pP3);
  dots<<<5120, blk, 0, stream>>>(pP1, pHvE, pHvEi, pP3, pHvF);
  xpose_ev<<<dim3(96, 4, 2), blk, 0, stream>>>(pP1, eVT_hi, Y0T_hi, pHvE);

  // --- T1 + T3 in one launch ---
  GJob jT1, jT3;
  jT1.Ah = eVT_hi; jT1.Bh = d1N_hi; jT1.C = pTp1;
  jT1.K = ME; jT1.ldA = ME; jT1.ldB = ME; jT1.S = 3; jT1.gx = 2; jT1.gy = 32;
  jT1.sA = 256LL * ME; jT1.sB = (long long)KF * ME; jT1.sC = 256LL * KF;
  jT3.Ah = Y0T_hi; jT3.Bh = d0T_hi; jT3.C = pTp3;
  jT3.K = ME; jT3.ldA = ME; jT3.ldB = ME; jT3.S = 6; jT3.gx = 2; jT3.gy = 16;
  jT3.sA = 256LL * ME; jT3.sB = (long long)NV * ME; jT3.sC = 256LL * NV;
  gemm_dual<true><<<768, blk, 0, stream>>>(jT1, jT3, 384);

  // --- reductions + scale + cvt ---
  rsc2<<<3072, blk, 0, stream>>>(pTp1, T1sT_hi, pHvF, pTp3, T3sT_hi, pHvV);

  // --- T2 + T4 in one launch ---
  GJob jT2, jT4;
  jT2.Ah = d1T_hi; jT2.Bh = T1sT_hi; jT2.C = pT2p;
  jT2.K = KF; jT2.ldA = KF; jT2.ldB = KF; jT2.S = 2; jT2.gx = 48; jT2.gy = 2;
  jT2.sA = (long long)ME * KF; jT2.sB = 256LL * KF; jT2.sC = (long long)ME * 256;
  jT4.Ah = d0N_hi; jT4.Bh = T3sT_hi; jT4.C = pT4p;
  jT4.K = NV; jT4.ldA = NV; jT4.ldB = NV; jT4.S = 2; jT4.gx = 48; jT4.gy = 2;
  jT4.sA = (long long)ME * NV; jT4.sB = 256LL * NV; jT4.sC = (long long)ME * 256;
  gemm_dual<false><<<768, blk, 0, stream>>>(jT2, jT4, 384);

  // --- fused combine + output projection ---
  gemm_out<<<dim3(96, 2, 1), blk, 0, stream>>>(pT2p, pT4p, pHvEi, Wo_hi, Wo_lo, out);
}

// Round 16
// 389.728 us; speedup vs baseline: 1.1208x; 1.0053x over previous
//
#include <hip/hip_runtime.h>
#include <hip/hip_bf16.h>
#include <cstdint>
#include <cstddef>

// ---------------------------------------------------------------------------
// MeshMultiHeadHodgeLaplaceAttention  (b=2, n=2048, m=6144, k=4096, D=256, H=8)
//
//   up:   T1 = d_1 @ eV ; *f_hval ; T2 = d_1^T @ T1s ; (*einv_hval in combine)
//   down: Y0 = eV*e_hval ; T3 = d_0^T @ Y0 ; *1/(v_hval+eps) ; T4 = d_0 @ T3s
//   out = (T2*einv_hval + T4) @ W_o
//
// Precision: v_hval replicates numpy fp32 bit-exactly; P1 + output GEMM
// split-bf16; T1..T4 plain bf16 (validated R10-R15, absmax=256).
//
// R16: natural bf16 copies d1N/d0N eliminated (-150 MB prep writes, -150 MB
// GEMM reads). T1 consumes d1 fp32 as B (cvt-in-staging, MODE=2); T4
// consumes d0 fp32 as A (MODE=1). prep d-branches: read fp32 -> write
// transposed bf16 only. Rest identical to R15.
// ---------------------------------------------------------------------------

typedef __attribute__((ext_vector_type(4))) float f32x4;
typedef __attribute__((ext_vector_type(2))) unsigned short u16x2;
typedef __attribute__((ext_vector_type(4))) unsigned short u16x4;
typedef __attribute__((ext_vector_type(8))) unsigned short u16x8;
typedef __attribute__((ext_vector_type(8))) __bf16 bf16x8;

static __device__ __forceinline__ unsigned short f2bf(float f) {
  uint32_t u = __builtin_bit_cast(uint32_t, f);
  uint32_t r = (u + 0x7FFFu + ((u >> 16) & 1u)) >> 16;  // RNE
  return (unsigned short)r;
}
static __device__ __forceinline__ float bf2f(unsigned short h) {
  return __builtin_bit_cast(float, (uint32_t)h << 16);
}
static __device__ __forceinline__ void st4(unsigned short* p, u16x4 v) {
  *(u16x2*)p = u16x2{v[0], v[1]};
  *(u16x2*)(p + 2) = u16x2{v[2], v[3]};
}

// ---------------------------------------------------------------------------
// Mode-templated GEMM body. MODE: 0 = A,B bf16 ; 1 = A fp32 cvt ; 2 = B fp32
// cvt. C[M x gy*128] = A[M x K] * B[N x K]; split-K z = batch*S + split.
// 128x128 tile, BK=32, reg-prefetch, 2-buffer LDS (20 KB).
// ---------------------------------------------------------------------------
struct GJob {
  const unsigned short* Ah; const float* Af;
  const unsigned short* Bh; const float* Bf;
  float* C;
  int K, ldA, ldB, S, gx, gy;
  long long sA, sB, sC;
};

template <int MODE, bool XFAST>
static __device__ void gemm_body(char* smem, const GJob& J, int b) {
  const int per = J.gx * J.gy;
  const int z = b / per;
  const int wid = b - z * per;
  const int batch = z / J.S, split = z - batch * J.S;
  const unsigned short* Ah = nullptr; const float* Af = nullptr;
  const unsigned short* Bh = nullptr; const float* Bf = nullptr;
  if constexpr (MODE == 1) Af = J.Af + (long long)batch * J.sA;
  else                     Ah = J.Ah + (long long)batch * J.sA;
  if constexpr (MODE == 2) Bf = J.Bf + (long long)batch * J.sB;
  else                     Bh = J.Bh + (long long)batch * J.sB;
  float* C = J.C + (long long)z * J.sC;

  const int nwg = per;
  const int q = nwg >> 3, r = nwg & 7;
  const int xcd = wid & 7, posn = wid >> 3;
  const int swz = (xcd < r ? xcd * (q + 1) : r * (q + 1) + (xcd - r) * q) + posn;
  int mt, nt;
  if constexpr (XFAST) { mt = swz % J.gx; nt = swz / J.gx; }
  else                 { mt = swz / J.gy; nt = swz - mt * J.gy; }
  const int m0 = mt * 128, n0 = nt * 128;
  const int NC = J.gy << 7;
  const int kLen = J.K / J.S, k0base = split * kLen;

  typedef unsigned short ldsrow[128][40];
  ldsrow* lds = (ldsrow*)smem;   // [2][128][40]

  const int t = threadIdx.x;
  const int w4 = t >> 6, lane = t & 63;
  const int wr = w4 >> 1, wc = w4 & 1;
  const int lr = lane & 15, kq = lane >> 4;
  const int rowV = t >> 2, c8V = (t & 3) * 8;     // bf16 staging
  const int rowA8 = t >> 3, qdA = (t & 7) * 4;    // fp32 staging

  u16x8 rAh[2], rBh[2];
  f32x4 rF[4];

  auto LOAD = [&](int kb) {
    if constexpr (MODE == 1) {
      #pragma unroll
      for (int a = 0; a < 4; ++a)
        rF[a] = *(const f32x4*)(Af + (size_t)(m0 + rowA8 + 32 * a) * J.ldA + kb + qdA);
    } else {
      #pragma unroll
      for (int a = 0; a < 2; ++a)
        rAh[a] = *(const u16x8*)(Ah + (size_t)(m0 + rowV + 64 * a) * J.ldA + kb + c8V);
    }
    if constexpr (MODE == 2) {
      #pragma unroll
      for (int a = 0; a < 4; ++a)
        rF[a] = *(const f32x4*)(Bf + (size_t)(n0 + rowA8 + 32 * a) * J.ldB + kb + qdA);
    } else {
      #pragma unroll
      for (int a = 0; a < 2; ++a)
        rBh[a] = *(const u16x8*)(Bh + (size_t)(n0 + rowV + 64 * a) * J.ldB + kb + c8V);
    }
  };
  auto STORE = [&]() {
    if constexpr (MODE == 1) {
      #pragma unroll
      for (int a = 0; a < 4; ++a) {
        f32x4 v = rF[a];
        u16x4 h = {f2bf(v[0]), f2bf(v[1]), f2bf(v[2]), f2bf(v[3])};
        *(u16x4*)&lds[0][rowA8 + 32 * a][qdA] = h;
      }
    } else {
      #pragma unroll
      for (int a = 0; a < 2; ++a) *(u16x8*)&lds[0][rowV + 64 * a][c8V] = rAh[a];
    }
    if constexpr (MODE == 2) {
      #pragma unroll
      for (int a = 0; a < 4; ++a) {
        f32x4 v = rF[a];
        u16x4 h = {f2bf(v[0]), f2bf(v[1]), f2bf(v[2]), f2bf(v[3])};
        *(u16x4*)&lds[1][rowA8 + 32 * a][qdA] = h;
      }
    } else {
      #pragma unroll
      for (int a = 0; a < 2; ++a) *(u16x8*)&lds[1][rowV + 64 * a][c8V] = rBh[a];
    }
  };

  f32x4 acc[4][4] = {};
  LOAD(k0base);
  for (int kk = 0; kk < kLen; kk += 32) {
    STORE();
    __syncthreads();
    if (kk + 32 < kLen) LOAD(k0base + kk + 32);  // prefetch under MFMA

    bf16x8 ah[4], bh[4];
    #pragma unroll
    for (int i = 0; i < 4; ++i) {
      ah[i] = __builtin_bit_cast(bf16x8, *(const u16x8*)&lds[0][wr * 64 + i * 16 + lr][kq * 8]);
      bh[i] = __builtin_bit_cast(bf16x8, *(const u16x8*)&lds[1][wc * 64 + i * 16 + lr][kq * 8]);
    }
    #pragma unroll
    for (int i = 0; i < 4; ++i)
      #pragma unroll
      for (int j = 0; j < 4; ++j)
        acc[i][j] = __builtin_amdgcn_mfma_f32_16x16x32_bf16(ah[i], bh[j], acc[i][j], 0, 0, 0);
    __syncthreads();
  }

  #pragma unroll
  for (int i = 0; i < 4; ++i)
    #pragma unroll
    for (int j = 0; j < 4; ++j) {
      float* cp = C + (size_t)(m0 + wr * 64 + i * 16 + kq * 4) * NC + n0 + wc * 64 + j * 16 + lr;
      #pragma unroll
      for (int qq = 0; qq < 4; ++qq) cp[(size_t)qq * NC] = acc[i][j][qq];
    }
}

template <int M0, int M1, bool XFAST>
__global__ __launch_bounds__(256) void gemm_dual(GJob j0, GJob j1, int nb0) {
  __shared__ __align__(16) unsigned short lds[2][128][40];
  if ((int)blockIdx.x < nb0) gemm_body<M0, XFAST>((char*)lds, j0, blockIdx.x);
  else                       gemm_body<M1, XFAST>((char*)lds, j1, blockIdx.x - nb0);
}

// ---------------------------------------------------------------------------
// Projection GEMM body (K=256): C = A fp32 (cvt) * B bf16 hi(/lo).
// ---------------------------------------------------------------------------
template <bool SPLIT>
static __device__ void proj_body(char* smem, int wid, int gx, int gy,
                                 const float* __restrict__ Af,
                                 const unsigned short* __restrict__ Bh,
                                 const unsigned short* __restrict__ Bl,
                                 float* __restrict__ C) {
  const int nwg = gx * gy;
  const int q = nwg >> 3, r = nwg & 7;
  const int xcd = wid & 7, posn = wid >> 3;
  const int swz = (xcd < r ? xcd * (q + 1) : r * (q + 1) + (xcd - r) * q) + posn;
  const int mt = swz / gy;
  const int m0 = mt * 128, n0 = (swz - mt * gy) * 128;
  const int NC = gy << 7;

  typedef unsigned short ldsrow[128][40];
  ldsrow* lds = (ldsrow*)smem;

  const int t = threadIdx.x;
  const int w4 = t >> 6, lane = t & 63;
  const int wr = w4 >> 1, wc = w4 & 1;
  const int lr = lane & 15, kq = lane >> 4;
  const int rowA8 = t >> 3, qdA = (t & 7) * 4;
  const int rowV = t >> 2, c8V = (t & 3) * 8;

  f32x4 rAf[4];
  u16x8 rBh[2], rBl[2];

  auto LOAD = [&](int kb) {
    #pragma unroll
    for (int a = 0; a < 4; ++a)
      rAf[a] = *(const f32x4*)(Af + (size_t)(m0 + rowA8 + 32 * a) * 256 + kb + qdA);
    #pragma unroll
    for (int a = 0; a < 2; ++a) {
      rBh[a] = *(const u16x8*)(Bh + (size_t)(n0 + rowV + 64 * a) * 256 + kb + c8V);
      if constexpr (SPLIT)
        rBl[a] = *(const u16x8*)(Bl + (size_t)(n0 + rowV + 64 * a) * 256 + kb + c8V);
    }
  };
  auto STORE = [&]() {
    #pragma unroll
    for (int a = 0; a < 4; ++a) {
      f32x4 v = rAf[a];
      u16x4 h = {f2bf(v[0]), f2bf(v[1]), f2bf(v[2]), f2bf(v[3])};
      *(u16x4*)&lds[0][rowA8 + 32 * a][qdA] = h;
      if constexpr (SPLIT) {
        u16x4 l = {f2bf(v[0] - bf2f(h[0])), f2bf(v[1] - bf2f(h[1])),
                   f2bf(v[2] - bf2f(h[2])), f2bf(v[3] - bf2f(h[3]))};
        *(u16x4*)&lds[2][rowA8 + 32 * a][qdA] = l;
      }
    }
    #pragma unroll
    for (int a = 0; a < 2; ++a) {
      *(u16x8*)&lds[1][rowV + 64 * a][c8V] = rBh[a];
      if constexpr (SPLIT) *(u16x8*)&lds[3][rowV + 64 * a][c8V] = rBl[a];
    }
  };

  f32x4 acc[4][4] = {};
  LOAD(0);
  for (int kk = 0; kk < 256; kk += 32) {
    STORE();
    __syncthreads();
    if (kk + 32 < 256) LOAD(kk + 32);

    bf16x8 ah[4], bh[4], al[4], bl[4];
    #pragma unroll
    for (int i = 0; i < 4; ++i) {
      ah[i] = __builtin_bit_cast(bf16x8, *(const u16x8*)&lds[0][wr * 64 + i * 16 + lr][kq * 8]);
      bh[i] = __builtin_bit_cast(bf16x8, *(const u16x8*)&lds[1][wc * 64 + i * 16 + lr][kq * 8]);
      if constexpr (SPLIT) {
        al[i] = __builtin_bit_cast(bf16x8, *(const u16x8*)&lds[2][wr * 64 + i * 16 + lr][kq * 8]);
        bl[i] = __builtin_bit_cast(bf16x8, *(const u16x8*)&lds[3][wc * 64 + i * 16 + lr][kq * 8]);
      }
    }
    #pragma unroll
    for (int i = 0; i < 4; ++i)
      #pragma unroll
      for (int j = 0; j < 4; ++j) {
        acc[i][j] = __builtin_amdgcn_mfma_f32_16x16x32_bf16(ah[i], bh[j], acc[i][j], 0, 0, 0);
        if constexpr (SPLIT) {
          acc[i][j] = __builtin_amdgcn_mfma_f32_16x16x32_bf16(ah[i], bl[j], acc[i][j], 0, 0, 0);
          acc[i][j] = __builtin_amdgcn_mfma_f32_16x16x32_bf16(al[i], bh[j], acc[i][j], 0, 0, 0);
        }
      }
    __syncthreads();
  }

  #pragma unroll
  for (int i = 0; i < 4; ++i)
    #pragma unroll
    for (int j = 0; j < 4; ++j) {
      float* cp = C + (size_t)(m0 + wr * 64 + i * 16 + kq * 4) * NC + n0 + wc * 64 + j * 16 + lr;
      #pragma unroll
      for (int qq = 0; qq < 4; ++qq) cp[(size_t)qq * NC] = acc[i][j][qq];
    }
}

// P1 (split, 960 blocks) + P3 (plain, 256 blocks) in one launch.
__global__ __launch_bounds__(256) void proj_dual(
    const float* __restrict__ xe, const unsigned short* __restrict__ W5h,
    const unsigned short* __restrict__ W5l, float* __restrict__ P1,
    const float* __restrict__ xf, const unsigned short* __restrict__ W3h,
    float* __restrict__ P3) {
  __shared__ __align__(16) unsigned short lds[4][128][40];
  if ((int)blockIdx.x < 960)
    proj_body<true>((char*)lds, blockIdx.x, 96, 10, xe, W5h, W5l, P1);
  else
    proj_body<false>((char*)lds, blockIdx.x - 960, 64, 4, xf, W3h, nullptr, P3);
}

// ---------------------------------------------------------------------------
// Output GEMM with fused combine: A[r][c] = (T4p 2-slab sum) +
// (T2p 2-slab sum)*einv_hval;  C = A @ W_o (split hi/lo). M=12288,N=256,K=256.
// ---------------------------------------------------------------------------
__global__ __launch_bounds__(256) void gemm_out(
    const float* __restrict__ T2p, const float* __restrict__ T4p,
    const float* __restrict__ hEi, const unsigned short* __restrict__ Bh,
    const unsigned short* __restrict__ Bl, float* __restrict__ C) {
  const int gx = gridDim.x, gy = gridDim.y;
  const int nwg = gx * gy;
  const int wid = blockIdx.x + gx * blockIdx.y;
  const int q = nwg >> 3, r = nwg & 7;
  const int xcd = wid & 7, posn = wid >> 3;
  const int swz = (xcd < r ? xcd * (q + 1) : r * (q + 1) + (xcd - r) * q) + posn;
  const int mt = swz / gy;
  const int m0 = mt * 128, n0 = (swz - mt * gy) * 128;

  __shared__ unsigned short lds[4][128][40];
  const int t = threadIdx.x;
  const int w4 = t >> 6, lane = t & 63;
  const int wr = w4 >> 1, wc = w4 & 1;
  const int lr = lane & 15, kq = lane >> 4;
  const long long slab = 6144LL * 256;

  f32x4 acc[4][4] = {};

  for (int kb = 0; kb < 256; kb += 32) {
    #pragma unroll
    for (int a = 0; a < 4; ++a) {
      int idx = t + 256 * a;
      int row = idx >> 3, qd = (idx & 7) * 4;
      int rg = m0 + row;
      int b = rg >= 6144;
      int pos = rg - b * 6144;
      int ck = kb + qd;
      float s = hEi[((size_t)b * 8 + (ck >> 5)) * 6144 + pos];
      const float* b2 = T2p + ((long long)(b * 2) * 6144 + pos) * 256 + ck;
      const float* b4 = T4p + ((long long)(b * 2) * 6144 + pos) * 256 + ck;
      f32x4 t2 = *(const f32x4*)b2 + *(const f32x4*)(b2 + slab);
      f32x4 t4 = *(const f32x4*)b4 + *(const f32x4*)(b4 + slab);
      f32x4 v = t4 + t2 * s;
      u16x4 h = {f2bf(v[0]), f2bf(v[1]), f2bf(v[2]), f2bf(v[3])};
      *(u16x4*)&lds[0][row][qd] = h;
      u16x4 l = {f2bf(v[0] - bf2f(h[0])), f2bf(v[1] - bf2f(h[1])),
                 f2bf(v[2] - bf2f(h[2])), f2bf(v[3] - bf2f(h[3]))};
      *(u16x4*)&lds[2][row][qd] = l;
    }
    #pragma unroll
    for (int a = 0; a < 2; ++a) {
      int idx = t + 256 * a;
      int row = idx >> 2, c8 = (idx & 3) * 8;
      *(u16x8*)&lds[1][row][c8] = *(const u16x8*)(Bh + (size_t)(n0 + row) * 256 + kb + c8);
      *(u16x8*)&lds[3][row][c8] = *(const u16x8*)(Bl + (size_t)(n0 + row) * 256 + kb + c8);
    }
    __syncthreads();

    bf16x8 ah[4], bh[4], al[4], bl[4];
    #pragma unroll
    for (int i = 0; i < 4; ++i) {
      ah[i] = __builtin_bit_cast(bf16x8, *(const u16x8*)&lds[0][wr * 64 + i * 16 + lr][kq * 8]);
      bh[i] = __builtin_bit_cast(bf16x8, *(const u16x8*)&lds[1][wc * 64 + i * 16 + lr][kq * 8]);
      al[i] = __builtin_bit_cast(bf16x8, *(const u16x8*)&lds[2][wr * 64 + i * 16 + lr][kq * 8]);
      bl[i] = __builtin_bit_cast(bf16x8, *(const u16x8*)&lds[3][wc * 64 + i * 16 + lr][kq * 8]);
    }
    #pragma unroll
    for (int i = 0; i < 4; ++i)
      #pragma unroll
      for (int j = 0; j < 4; ++j) {
        acc[i][j] = __builtin_amdgcn_mfma_f32_16x16x32_bf16(ah[i], bh[j], acc[i][j], 0, 0, 0);
        acc[i][j] = __builtin_amdgcn_mfma_f32_16x16x32_bf16(ah[i], bl[j], acc[i][j], 0, 0, 0);
        acc[i][j] = __builtin_amdgcn_mfma_f32_16x16x32_bf16(al[i], bh[j], acc[i][j], 0, 0, 0);
      }
    __syncthreads();
  }

  #pragma unroll
  for (int i = 0; i < 4; ++i)
    #pragma unroll
    for (int j = 0; j < 4; ++j) {
      float* cp = C + (size_t)(m0 + wr * 64 + i * 16 + kq * 4) * 256 + n0 + wc * 64 + j * 16 + lr;
      #pragma unroll
      for (int qq = 0; qq < 4; ++qq) cp[(size_t)qq * 256] = acc[i][j][qq];
    }
}

// ---------------------------------------------------------------------------
// Mega-prep kernel: [0,512) vproj ; [512,640) weight transposes ;
// [640,12928) d1 -> d1T only ; [12928,19072) d0 -> d0T only.
// 64x64 tiles, 74-u16 row stride.
// ---------------------------------------------------------------------------
struct PrepArgs {
  const float* wsrc[8]; unsigned short* wh[8]; unsigned short* wl[8];
  const float* d1; unsigned short* d1T;
  const float* d0; unsigned short* d0T_hi;
  const float* xv; const float* Wvq; const float* Wvk; float* hvV;
};

__global__ __launch_bounds__(256) void prep_all(PrepArgs A) {
  __shared__ __align__(16) char smem[24576];
  const int t = threadIdx.x;
  const int bid = blockIdx.x;

  if (bid < 512) {
    // ---- vproj (np-fp32 exact, 8 rows/block) ----
    float* sx = (float*)smem;
    float* sq = (float*)(smem + 8192);
    float* sk = (float*)(smem + 16384);
    const int r0 = bid * 8;
    const int j = t;
    #pragma unroll
    for (int r = 0; r < 8; ++r) sx[r * 256 + j] = A.xv[(size_t)(r0 + r) * 256 + j];
    __syncthreads();
    float qa[8] = {}, ka[8] = {};
    for (int i = 0; i < 256; ++i) {
      float wq = A.Wvq[i * 256 + j], wk = A.Wvk[i * 256 + j];
      #pragma unroll
      for (int r = 0; r < 8; ++r) {
        qa[r] = __fmaf_rn(sx[r * 256 + i], wq, qa[r]);
        ka[r] = __fmaf_rn(sx[r * 256 + i], wk, ka[r]);
      }
    }
    #pragma unroll
    for (int r = 0; r < 8; ++r) { sq[r * 256 + j] = qa[r]; sk[r * 256 + j] = ka[r]; }
    __syncthreads();
    if (j < 64) {
      const int r = j >> 3, head = j & 7;
      const float* qq = &sq[r * 256 + head * 32];
      const float* kk = &sk[r * 256 + head * 32];
      float s0 = 0.0f, s1 = 0.0f, s2 = 0.0f, s3 = 0.0f;
      #pragma unroll 1
      for (int d = 0; d < 32; d += 4) {
        s0 = __fadd_rn(s0, __fmul_rn(qq[d + 0], kk[d + 0]));
        s1 = __fadd_rn(s1, __fmul_rn(qq[d + 1], kk[d + 1]));
        s2 = __fadd_rn(s2, __fmul_rn(qq[d + 2], kk[d + 2]));
        s3 = __fadd_rn(s3, __fmul_rn(qq[d + 3], kk[d + 3]));
      }
      float p = __fadd_rn(__fadd_rn(s0, s2), __fadd_rn(s1, s3));
      float hval = __fdiv_rn(p, sqrtf(32.0f));
      float inv = __fdiv_rn(1.0f, __fadd_rn(hval, 1e-6f));
      const int row = r0 + r;
      const int b = row / 2048, pos = row - b * 2048;
      A.hvV[((size_t)b * 8 + head) * 2048 + pos] = inv;
    }
  } else if (bid < 640) {
    // ---- weight transposes (hi + lo tiles, 74-stride) ----
    const int idx = bid - 512;
    const int w = idx >> 4;
    const int r0 = (idx & 3) * 64, c0 = ((idx >> 2) & 3) * 64;
    const float* src = A.wsrc[w];
    unsigned short* oh = A.wh[w];
    unsigned short* ol = A.wl[w];
    unsigned short* thi = (unsigned short*)smem;            // [64][74]
    unsigned short* tlo = (unsigned short*)(smem + 9472);   // [64][74]
    #pragma unroll
    for (int a = 0; a < 4; ++a) {
      int idx2 = t + 256 * a;
      int tr = idx2 >> 4, tc = (idx2 & 15) * 4;
      f32x4 v = *(const f32x4*)(src + (size_t)(r0 + tr) * 256 + c0 + tc);
      u16x4 hh = {f2bf(v[0]), f2bf(v[1]), f2bf(v[2]), f2bf(v[3])};
      st4(&thi[tr * 74 + tc], hh);
      if (ol) {
        u16x4 ll = {f2bf(v[0] - bf2f(hh[0])), f2bf(v[1] - bf2f(hh[1])),
                    f2bf(v[2] - bf2f(hh[2])), f2bf(v[3] - bf2f(hh[3]))};
        st4(&tlo[tr * 74 + tc], ll);
      }
    }
    __syncthreads();
    #pragma unroll
    for (int a = 0; a < 2; ++a) {
      int idx2 = t + 256 * a;
      int orow = idx2 >> 3, oc = (idx2 & 7) * 8;
      u16x8 vh;
      #pragma unroll
      for (int j = 0; j < 8; ++j) vh[j] = thi[(oc + j) * 74 + orow];
      *(u16x8*)(oh + (size_t)(c0 + orow) * 256 + r0 + oc) = vh;
      if (ol) {
        u16x8 vl;
        #pragma unroll
        for (int j = 0; j < 8; ++j) vl[j] = tlo[(oc + j) * 74 + orow];
        *(u16x8*)(ol + (size_t)(c0 + orow) * 256 + r0 + oc) = vl;
      }
    }
  } else if (bid < 12928) {
    // ---- d1: [2][4096][6144] fp32 -> d1T bf16 only ----
    const int idx = bid - 640;
    const int x = idx & 63;
    const int rem = idx >> 6;
    const int y = rem % 96;
    const int b = rem / 96;
    const int r0 = x * 64, c0 = y * 64;
    unsigned short* tile = (unsigned short*)smem;   // [64][74]
    #pragma unroll
    for (int a = 0; a < 4; ++a) {
      int idx2 = t + 256 * a;
      int tr = idx2 >> 4, tc = (idx2 & 15) * 4;
      size_t off = ((size_t)b * 4096 + r0 + tr) * 6144 + c0 + tc;
      f32x4 v = *(const f32x4*)(A.d1 + off);
      u16x4 hh = {f2bf(v[0]), f2bf(v[1]), f2bf(v[2]), f2bf(v[3])};
      st4(&tile[tr * 74 + tc], hh);
    }
    __syncthreads();
    #pragma unroll
    for (int a = 0; a < 2; ++a) {
      int idx2 = t + 256 * a;
      int orow = idx2 >> 3, oc = (idx2 & 7) * 8;
      u16x8 vh;
      #pragma unroll
      for (int j = 0; j < 8; ++j) vh[j] = tile[(oc + j) * 74 + orow];
      *(u16x8*)(A.d1T + ((size_t)b * 6144 + c0 + orow) * 4096 + r0 + oc) = vh;
    }
  } else {
    // ---- d0: [2][6144][2048] fp32 -> d0T bf16 only ----
    const int idx = bid - 12928;
    const int x = idx % 96;
    const int rem = idx / 96;
    const int y = rem & 31;
    const int b = rem >> 5;
    const int r0 = x * 64, c0 = y * 64;
    unsigned short* tile = (unsigned short*)smem;   // [64][74]
    #pragma unroll
    for (int a = 0; a < 4; ++a) {
      int idx2 = t + 256 * a;
      int tr = idx2 >> 4, tc = (idx2 & 15) * 4;
      size_t off = ((size_t)b * 6144 + r0 + tr) * 2048 + c0 + tc;
      f32x4 v = *(const f32x4*)(A.d0 + off);
      u16x4 hh = {f2bf(v[0]), f2bf(v[1]), f2bf(v[2]), f2bf(v[3])};
      st4(&tile[tr * 74 + tc], hh);
    }
    __syncthreads();
    #pragma unroll
    for (int a = 0; a < 2; ++a) {
      int idx2 = t + 256 * a;
      int orow = idx2 >> 3, oc = (idx2 & 7) * 8;
      u16x8 vh;
      #pragma unroll
      for (int j = 0; j < 8; ++j) vh[j] = tile[(oc + j) * 74 + orow];
      *(u16x8*)(A.d0T_hi + ((size_t)b * 2048 + c0 + orow) * 6144 + r0 + oc) = vh;
    }
  }
}

// ---------------------------------------------------------------------------
// Fused eVT (unscaled bf16) + Y0T (scaled bf16) from P1 cols 512..767.
// ---------------------------------------------------------------------------
__global__ __launch_bounds__(256) void xpose_ev(
    const float* __restrict__ P1, unsigned short* __restrict__ eVT,
    unsigned short* __restrict__ yhi, const float* __restrict__ hE) {
  __shared__ __align__(16) unsigned short smem[2 * 64 * 74];
  unsigned short* te = smem;
  unsigned short* th = smem + 64 * 74;
  const int b = blockIdx.z;
  const int r0 = blockIdx.x * 64, c0 = blockIdx.y * 64;
  const int t = threadIdx.x;
  #pragma unroll
  for (int a = 0; a < 4; ++a) {
    int idx = t + 256 * a;
    int tr = idx >> 4, tc = (idx & 15) * 4;
    f32x4 v = *(const f32x4*)(P1 + ((size_t)b * 6144 + r0 + tr) * 1280 + 512 + c0 + tc);
    u16x4 eh = {f2bf(v[0]), f2bf(v[1]), f2bf(v[2]), f2bf(v[3])};
    st4(&te[tr * 74 + tc], eh);
    float s = hE[((size_t)b * 8 + ((c0 + tc) >> 5)) * 6144 + r0 + tr];
    f32x4 y = v * s;
    u16x4 hh = {f2bf(y[0]), f2bf(y[1]), f2bf(y[2]), f2bf(y[3])};
    st4(&th[tr * 74 + tc], hh);
  }
  __syncthreads();
  #pragma unroll
  for (int a = 0; a < 2; ++a) {
    int idx = t + 256 * a;
    int orow = idx >> 3, oc = (idx & 7) * 8;
    u16x8 ve, vh;
    #pragma unroll
    for (int j = 0; j < 8; ++j) {
      ve[j] = te[(oc + j) * 74 + orow];
      vh[j] = th[(oc + j) * 74 + orow];
    }
    size_t o = ((size_t)b * 256 + c0 + orow) * 6144 + r0 + oc;
    *(u16x8*)(eVT + o) = ve;
    *(u16x8*)(yhi + o) = vh;
  }
}

// ---------------------------------------------------------------------------
// Merged rsc_cvt (sum S slabs ascending, scale, cvt bf16).
// ---------------------------------------------------------------------------
static __device__ __forceinline__ void rsc_body(
    const float* in, unsigned short* out_hi, const float* h,
    int S, int R, int P, int bid, int nblk) {
  const long long qP = P >> 2;
  const long long nq = 2LL * R * qP;
  long long i = (long long)bid * 256 + threadIdx.x;
  const long long stride = (long long)nblk * 256;
  for (; i < nq; i += stride) {
    long long b = i / (R * qP);
    long long rem = i - b * (R * qP);
    int row = (int)(rem / qP);
    long long qc = rem - (long long)row * qP;
    const f32x4* base = (const f32x4*)in + ((b * S) * R + row) * qP + qc;
    f32x4 v = base[0];
    for (int s = 1; s < S; ++s) v += base[(long long)s * R * qP];
    v *= *(const f32x4*)(h + ((size_t)b * 8 + (row >> 5)) * P + (qc << 2));
    u16x4 hh = {f2bf(v[0]), f2bf(v[1]), f2bf(v[2]), f2bf(v[3])};
    ((u16x4*)out_hi)[i] = hh;
  }
}

__global__ void rsc2(const float* in1, unsigned short* o1h, const float* hF,
                     const float* in3, unsigned short* o3h, const float* hV) {
  if (blockIdx.x < 2048)
    rsc_body(in1, o1h, hF, 3, 256, 4096, blockIdx.x, 2048);
  else
    rsc_body(in3, o3h, hV, 6, 256, 2048, blockIdx.x - 2048, 1024);
}

// ---------------------------------------------------------------------------
// Merged hval dots: [0,3072) e/einv pairs from P1; [3072,5120) f pair from P3.
// ---------------------------------------------------------------------------
__global__ __launch_bounds__(256) void dots(
    const float* __restrict__ P1, float* __restrict__ hE, float* __restrict__ hEi,
    const float* __restrict__ P3, float* __restrict__ hF) {
  const int wv = threadIdx.x >> 6, lane = threadIdx.x & 63;
  if (blockIdx.x < 3072) {
    const int row = blockIdx.x * 4 + wv;
    const float* base = P1 + (size_t)row * 1280 + lane * 4;
    f32x4 qv = *(const f32x4*)(base);
    f32x4 kv = *(const f32x4*)(base + 256);
    float p = qv[0] * kv[0] + qv[1] * kv[1] + qv[2] * kv[2] + qv[3] * kv[3];
    p += __shfl_xor(p, 1); p += __shfl_xor(p, 2); p += __shfl_xor(p, 4);
    f32x4 q2 = *(const f32x4*)(base + 768);
    f32x4 k2 = *(const f32x4*)(base + 1024);
    float p2 = q2[0] * k2[0] + q2[1] * k2[1] + q2[2] * k2[2] + q2[3] * k2[3];
    p2 += __shfl_xor(p2, 1); p2 += __shfl_xor(p2, 2); p2 += __shfl_xor(p2, 4);
    if ((lane & 7) == 0) {
      const int head = lane >> 3;
      const int b = row / 6144, pos = row % 6144;
      hE[((size_t)b * 8 + head) * 6144 + pos] = p * 0.17677669529663687f;
      hEi[((size_t)b * 8 + head) * 6144 + pos] = p2 * 0.17677669529663687f;
    }
  } else {
    const int row = (blockIdx.x - 3072) * 4 + wv;
    const float* base = P3 + (size_t)row * 512 + lane * 4;
    f32x4 qv = *(const f32x4*)(base);
    f32x4 kv = *(const f32x4*)(base + 256);
    float p = qv[0] * kv[0] + qv[1] * kv[1] + qv[2] * kv[2] + qv[3] * kv[3];
    p += __shfl_xor(p, 1); p += __shfl_xor(p, 2); p += __shfl_xor(p, 4);
    if ((lane & 7) == 0) {
      const int head = lane >> 3;
      const int b = row / 4096, pos = row % 4096;
      hF[((size_t)b * 8 + head) * 4096 + pos] = p * 0.17677669529663687f;
    }
  }
}

// ---------------------------------------------------------------------------
extern "C" void kernel_launch(void* const* d_in, const int* in_sizes, int n_in,
                              void* d_out, int out_size, void* d_ws, size_t ws_size,
                              hipStream_t stream) {
  const float* x_v = (const float*)d_in[0];
  const float* x_e = (const float*)d_in[1];
  const float* x_f = (const float*)d_in[2];
  const float* d0  = (const float*)d_in[3];   // (2, 6144, 2048)
  const float* d1  = (const float*)d_in[4];   // (2, 4096, 6144)
  float* out = (float*)d_out;

  const int NV = 2048, ME = 6144, KF = 4096;

  char* ws = (char*)d_ws;
  size_t o = 0;
  auto alloc = [&](size_t bytes) { size_t r = o; o = (o + bytes + 255) & ~255ULL; return r; };

  unsigned short* Wcat5_hi = (unsigned short*)(ws + alloc(1280 * 256 * 2));
  unsigned short* Wcat5_lo = (unsigned short*)(ws + alloc(1280 * 256 * 2));
  unsigned short* W3_hi = (unsigned short*)(ws + alloc(512 * 256 * 2));
  unsigned short* Wo_hi = (unsigned short*)(ws + alloc(256 * 256 * 2));
  unsigned short* Wo_lo = (unsigned short*)(ws + alloc(256 * 256 * 2));
  float* pHvE  = (float*)(ws + alloc(2 * 8 * ME * 4));
  float* pHvEi = (float*)(ws + alloc(2 * 8 * ME * 4));
  float* pHvF  = (float*)(ws + alloc(2 * 8 * KF * 4));
  float* pHvV  = (float*)(ws + alloc(2 * 8 * NV * 4));
  unsigned short* d1T_hi = (unsigned short*)(ws + alloc((size_t)2 * ME * KF * 2));   // [2][6144][4096]
  unsigned short* d0T_hi = (unsigned short*)(ws + alloc((size_t)2 * NV * ME * 2));   // [2][2048][6144]
  unsigned short* eVT_hi = (unsigned short*)(ws + alloc((size_t)2 * 256 * ME * 2));
  unsigned short* Y0T_hi = (unsigned short*)(ws + alloc((size_t)2 * 256 * ME * 2));
  unsigned short* T1sT_hi = (unsigned short*)(ws + alloc((size_t)2 * 256 * KF * 2));
  unsigned short* T3sT_hi = (unsigned short*)(ws + alloc((size_t)2 * 256 * NV * 2));
  float* pP1 = (float*)(ws + alloc((size_t)12288 * 1280 * 4));
  float* pP3 = (float*)(ws + alloc((size_t)8192 * 512 * 4));
  float* pTp1 = (float*)(ws + alloc((size_t)2 * 3 * 256 * KF * 4));   // T1^T slabs
  float* pTp3 = (float*)(ws + alloc((size_t)2 * 6 * 256 * NV * 4));   // T3^T slabs
  float* pT2p = (float*)(ws + alloc((size_t)2 * 2 * ME * 256 * 4));
  float* pT4p = (float*)(ws + alloc((size_t)2 * 2 * ME * 256 * 4));

  dim3 blk(256);

  // --- mega-prep: vproj + weight transposes + d1T/d0T conversions ---
  PrepArgs pa;
  pa.wsrc[0] = (const float*)d_in[7];  pa.wh[0] = Wcat5_hi;          pa.wl[0] = Wcat5_lo;
  pa.wsrc[1] = (const float*)d_in[8];  pa.wh[1] = Wcat5_hi + 65536;  pa.wl[1] = Wcat5_lo + 65536;
  pa.wsrc[2] = (const float*)d_in[11]; pa.wh[2] = Wcat5_hi + 131072; pa.wl[2] = Wcat5_lo + 131072;
  pa.wsrc[3] = (const float*)d_in[9];  pa.wh[3] = Wcat5_hi + 196608; pa.wl[3] = Wcat5_lo + 196608;
  pa.wsrc[4] = (const float*)d_in[10]; pa.wh[4] = Wcat5_hi + 262144; pa.wl[4] = Wcat5_lo + 262144;
  pa.wsrc[5] = (const float*)d_in[12]; pa.wh[5] = W3_hi;             pa.wl[5] = nullptr;
  pa.wsrc[6] = (const float*)d_in[13]; pa.wh[6] = W3_hi + 65536;     pa.wl[6] = nullptr;
  pa.wsrc[7] = (const float*)d_in[14]; pa.wh[7] = Wo_hi;             pa.wl[7] = Wo_lo;
  pa.d1 = d1; pa.d1T = d1T_hi;
  pa.d0 = d0; pa.d0T_hi = d0T_hi;
  pa.xv = x_v; pa.Wvq = (const float*)d_in[5]; pa.Wvk = (const float*)d_in[6];
  pa.hvV = pHvV;
  prep_all<<<19072, blk, 0, stream>>>(pa);

  // --- projections (P1 + P3 in one launch) ---
  proj_dual<<<1216, blk, 0, stream>>>(x_e, Wcat5_hi, Wcat5_lo, pP1, x_f, W3_hi, pP3);
  dots<<<5120, blk, 0, stream>>>(pP1, pHvE, pHvEi, pP3, pHvF);
  xpose_ev<<<dim3(96, 4, 2), blk, 0, stream>>>(pP1, eVT_hi, Y0T_hi, pHvE);

  // --- T1 + T3 in one launch (T1: B = d1 fp32 cvt-in-staging) ---
  GJob jT1 = {}, jT3 = {};
  jT1.Ah = eVT_hi; jT1.Bf = d1; jT1.C = pTp1;
  jT1.K = ME; jT1.ldA = ME; jT1.ldB = ME; jT1.S = 3; jT1.gx = 2; jT1.gy = 32;
  jT1.sA = 256LL * ME; jT1.sB = (long long)KF * ME; jT1.sC = 256LL * KF;
  jT3.Ah = Y0T_hi; jT3.Bh = d0T_hi; jT3.C = pTp3;
  jT3.K = ME; jT3.ldA = ME; jT3.ldB = ME; jT3.S = 6; jT3.gx = 2; jT3.gy = 16;
  jT3.sA = 256LL * ME; jT3.sB = (long long)NV * ME; jT3.sC = 256LL * NV;
  gemm_dual<2, 0, true><<<768, blk, 0, stream>>>(jT1, jT3, 384);

  // --- reductions + scale + cvt ---
  rsc2<<<3072, blk, 0, stream>>>(pTp1, T1sT_hi, pHvF, pTp3, T3sT_hi, pHvV);

  // --- T2 + T4 in one launch (T4: A = d0 fp32 cvt-in-staging) ---
  GJob jT2 = {}, jT4 = {};
  jT2.Ah = d1T_hi; jT2.Bh = T1sT_hi; jT2.C = pT2p;
  jT2.K = KF; jT2.ldA = KF; jT2.ldB = KF; jT2.S = 2; jT2.gx = 48; jT2.gy = 2;
  jT2.sA = (long long)ME * KF; jT2.sB = 256LL * KF; jT2.sC = (long long)ME * 256;
  jT4.Af = d0; jT4.Bh = T3sT_hi; jT4.C = pT4p;
  jT4.K = NV; jT4.ldA = NV; jT4.ldB = NV; jT4.S = 2; jT4.gx = 48; jT4.gy = 2;
  jT4.sA = (long long)ME * NV; jT4.sB = 256LL * NV; jT4.sC = (long long)ME * 256;
  gemm_dual<0, 1, false><<<768, blk, 0, stream>>>(jT2, jT4, 384);

  // --- fused combine + output projection ---
  gemm_out<<<dim3(96, 2, 1), blk, 0, stream>>>(pT2p, pT4p, pHvEi, Wo_hi, Wo_lo, out);
}

// Round 17
// 379.385 us; speedup vs baseline: 1.1514x; 1.0273x over previous
//
#include <hip/hip_runtime.h>
#include <hip/hip_bf16.h>
#include <cstdint>
#include <cstddef>

// ---------------------------------------------------------------------------
// MeshMultiHeadHodgeLaplaceAttention  (b=2, n=2048, m=6144, k=4096, D=256, H=8)
//
//   up:   T1 = d_1 @ eV ; *f_hval ; T2 = d_1^T @ T1s ; (*einv_hval in combine)
//   down: Y0 = eV*e_hval ; T3 = d_0^T @ Y0 ; *1/(v_hval+eps) ; T4 = d_0 @ T3s
//   out = (T2*einv_hval + T4) @ W_o
//
// Precision: v_hval replicates numpy fp32 bit-exactly; P1 + output GEMM
// split-bf16; T1..T4 plain bf16 (validated R10-R16, absmax=256).
//
// R17: launch reorder for L3 temporal locality on d1 (201 MB fp32 read
// twice): wxpose (tiny) -> proj_dual -> dots -> xpose_ev -> prep2 with
// d1-pass LAST -> T1+T3 immediately (T1 reads d1 L3-warm). Zero arithmetic
// change vs R16.
// ---------------------------------------------------------------------------

typedef __attribute__((ext_vector_type(4))) float f32x4;
typedef __attribute__((ext_vector_type(2))) unsigned short u16x2;
typedef __attribute__((ext_vector_type(4))) unsigned short u16x4;
typedef __attribute__((ext_vector_type(8))) unsigned short u16x8;
typedef __attribute__((ext_vector_type(8))) __bf16 bf16x8;

static __device__ __forceinline__ unsigned short f2bf(float f) {
  uint32_t u = __builtin_bit_cast(uint32_t, f);
  uint32_t r = (u + 0x7FFFu + ((u >> 16) & 1u)) >> 16;  // RNE
  return (unsigned short)r;
}
static __device__ __forceinline__ float bf2f(unsigned short h) {
  return __builtin_bit_cast(float, (uint32_t)h << 16);
}
static __device__ __forceinline__ void st4(unsigned short* p, u16x4 v) {
  *(u16x2*)p = u16x2{v[0], v[1]};
  *(u16x2*)(p + 2) = u16x2{v[2], v[3]};
}

// ---------------------------------------------------------------------------
// Mode-templated GEMM body. MODE: 0 = A,B bf16 ; 1 = A fp32 cvt ; 2 = B fp32
// cvt. C[M x gy*128] = A[M x K] * B[N x K]; split-K z = batch*S + split.
// ---------------------------------------------------------------------------
struct GJob {
  const unsigned short* Ah; const float* Af;
  const unsigned short* Bh; const float* Bf;
  float* C;
  int K, ldA, ldB, S, gx, gy;
  long long sA, sB, sC;
};

template <int MODE, bool XFAST>
static __device__ void gemm_body(char* smem, const GJob& J, int b) {
  const int per = J.gx * J.gy;
  const int z = b / per;
  const int wid = b - z * per;
  const int batch = z / J.S, split = z - batch * J.S;
  const unsigned short* Ah = nullptr; const float* Af = nullptr;
  const unsigned short* Bh = nullptr; const float* Bf = nullptr;
  if constexpr (MODE == 1) Af = J.Af + (long long)batch * J.sA;
  else                     Ah = J.Ah + (long long)batch * J.sA;
  if constexpr (MODE == 2) Bf = J.Bf + (long long)batch * J.sB;
  else                     Bh = J.Bh + (long long)batch * J.sB;
  float* C = J.C + (long long)z * J.sC;

  const int nwg = per;
  const int q = nwg >> 3, r = nwg & 7;
  const int xcd = wid & 7, posn = wid >> 3;
  const int swz = (xcd < r ? xcd * (q + 1) : r * (q + 1) + (xcd - r) * q) + posn;
  int mt, nt;
  if constexpr (XFAST) { mt = swz % J.gx; nt = swz / J.gx; }
  else                 { mt = swz / J.gy; nt = swz - mt * J.gy; }
  const int m0 = mt * 128, n0 = nt * 128;
  const int NC = J.gy << 7;
  const int kLen = J.K / J.S, k0base = split * kLen;

  typedef unsigned short ldsrow[128][40];
  ldsrow* lds = (ldsrow*)smem;   // [2][128][40]

  const int t = threadIdx.x;
  const int w4 = t >> 6, lane = t & 63;
  const int wr = w4 >> 1, wc = w4 & 1;
  const int lr = lane & 15, kq = lane >> 4;
  const int rowV = t >> 2, c8V = (t & 3) * 8;     // bf16 staging
  const int rowA8 = t >> 3, qdA = (t & 7) * 4;    // fp32 staging

  u16x8 rAh[2], rBh[2];
  f32x4 rF[4];

  auto LOAD = [&](int kb) {
    if constexpr (MODE == 1) {
      #pragma unroll
      for (int a = 0; a < 4; ++a)
        rF[a] = *(const f32x4*)(Af + (size_t)(m0 + rowA8 + 32 * a) * J.ldA + kb + qdA);
    } else {
      #pragma unroll
      for (int a = 0; a < 2; ++a)
        rAh[a] = *(const u16x8*)(Ah + (size_t)(m0 + rowV + 64 * a) * J.ldA + kb + c8V);
    }
    if constexpr (MODE == 2) {
      #pragma unroll
      for (int a = 0; a < 4; ++a)
        rF[a] = *(const f32x4*)(Bf + (size_t)(n0 + rowA8 + 32 * a) * J.ldB + kb + qdA);
    } else {
      #pragma unroll
      for (int a = 0; a < 2; ++a)
        rBh[a] = *(const u16x8*)(Bh + (size_t)(n0 + rowV + 64 * a) * J.ldB + kb + c8V);
    }
  };
  auto STORE = [&]() {
    if constexpr (MODE == 1) {
      #pragma unroll
      for (int a = 0; a < 4; ++a) {
        f32x4 v = rF[a];
        u16x4 h = {f2bf(v[0]), f2bf(v[1]), f2bf(v[2]), f2bf(v[3])};
        *(u16x4*)&lds[0][rowA8 + 32 * a][qdA] = h;
      }
    } else {
      #pragma unroll
      for (int a = 0; a < 2; ++a) *(u16x8*)&lds[0][rowV + 64 * a][c8V] = rAh[a];
    }
    if constexpr (MODE == 2) {
      #pragma unroll
      for (int a = 0; a < 4; ++a) {
        f32x4 v = rF[a];
        u16x4 h = {f2bf(v[0]), f2bf(v[1]), f2bf(v[2]), f2bf(v[3])};
        *(u16x4*)&lds[1][rowA8 + 32 * a][qdA] = h;
      }
    } else {
      #pragma unroll
      for (int a = 0; a < 2; ++a) *(u16x8*)&lds[1][rowV + 64 * a][c8V] = rBh[a];
    }
  };

  f32x4 acc[4][4] = {};
  LOAD(k0base);
  for (int kk = 0; kk < kLen; kk += 32) {
    STORE();
    __syncthreads();
    if (kk + 32 < kLen) LOAD(k0base + kk + 32);  // prefetch under MFMA

    bf16x8 ah[4], bh[4];
    #pragma unroll
    for (int i = 0; i < 4; ++i) {
      ah[i] = __builtin_bit_cast(bf16x8, *(const u16x8*)&lds[0][wr * 64 + i * 16 + lr][kq * 8]);
      bh[i] = __builtin_bit_cast(bf16x8, *(const u16x8*)&lds[1][wc * 64 + i * 16 + lr][kq * 8]);
    }
    #pragma unroll
    for (int i = 0; i < 4; ++i)
      #pragma unroll
      for (int j = 0; j < 4; ++j)
        acc[i][j] = __builtin_amdgcn_mfma_f32_16x16x32_bf16(ah[i], bh[j], acc[i][j], 0, 0, 0);
    __syncthreads();
  }

  #pragma unroll
  for (int i = 0; i < 4; ++i)
    #pragma unroll
    for (int j = 0; j < 4; ++j) {
      float* cp = C + (size_t)(m0 + wr * 64 + i * 16 + kq * 4) * NC + n0 + wc * 64 + j * 16 + lr;
      #pragma unroll
      for (int qq = 0; qq < 4; ++qq) cp[(size_t)qq * NC] = acc[i][j][qq];
    }
}

template <int M0, int M1, bool XFAST>
__global__ __launch_bounds__(256) void gemm_dual(GJob j0, GJob j1, int nb0) {
  __shared__ __align__(16) unsigned short lds[2][128][40];
  if ((int)blockIdx.x < nb0) gemm_body<M0, XFAST>((char*)lds, j0, blockIdx.x);
  else                       gemm_body<M1, XFAST>((char*)lds, j1, blockIdx.x - nb0);
}

// ---------------------------------------------------------------------------
// Projection GEMM body (K=256): C = A fp32 (cvt) * B bf16 hi(/lo).
// ---------------------------------------------------------------------------
template <bool SPLIT>
static __device__ void proj_body(char* smem, int wid, int gx, int gy,
                                 const float* __restrict__ Af,
                                 const unsigned short* __restrict__ Bh,
                                 const unsigned short* __restrict__ Bl,
                                 float* __restrict__ C) {
  const int nwg = gx * gy;
  const int q = nwg >> 3, r = nwg & 7;
  const int xcd = wid & 7, posn = wid >> 3;
  const int swz = (xcd < r ? xcd * (q + 1) : r * (q + 1) + (xcd - r) * q) + posn;
  const int mt = swz / gy;
  const int m0 = mt * 128, n0 = (swz - mt * gy) * 128;
  const int NC = gy << 7;

  typedef unsigned short ldsrow[128][40];
  ldsrow* lds = (ldsrow*)smem;

  const int t = threadIdx.x;
  const int w4 = t >> 6, lane = t & 63;
  const int wr = w4 >> 1, wc = w4 & 1;
  const int lr = lane & 15, kq = lane >> 4;
  const int rowA8 = t >> 3, qdA = (t & 7) * 4;
  const int rowV = t >> 2, c8V = (t & 3) * 8;

  f32x4 rAf[4];
  u16x8 rBh[2], rBl[2];

  auto LOAD = [&](int kb) {
    #pragma unroll
    for (int a = 0; a < 4; ++a)
      rAf[a] = *(const f32x4*)(Af + (size_t)(m0 + rowA8 + 32 * a) * 256 + kb + qdA);
    #pragma unroll
    for (int a = 0; a < 2; ++a) {
      rBh[a] = *(const u16x8*)(Bh + (size_t)(n0 + rowV + 64 * a) * 256 + kb + c8V);
      if constexpr (SPLIT)
        rBl[a] = *(const u16x8*)(Bl + (size_t)(n0 + rowV + 64 * a) * 256 + kb + c8V);
    }
  };
  auto STORE = [&]() {
    #pragma unroll
    for (int a = 0; a < 4; ++a) {
      f32x4 v = rAf[a];
      u16x4 h = {f2bf(v[0]), f2bf(v[1]), f2bf(v[2]), f2bf(v[3])};
      *(u16x4*)&lds[0][rowA8 + 32 * a][qdA] = h;
      if constexpr (SPLIT) {
        u16x4 l = {f2bf(v[0] - bf2f(h[0])), f2bf(v[1] - bf2f(h[1])),
                   f2bf(v[2] - bf2f(h[2])), f2bf(v[3] - bf2f(h[3]))};
        *(u16x4*)&lds[2][rowA8 + 32 * a][qdA] = l;
      }
    }
    #pragma unroll
    for (int a = 0; a < 2; ++a) {
      *(u16x8*)&lds[1][rowV + 64 * a][c8V] = rBh[a];
      if constexpr (SPLIT) *(u16x8*)&lds[3][rowV + 64 * a][c8V] = rBl[a];
    }
  };

  f32x4 acc[4][4] = {};
  LOAD(0);
  for (int kk = 0; kk < 256; kk += 32) {
    STORE();
    __syncthreads();
    if (kk + 32 < 256) LOAD(kk + 32);

    bf16x8 ah[4], bh[4], al[4], bl[4];
    #pragma unroll
    for (int i = 0; i < 4; ++i) {
      ah[i] = __builtin_bit_cast(bf16x8, *(const u16x8*)&lds[0][wr * 64 + i * 16 + lr][kq * 8]);
      bh[i] = __builtin_bit_cast(bf16x8, *(const u16x8*)&lds[1][wc * 64 + i * 16 + lr][kq * 8]);
      if constexpr (SPLIT) {
        al[i] = __builtin_bit_cast(bf16x8, *(const u16x8*)&lds[2][wr * 64 + i * 16 + lr][kq * 8]);
        bl[i] = __builtin_bit_cast(bf16x8, *(const u16x8*)&lds[3][wc * 64 + i * 16 + lr][kq * 8]);
      }
    }
    #pragma unroll
    for (int i = 0; i < 4; ++i)
      #pragma unroll
      for (int j = 0; j < 4; ++j) {
        acc[i][j] = __builtin_amdgcn_mfma_f32_16x16x32_bf16(ah[i], bh[j], acc[i][j], 0, 0, 0);
        if constexpr (SPLIT) {
          acc[i][j] = __builtin_amdgcn_mfma_f32_16x16x32_bf16(ah[i], bl[j], acc[i][j], 0, 0, 0);
          acc[i][j] = __builtin_amdgcn_mfma_f32_16x16x32_bf16(al[i], bh[j], acc[i][j], 0, 0, 0);
        }
      }
    __syncthreads();
  }

  #pragma unroll
  for (int i = 0; i < 4; ++i)
    #pragma unroll
    for (int j = 0; j < 4; ++j) {
      float* cp = C + (size_t)(m0 + wr * 64 + i * 16 + kq * 4) * NC + n0 + wc * 64 + j * 16 + lr;
      #pragma unroll
      for (int qq = 0; qq < 4; ++qq) cp[(size_t)qq * NC] = acc[i][j][qq];
    }
}

// P1 (split, 960 blocks) + P3 (plain, 256 blocks) in one launch.
__global__ __launch_bounds__(256) void proj_dual(
    const float* __restrict__ xe, const unsigned short* __restrict__ W5h,
    const unsigned short* __restrict__ W5l, float* __restrict__ P1,
    const float* __restrict__ xf, const unsigned short* __restrict__ W3h,
    float* __restrict__ P3) {
  __shared__ __align__(16) unsigned short lds[4][128][40];
  if ((int)blockIdx.x < 960)
    proj_body<true>((char*)lds, blockIdx.x, 96, 10, xe, W5h, W5l, P1);
  else
    proj_body<false>((char*)lds, blockIdx.x - 960, 64, 4, xf, W3h, nullptr, P3);
}

// ---------------------------------------------------------------------------
// Output GEMM with fused combine: A[r][c] = (T4p 2-slab sum) +
// (T2p 2-slab sum)*einv_hval;  C = A @ W_o (split hi/lo). M=12288,N=256,K=256.
// ---------------------------------------------------------------------------
__global__ __launch_bounds__(256) void gemm_out(
    const float* __restrict__ T2p, const float* __restrict__ T4p,
    const float* __restrict__ hEi, const unsigned short* __restrict__ Bh,
    const unsigned short* __restrict__ Bl, float* __restrict__ C) {
  const int gx = gridDim.x, gy = gridDim.y;
  const int nwg = gx * gy;
  const int wid = blockIdx.x + gx * blockIdx.y;
  const int q = nwg >> 3, r = nwg & 7;
  const int xcd = wid & 7, posn = wid >> 3;
  const int swz = (xcd < r ? xcd * (q + 1) : r * (q + 1) + (xcd - r) * q) + posn;
  const int mt = swz / gy;
  const int m0 = mt * 128, n0 = (swz - mt * gy) * 128;

  __shared__ unsigned short lds[4][128][40];
  const int t = threadIdx.x;
  const int w4 = t >> 6, lane = t & 63;
  const int wr = w4 >> 1, wc = w4 & 1;
  const int lr = lane & 15, kq = lane >> 4;
  const long long slab = 6144LL * 256;

  f32x4 acc[4][4] = {};

  for (int kb = 0; kb < 256; kb += 32) {
    #pragma unroll
    for (int a = 0; a < 4; ++a) {
      int idx = t + 256 * a;
      int row = idx >> 3, qd = (idx & 7) * 4;
      int rg = m0 + row;
      int b = rg >= 6144;
      int pos = rg - b * 6144;
      int ck = kb + qd;
      float s = hEi[((size_t)b * 8 + (ck >> 5)) * 6144 + pos];
      const float* b2 = T2p + ((long long)(b * 2) * 6144 + pos) * 256 + ck;
      const float* b4 = T4p + ((long long)(b * 2) * 6144 + pos) * 256 + ck;
      f32x4 t2 = *(const f32x4*)b2 + *(const f32x4*)(b2 + slab);
      f32x4 t4 = *(const f32x4*)b4 + *(const f32x4*)(b4 + slab);
      f32x4 v = t4 + t2 * s;
      u16x4 h = {f2bf(v[0]), f2bf(v[1]), f2bf(v[2]), f2bf(v[3])};
      *(u16x4*)&lds[0][row][qd] = h;
      u16x4 l = {f2bf(v[0] - bf2f(h[0])), f2bf(v[1] - bf2f(h[1])),
                 f2bf(v[2] - bf2f(h[2])), f2bf(v[3] - bf2f(h[3]))};
      *(u16x4*)&lds[2][row][qd] = l;
    }
    #pragma unroll
    for (int a = 0; a < 2; ++a) {
      int idx = t + 256 * a;
      int row = idx >> 2, c8 = (idx & 3) * 8;
      *(u16x8*)&lds[1][row][c8] = *(const u16x8*)(Bh + (size_t)(n0 + row) * 256 + kb + c8);
      *(u16x8*)&lds[3][row][c8] = *(const u16x8*)(Bl + (size_t)(n0 + row) * 256 + kb + c8);
    }
    __syncthreads();

    bf16x8 ah[4], bh[4], al[4], bl[4];
    #pragma unroll
    for (int i = 0; i < 4; ++i) {
      ah[i] = __builtin_bit_cast(bf16x8, *(const u16x8*)&lds[0][wr * 64 + i * 16 + lr][kq * 8]);
      bh[i] = __builtin_bit_cast(bf16x8, *(const u16x8*)&lds[1][wc * 64 + i * 16 + lr][kq * 8]);
      al[i] = __builtin_bit_cast(bf16x8, *(const u16x8*)&lds[2][wr * 64 + i * 16 + lr][kq * 8]);
      bl[i] = __builtin_bit_cast(bf16x8, *(const u16x8*)&lds[3][wc * 64 + i * 16 + lr][kq * 8]);
    }
    #pragma unroll
    for (int i = 0; i < 4; ++i)
      #pragma unroll
      for (int j = 0; j < 4; ++j) {
        acc[i][j] = __builtin_amdgcn_mfma_f32_16x16x32_bf16(ah[i], bh[j], acc[i][j], 0, 0, 0);
        acc[i][j] = __builtin_amdgcn_mfma_f32_16x16x32_bf16(ah[i], bl[j], acc[i][j], 0, 0, 0);
        acc[i][j] = __builtin_amdgcn_mfma_f32_16x16x32_bf16(al[i], bh[j], acc[i][j], 0, 0, 0);
      }
    __syncthreads();
  }

  #pragma unroll
  for (int i = 0; i < 4; ++i)
    #pragma unroll
    for (int j = 0; j < 4; ++j) {
      float* cp = C + (size_t)(m0 + wr * 64 + i * 16 + kq * 4) * 256 + n0 + wc * 64 + j * 16 + lr;
      #pragma unroll
      for (int qq = 0; qq < 4; ++qq) cp[(size_t)qq * 256] = acc[i][j][qq];
    }
}

// ---------------------------------------------------------------------------
// Weight transposes (tiny standalone launch, 128 blocks, 74-stride tiles).
// ---------------------------------------------------------------------------
struct WTab {
  const float* s[8];
  unsigned short* h[8];
  unsigned short* l[8];
};
__global__ __launch_bounds__(256) void wxpose(WTab tab) {
  __shared__ __align__(16) unsigned short smem[2 * 64 * 74];
  unsigned short* thi = smem;
  unsigned short* tlo = smem + 64 * 74;
  const int idx = blockIdx.x;
  const int w = idx >> 4;
  const int r0 = (idx & 3) * 64, c0 = ((idx >> 2) & 3) * 64;
  const float* src = tab.s[w];
  unsigned short* oh = tab.h[w];
  unsigned short* ol = tab.l[w];
  const int t = threadIdx.x;
  #pragma unroll
  for (int a = 0; a < 4; ++a) {
    int idx2 = t + 256 * a;
    int tr = idx2 >> 4, tc = (idx2 & 15) * 4;
    f32x4 v = *(const f32x4*)(src + (size_t)(r0 + tr) * 256 + c0 + tc);
    u16x4 hh = {f2bf(v[0]), f2bf(v[1]), f2bf(v[2]), f2bf(v[3])};
    st4(&thi[tr * 74 + tc], hh);
    if (ol) {
      u16x4 ll = {f2bf(v[0] - bf2f(hh[0])), f2bf(v[1] - bf2f(hh[1])),
                  f2bf(v[2] - bf2f(hh[2])), f2bf(v[3] - bf2f(hh[3]))};
      st4(&tlo[tr * 74 + tc], ll);
    }
  }
  __syncthreads();
  #pragma unroll
  for (int a = 0; a < 2; ++a) {
    int idx2 = t + 256 * a;
    int orow = idx2 >> 3, oc = (idx2 & 7) * 8;
    u16x8 vh;
    #pragma unroll
    for (int j = 0; j < 8; ++j) vh[j] = thi[(oc + j) * 74 + orow];
    *(u16x8*)(oh + (size_t)(c0 + orow) * 256 + r0 + oc) = vh;
    if (ol) {
      u16x8 vl;
      #pragma unroll
      for (int j = 0; j < 8; ++j) vl[j] = tlo[(oc + j) * 74 + orow];
      *(u16x8*)(ol + (size_t)(c0 + orow) * 256 + r0 + oc) = vl;
    }
  }
}

// ---------------------------------------------------------------------------
// prep2: [0,512) vproj ; [512,6656) d0 -> d0T ; [6656,18944) d1 -> d1T (LAST,
// so d1 stays L3-warm for the immediately following T1). 74-stride tiles.
// ---------------------------------------------------------------------------
struct PrepArgs {
  const float* d1; unsigned short* d1T;
  const float* d0; unsigned short* d0T_hi;
  const float* xv; const float* Wvq; const float* Wvk; float* hvV;
};

__global__ __launch_bounds__(256) void prep2(PrepArgs A) {
  __shared__ __align__(16) char smem[24576];
  const int t = threadIdx.x;
  const int bid = blockIdx.x;

  if (bid < 512) {
    // ---- vproj (np-fp32 exact, 8 rows/block) ----
    float* sx = (float*)smem;
    float* sq = (float*)(smem + 8192);
    float* sk = (float*)(smem + 16384);
    const int r0 = bid * 8;
    const int j = t;
    #pragma unroll
    for (int r = 0; r < 8; ++r) sx[r * 256 + j] = A.xv[(size_t)(r0 + r) * 256 + j];
    __syncthreads();
    float qa[8] = {}, ka[8] = {};
    for (int i = 0; i < 256; ++i) {
      float wq = A.Wvq[i * 256 + j], wk = A.Wvk[i * 256 + j];
      #pragma unroll
      for (int r = 0; r < 8; ++r) {
        qa[r] = __fmaf_rn(sx[r * 256 + i], wq, qa[r]);
        ka[r] = __fmaf_rn(sx[r * 256 + i], wk, ka[r]);
      }
    }
    #pragma unroll
    for (int r = 0; r < 8; ++r) { sq[r * 256 + j] = qa[r]; sk[r * 256 + j] = ka[r]; }
    __syncthreads();
    if (j < 64) {
      const int r = j >> 3, head = j & 7;
      const float* qq = &sq[r * 256 + head * 32];
      const float* kk = &sk[r * 256 + head * 32];
      float s0 = 0.0f, s1 = 0.0f, s2 = 0.0f, s3 = 0.0f;
      #pragma unroll 1
      for (int d = 0; d < 32; d += 4) {
        s0 = __fadd_rn(s0, __fmul_rn(qq[d + 0], kk[d + 0]));
        s1 = __fadd_rn(s1, __fmul_rn(qq[d + 1], kk[d + 1]));
        s2 = __fadd_rn(s2, __fmul_rn(qq[d + 2], kk[d + 2]));
        s3 = __fadd_rn(s3, __fmul_rn(qq[d + 3], kk[d + 3]));
      }
      float p = __fadd_rn(__fadd_rn(s0, s2), __fadd_rn(s1, s3));
      float hval = __fdiv_rn(p, sqrtf(32.0f));
      float inv = __fdiv_rn(1.0f, __fadd_rn(hval, 1e-6f));
      const int row = r0 + r;
      const int b = row / 2048, pos = row - b * 2048;
      A.hvV[((size_t)b * 8 + head) * 2048 + pos] = inv;
    }
  } else if (bid < 6656) {
    // ---- d0: [2][6144][2048] fp32 -> d0T bf16 (96x32x2 tiles) ----
    const int idx = bid - 512;
    const int x = idx % 96;
    const int rem = idx / 96;
    const int y = rem & 31;
    const int b = rem >> 5;
    const int r0 = x * 64, c0 = y * 64;
    unsigned short* tile = (unsigned short*)smem;   // [64][74]
    #pragma unroll
    for (int a = 0; a < 4; ++a) {
      int idx2 = t + 256 * a;
      int tr = idx2 >> 4, tc = (idx2 & 15) * 4;
      size_t off = ((size_t)b * 6144 + r0 + tr) * 2048 + c0 + tc;
      f32x4 v = *(const f32x4*)(A.d0 + off);
      u16x4 hh = {f2bf(v[0]), f2bf(v[1]), f2bf(v[2]), f2bf(v[3])};
      st4(&tile[tr * 74 + tc], hh);
    }
    __syncthreads();
    #pragma unroll
    for (int a = 0; a < 2; ++a) {
      int idx2 = t + 256 * a;
      int orow = idx2 >> 3, oc = (idx2 & 7) * 8;
      u16x8 vh;
      #pragma unroll
      for (int j = 0; j < 8; ++j) vh[j] = tile[(oc + j) * 74 + orow];
      *(u16x8*)(A.d0T_hi + ((size_t)b * 2048 + c0 + orow) * 6144 + r0 + oc) = vh;
    }
  } else {
    // ---- d1: [2][4096][6144] fp32 -> d1T bf16 (64x96x2 tiles, LAST) ----
    const int idx = bid - 6656;
    const int x = idx & 63;
    const int rem = idx >> 6;
    const int y = rem % 96;
    const int b = rem / 96;
    const int r0 = x * 64, c0 = y * 64;
    unsigned short* tile = (unsigned short*)smem;   // [64][74]
    #pragma unroll
    for (int a = 0; a < 4; ++a) {
      int idx2 = t + 256 * a;
      int tr = idx2 >> 4, tc = (idx2 & 15) * 4;
      size_t off = ((size_t)b * 4096 + r0 + tr) * 6144 + c0 + tc;
      f32x4 v = *(const f32x4*)(A.d1 + off);
      u16x4 hh = {f2bf(v[0]), f2bf(v[1]), f2bf(v[2]), f2bf(v[3])};
      st4(&tile[tr * 74 + tc], hh);
    }
    __syncthreads();
    #pragma unroll
    for (int a = 0; a < 2; ++a) {
      int idx2 = t + 256 * a;
      int orow = idx2 >> 3, oc = (idx2 & 7) * 8;
      u16x8 vh;
      #pragma unroll
      for (int j = 0; j < 8; ++j) vh[j] = tile[(oc + j) * 74 + orow];
      *(u16x8*)(A.d1T + ((size_t)b * 6144 + c0 + orow) * 4096 + r0 + oc) = vh;
    }
  }
}

// ---------------------------------------------------------------------------
// Fused eVT (unscaled bf16) + Y0T (scaled bf16) from P1 cols 512..767.
// ---------------------------------------------------------------------------
__global__ __launch_bounds__(256) void xpose_ev(
    const float* __restrict__ P1, unsigned short* __restrict__ eVT,
    unsigned short* __restrict__ yhi, const float* __restrict__ hE) {
  __shared__ __align__(16) unsigned short smem[2 * 64 * 74];
  unsigned short* te = smem;
  unsigned short* th = smem + 64 * 74;
  const int b = blockIdx.z;
  const int r0 = blockIdx.x * 64, c0 = blockIdx.y * 64;
  const int t = threadIdx.x;
  #pragma unroll
  for (int a = 0; a < 4; ++a) {
    int idx = t + 256 * a;
    int tr = idx >> 4, tc = (idx & 15) * 4;
    f32x4 v = *(const f32x4*)(P1 + ((size_t)b * 6144 + r0 + tr) * 1280 + 512 + c0 + tc);
    u16x4 eh = {f2bf(v[0]), f2bf(v[1]), f2bf(v[2]), f2bf(v[3])};
    st4(&te[tr * 74 + tc], eh);
    float s = hE[((size_t)b * 8 + ((c0 + tc) >> 5)) * 6144 + r0 + tr];
    f32x4 y = v * s;
    u16x4 hh = {f2bf(y[0]), f2bf(y[1]), f2bf(y[2]), f2bf(y[3])};
    st4(&th[tr * 74 + tc], hh);
  }
  __syncthreads();
  #pragma unroll
  for (int a = 0; a < 2; ++a) {
    int idx = t + 256 * a;
    int orow = idx >> 3, oc = (idx & 7) * 8;
    u16x8 ve, vh;
    #pragma unroll
    for (int j = 0; j < 8; ++j) {
      ve[j] = te[(oc + j) * 74 + orow];
      vh[j] = th[(oc + j) * 74 + orow];
    }
    size_t o = ((size_t)b * 256 + c0 + orow) * 6144 + r0 + oc;
    *(u16x8*)(eVT + o) = ve;
    *(u16x8*)(yhi + o) = vh;
  }
}

// ---------------------------------------------------------------------------
// Merged rsc_cvt (sum S slabs ascending, scale, cvt bf16).
// ---------------------------------------------------------------------------
static __device__ __forceinline__ void rsc_body(
    const float* in, unsigned short* out_hi, const float* h,
    int S, int R, int P, int bid, int nblk) {
  const long long qP = P >> 2;
  const long long nq = 2LL * R * qP;
  long long i = (long long)bid * 256 + threadIdx.x;
  const long long stride = (long long)nblk * 256;
  for (; i < nq; i += stride) {
    long long b = i / (R * qP);
    long long rem = i - b * (R * qP);
    int row = (int)(rem / qP);
    long long qc = rem - (long long)row * qP;
    const f32x4* base = (const f32x4*)in + ((b * S) * R + row) * qP + qc;
    f32x4 v = base[0];
    for (int s = 1; s < S; ++s) v += base[(long long)s * R * qP];
    v *= *(const f32x4*)(h + ((size_t)b * 8 + (row >> 5)) * P + (qc << 2));
    u16x4 hh = {f2bf(v[0]), f2bf(v[1]), f2bf(v[2]), f2bf(v[3])};
    ((u16x4*)out_hi)[i] = hh;
  }
}

__global__ void rsc2(const float* in1, unsigned short* o1h, const float* hF,
                     const float* in3, unsigned short* o3h, const float* hV) {
  if (blockIdx.x < 2048)
    rsc_body(in1, o1h, hF, 3, 256, 4096, blockIdx.x, 2048);
  else
    rsc_body(in3, o3h, hV, 6, 256, 2048, blockIdx.x - 2048, 1024);
}

// ---------------------------------------------------------------------------
// Merged hval dots: [0,3072) e/einv pairs from P1; [3072,5120) f pair from P3.
// ---------------------------------------------------------------------------
__global__ __launch_bounds__(256) void dots(
    const float* __restrict__ P1, float* __restrict__ hE, float* __restrict__ hEi,
    const float* __restrict__ P3, float* __restrict__ hF) {
  const int wv = threadIdx.x >> 6, lane = threadIdx.x & 63;
  if (blockIdx.x < 3072) {
    const int row = blockIdx.x * 4 + wv;
    const float* base = P1 + (size_t)row * 1280 + lane * 4;
    f32x4 qv = *(const f32x4*)(base);
    f32x4 kv = *(const f32x4*)(base + 256);
    float p = qv[0] * kv[0] + qv[1] * kv[1] + qv[2] * kv[2] + qv[3] * kv[3];
    p += __shfl_xor(p, 1); p += __shfl_xor(p, 2); p += __shfl_xor(p, 4);
    f32x4 q2 = *(const f32x4*)(base + 768);
    f32x4 k2 = *(const f32x4*)(base + 1024);
    float p2 = q2[0] * k2[0] + q2[1] * k2[1] + q2[2] * k2[2] + q2[3] * k2[3];
    p2 += __shfl_xor(p2, 1); p2 += __shfl_xor(p2, 2); p2 += __shfl_xor(p2, 4);
    if ((lane & 7) == 0) {
      const int head = lane >> 3;
      const int b = row / 6144, pos = row % 6144;
      hE[((size_t)b * 8 + head) * 6144 + pos] = p * 0.17677669529663687f;
      hEi[((size_t)b * 8 + head) * 6144 + pos] = p2 * 0.17677669529663687f;
    }
  } else {
    const int row = (blockIdx.x - 3072) * 4 + wv;
    const float* base = P3 + (size_t)row * 512 + lane * 4;
    f32x4 qv = *(const f32x4*)(base);
    f32x4 kv = *(const f32x4*)(base + 256);
    float p = qv[0] * kv[0] + qv[1] * kv[1] + qv[2] * kv[2] + qv[3] * kv[3];
    p += __shfl_xor(p, 1); p += __shfl_xor(p, 2); p += __shfl_xor(p, 4);
    if ((lane & 7) == 0) {
      const int head = lane >> 3;
      const int b = row / 4096, pos = row % 4096;
      hF[((size_t)b * 8 + head) * 4096 + pos] = p * 0.17677669529663687f;
    }
  }
}

// ---------------------------------------------------------------------------
extern "C" void kernel_launch(void* const* d_in, const int* in_sizes, int n_in,
                              void* d_out, int out_size, void* d_ws, size_t ws_size,
                              hipStream_t stream) {
  const float* x_v = (const float*)d_in[0];
  const float* x_e = (const float*)d_in[1];
  const float* x_f = (const float*)d_in[2];
  const float* d0  = (const float*)d_in[3];   // (2, 6144, 2048)
  const float* d1  = (const float*)d_in[4];   // (2, 4096, 6144)
  float* out = (float*)d_out;

  const int NV = 2048, ME = 6144, KF = 4096;

  char* ws = (char*)d_ws;
  size_t o = 0;
  auto alloc = [&](size_t bytes) { size_t r = o; o = (o + bytes + 255) & ~255ULL; return r; };

  unsigned short* Wcat5_hi = (unsigned short*)(ws + alloc(1280 * 256 * 2));
  unsigned short* Wcat5_lo = (unsigned short*)(ws + alloc(1280 * 256 * 2));
  unsigned short* W3_hi = (unsigned short*)(ws + alloc(512 * 256 * 2));
  unsigned short* Wo_hi = (unsigned short*)(ws + alloc(256 * 256 * 2));
  unsigned short* Wo_lo = (unsigned short*)(ws + alloc(256 * 256 * 2));
  float* pHvE  = (float*)(ws + alloc(2 * 8 * ME * 4));
  float* pHvEi = (float*)(ws + alloc(2 * 8 * ME * 4));
  float* pHvF  = (float*)(ws + alloc(2 * 8 * KF * 4));
  float* pHvV  = (float*)(ws + alloc(2 * 8 * NV * 4));
  unsigned short* d1T_hi = (unsigned short*)(ws + alloc((size_t)2 * ME * KF * 2));   // [2][6144][4096]
  unsigned short* d0T_hi = (unsigned short*)(ws + alloc((size_t)2 * NV * ME * 2));   // [2][2048][6144]
  unsigned short* eVT_hi = (unsigned short*)(ws + alloc((size_t)2 * 256 * ME * 2));
  unsigned short* Y0T_hi = (unsigned short*)(ws + alloc((size_t)2 * 256 * ME * 2));
  unsigned short* T1sT_hi = (unsigned short*)(ws + alloc((size_t)2 * 256 * KF * 2));
  unsigned short* T3sT_hi = (unsigned short*)(ws + alloc((size_t)2 * 256 * NV * 2));
  float* pP1 = (float*)(ws + alloc((size_t)12288 * 1280 * 4));
  float* pP3 = (float*)(ws + alloc((size_t)8192 * 512 * 4));
  float* pTp1 = (float*)(ws + alloc((size_t)2 * 3 * 256 * KF * 4));   // T1^T slabs
  float* pTp3 = (float*)(ws + alloc((size_t)2 * 6 * 256 * NV * 4));   // T3^T slabs
  float* pT2p = (float*)(ws + alloc((size_t)2 * 2 * ME * 256 * 4));
  float* pT4p = (float*)(ws + alloc((size_t)2 * 2 * ME * 256 * 4));

  dim3 blk(256);

  // --- weight transposes (tiny) ---
  WTab tab;
  tab.s[0] = (const float*)d_in[7];  tab.h[0] = Wcat5_hi;          tab.l[0] = Wcat5_lo;
  tab.s[1] = (const float*)d_in[8];  tab.h[1] = Wcat5_hi + 65536;  tab.l[1] = Wcat5_lo + 65536;
  tab.s[2] = (const float*)d_in[11]; tab.h[2] = Wcat5_hi + 131072; tab.l[2] = Wcat5_lo + 131072;
  tab.s[3] = (const float*)d_in[9];  tab.h[3] = Wcat5_hi + 196608; tab.l[3] = Wcat5_lo + 196608;
  tab.s[4] = (const float*)d_in[10]; tab.h[4] = Wcat5_hi + 262144; tab.l[4] = Wcat5_lo + 262144;
  tab.s[5] = (const float*)d_in[12]; tab.h[5] = W3_hi;             tab.l[5] = nullptr;
  tab.s[6] = (const float*)d_in[13]; tab.h[6] = W3_hi + 65536;     tab.l[6] = nullptr;
  tab.s[7] = (const float*)d_in[14]; tab.h[7] = Wo_hi;             tab.l[7] = Wo_lo;
  wxpose<<<128, blk, 0, stream>>>(tab);

  // --- projections + hvals (before the d-conversions, so d1 stays L3-warm) ---
  proj_dual<<<1216, blk, 0, stream>>>(x_e, Wcat5_hi, Wcat5_lo, pP1, x_f, W3_hi, pP3);
  dots<<<5120, blk, 0, stream>>>(pP1, pHvE, pHvEi, pP3, pHvF);
  xpose_ev<<<dim3(96, 4, 2), blk, 0, stream>>>(pP1, eVT_hi, Y0T_hi, pHvE);

  // --- prep2: vproj + d0T + d1T (d1 LAST -> L3-warm for T1) ---
  PrepArgs pa;
  pa.d1 = d1; pa.d1T = d1T_hi;
  pa.d0 = d0; pa.d0T_hi = d0T_hi;
  pa.xv = x_v; pa.Wvq = (const float*)d_in[5]; pa.Wvk = (const float*)d_in[6];
  pa.hvV = pHvV;
  prep2<<<18944, blk, 0, stream>>>(pa);

  // --- T1 + T3 immediately (T1: B = d1 fp32, L3-warm) ---
  GJob jT1 = {}, jT3 = {};
  jT1.Ah = eVT_hi; jT1.Bf = d1; jT1.C = pTp1;
  jT1.K = ME; jT1.ldA = ME; jT1.ldB = ME; jT1.S = 3; jT1.gx = 2; jT1.gy = 32;
  jT1.sA = 256LL * ME; jT1.sB = (long long)KF * ME; jT1.sC = 256LL * KF;
  jT3.Ah = Y0T_hi; jT3.Bh = d0T_hi; jT3.C = pTp3;
  jT3.K = ME; jT3.ldA = ME; jT3.ldB = ME; jT3.S = 6; jT3.gx = 2; jT3.gy = 16;
  jT3.sA = 256LL * ME; jT3.sB = (long long)NV * ME; jT3.sC = 256LL * NV;
  gemm_dual<2, 0, true><<<768, blk, 0, stream>>>(jT1, jT3, 384);

  // --- reductions + scale + cvt ---
  rsc2<<<3072, blk, 0, stream>>>(pTp1, T1sT_hi, pHvF, pTp3, T3sT_hi, pHvV);

  // --- T2 + T4 (T4: A = d0 fp32 cvt-in-staging) ---
  GJob jT2 = {}, jT4 = {};
  jT2.Ah = d1T_hi; jT2.Bh = T1sT_hi; jT2.C = pT2p;
  jT2.K = KF; jT2.ldA = KF; jT2.ldB = KF; jT2.S = 2; jT2.gx = 48; jT2.gy = 2;
  jT2.sA = (long long)ME * KF; jT2.sB = 256LL * KF; jT2.sC = (long long)ME * 256;
  jT4.Af = d0; jT4.Bh = T3sT_hi; jT4.C = pT4p;
  jT4.K = NV; jT4.ldA = NV; jT4.ldB = NV; jT4.S = 2; jT4.gx = 48; jT4.gy = 2;
  jT4.sA = (long long)ME * NV; jT4.sB = 256LL * NV; jT4.sC = (long long)ME * 256;
  gemm_dual<0, 1, false><<<768, blk, 0, stream>>>(jT2, jT4, 384);

  // --- fused combine + output projection ---
  gemm_out<<<dim3(96, 2, 1), blk, 0, stream>>>(pT2p, pT4p, pHvEi, Wo_hi, Wo_lo, out);
}

// Round 18
// 374.209 us; speedup vs baseline: 1.1673x; 1.0138x over previous
//
#include <hip/hip_runtime.h>
#include <hip/hip_bf16.h>
#include <cstdint>
#include <cstddef>

// ---------------------------------------------------------------------------
// MeshMultiHeadHodgeLaplaceAttention  (b=2, n=2048, m=6144, k=4096, D=256, H=8)
//
//   up:   T1 = d_1 @ eV ; *f_hval ; T2 = d_1^T @ T1s ; (*einv_hval in combine)
//   down: Y0 = eV*e_hval ; T3 = d_0^T @ Y0 ; *1/(v_hval+eps) ; T4 = d_0 @ T3s
//   out = (T2*einv_hval + T4) @ W_o
//
// Precision: v_hval replicates numpy fp32 bit-exactly; P1 + output GEMM
// split-bf16; T1..T4 plain bf16 (validated R10-R17, absmax=256).
//
// R18: T2/T4 split-K slabs stored as bf16 (-50 MB write, -50 MB gemm_out
// read). Partials already carry plain-bf16 GEMM error (0.4%); slab rounding
// adds same-order noise (budget: 537 absmax headroom). Rest identical R17.
// ---------------------------------------------------------------------------

typedef __attribute__((ext_vector_type(4))) float f32x4;
typedef __attribute__((ext_vector_type(2))) unsigned short u16x2;
typedef __attribute__((ext_vector_type(4))) unsigned short u16x4;
typedef __attribute__((ext_vector_type(8))) unsigned short u16x8;
typedef __attribute__((ext_vector_type(8))) __bf16 bf16x8;

static __device__ __forceinline__ unsigned short f2bf(float f) {
  uint32_t u = __builtin_bit_cast(uint32_t, f);
  uint32_t r = (u + 0x7FFFu + ((u >> 16) & 1u)) >> 16;  // RNE
  return (unsigned short)r;
}
static __device__ __forceinline__ float bf2f(unsigned short h) {
  return __builtin_bit_cast(float, (uint32_t)h << 16);
}
static __device__ __forceinline__ void st4(unsigned short* p, u16x4 v) {
  *(u16x2*)p = u16x2{v[0], v[1]};
  *(u16x2*)(p + 2) = u16x2{v[2], v[3]};
}

// ---------------------------------------------------------------------------
// Mode-templated GEMM body. MODE: 0 = A,B bf16 ; 1 = A fp32 cvt ; 2 = B fp32
// cvt. BF16C: store C as bf16. C[M x gy*128] = A[M x K] * B[N x K];
// split-K z = batch*S + split. 128x128 tile, BK=32, reg-prefetch.
// ---------------------------------------------------------------------------
struct GJob {
  const unsigned short* Ah; const float* Af;
  const unsigned short* Bh; const float* Bf;
  float* C; unsigned short* C16;
  int K, ldA, ldB, S, gx, gy;
  long long sA, sB, sC;
};

template <int MODE, bool XFAST, bool BF16C>
static __device__ void gemm_body(char* smem, const GJob& J, int b) {
  const int per = J.gx * J.gy;
  const int z = b / per;
  const int wid = b - z * per;
  const int batch = z / J.S, split = z - batch * J.S;
  const unsigned short* Ah = nullptr; const float* Af = nullptr;
  const unsigned short* Bh = nullptr; const float* Bf = nullptr;
  if constexpr (MODE == 1) Af = J.Af + (long long)batch * J.sA;
  else                     Ah = J.Ah + (long long)batch * J.sA;
  if constexpr (MODE == 2) Bf = J.Bf + (long long)batch * J.sB;
  else                     Bh = J.Bh + (long long)batch * J.sB;

  const int nwg = per;
  const int q = nwg >> 3, r = nwg & 7;
  const int xcd = wid & 7, posn = wid >> 3;
  const int swz = (xcd < r ? xcd * (q + 1) : r * (q + 1) + (xcd - r) * q) + posn;
  int mt, nt;
  if constexpr (XFAST) { mt = swz % J.gx; nt = swz / J.gx; }
  else                 { mt = swz / J.gy; nt = swz - mt * J.gy; }
  const int m0 = mt * 128, n0 = nt * 128;
  const int NC = J.gy << 7;
  const int kLen = J.K / J.S, k0base = split * kLen;

  typedef unsigned short ldsrow[128][40];
  ldsrow* lds = (ldsrow*)smem;   // [2][128][40]

  const int t = threadIdx.x;
  const int w4 = t >> 6, lane = t & 63;
  const int wr = w4 >> 1, wc = w4 & 1;
  const int lr = lane & 15, kq = lane >> 4;
  const int rowV = t >> 2, c8V = (t & 3) * 8;     // bf16 staging
  const int rowA8 = t >> 3, qdA = (t & 7) * 4;    // fp32 staging

  u16x8 rAh[2], rBh[2];
  f32x4 rF[4];

  auto LOAD = [&](int kb) {
    if constexpr (MODE == 1) {
      #pragma unroll
      for (int a = 0; a < 4; ++a)
        rF[a] = *(const f32x4*)(Af + (size_t)(m0 + rowA8 + 32 * a) * J.ldA + kb + qdA);
    } else {
      #pragma unroll
      for (int a = 0; a < 2; ++a)
        rAh[a] = *(const u16x8*)(Ah + (size_t)(m0 + rowV + 64 * a) * J.ldA + kb + c8V);
    }
    if constexpr (MODE == 2) {
      #pragma unroll
      for (int a = 0; a < 4; ++a)
        rF[a] = *(const f32x4*)(Bf + (size_t)(n0 + rowA8 + 32 * a) * J.ldB + kb + qdA);
    } else {
      #pragma unroll
      for (int a = 0; a < 2; ++a)
        rBh[a] = *(const u16x8*)(Bh + (size_t)(n0 + rowV + 64 * a) * J.ldB + kb + c8V);
    }
  };
  auto STORE = [&]() {
    if constexpr (MODE == 1) {
      #pragma unroll
      for (int a = 0; a < 4; ++a) {
        f32x4 v = rF[a];
        u16x4 h = {f2bf(v[0]), f2bf(v[1]), f2bf(v[2]), f2bf(v[3])};
        *(u16x4*)&lds[0][rowA8 + 32 * a][qdA] = h;
      }
    } else {
      #pragma unroll
      for (int a = 0; a < 2; ++a) *(u16x8*)&lds[0][rowV + 64 * a][c8V] = rAh[a];
    }
    if constexpr (MODE == 2) {
      #pragma unroll
      for (int a = 0; a < 4; ++a) {
        f32x4 v = rF[a];
        u16x4 h = {f2bf(v[0]), f2bf(v[1]), f2bf(v[2]), f2bf(v[3])};
        *(u16x4*)&lds[1][rowA8 + 32 * a][qdA] = h;
      }
    } else {
      #pragma unroll
      for (int a = 0; a < 2; ++a) *(u16x8*)&lds[1][rowV + 64 * a][c8V] = rBh[a];
    }
  };

  f32x4 acc[4][4] = {};
  LOAD(k0base);
  for (int kk = 0; kk < kLen; kk += 32) {
    STORE();
    __syncthreads();
    if (kk + 32 < kLen) LOAD(k0base + kk + 32);  // prefetch under MFMA

    bf16x8 ah[4], bh[4];
    #pragma unroll
    for (int i = 0; i < 4; ++i) {
      ah[i] = __builtin_bit_cast(bf16x8, *(const u16x8*)&lds[0][wr * 64 + i * 16 + lr][kq * 8]);
      bh[i] = __builtin_bit_cast(bf16x8, *(const u16x8*)&lds[1][wc * 64 + i * 16 + lr][kq * 8]);
    }
    #pragma unroll
    for (int i = 0; i < 4; ++i)
      #pragma unroll
      for (int j = 0; j < 4; ++j)
        acc[i][j] = __builtin_amdgcn_mfma_f32_16x16x32_bf16(ah[i], bh[j], acc[i][j], 0, 0, 0);
    __syncthreads();
  }

  // epilogue: D mapping col = lane&15, row = (lane>>4)*4 + q
  if constexpr (BF16C) {
    unsigned short* C16 = J.C16 + (long long)z * J.sC;
    #pragma unroll
    for (int i = 0; i < 4; ++i)
      #pragma unroll
      for (int j = 0; j < 4; ++j) {
        unsigned short* cp = C16 + (size_t)(m0 + wr * 64 + i * 16 + kq * 4) * NC + n0 + wc * 64 + j * 16 + lr;
        #pragma unroll
        for (int qq = 0; qq < 4; ++qq) cp[(size_t)qq * NC] = f2bf(acc[i][j][qq]);
      }
  } else {
    float* C = J.C + (long long)z * J.sC;
    #pragma unroll
    for (int i = 0; i < 4; ++i)
      #pragma unroll
      for (int j = 0; j < 4; ++j) {
        float* cp = C + (size_t)(m0 + wr * 64 + i * 16 + kq * 4) * NC + n0 + wc * 64 + j * 16 + lr;
        #pragma unroll
        for (int qq = 0; qq < 4; ++qq) cp[(size_t)qq * NC] = acc[i][j][qq];
      }
  }
}

template <int M0, int M1, bool XFAST, bool BF16C>
__global__ __launch_bounds__(256) void gemm_dual(GJob j0, GJob j1, int nb0) {
  __shared__ __align__(16) unsigned short lds[2][128][40];
  if ((int)blockIdx.x < nb0) gemm_body<M0, XFAST, BF16C>((char*)lds, j0, blockIdx.x);
  else                       gemm_body<M1, XFAST, BF16C>((char*)lds, j1, blockIdx.x - nb0);
}

// ---------------------------------------------------------------------------
// Projection GEMM body (K=256): C = A fp32 (cvt) * B bf16 hi(/lo).
// ---------------------------------------------------------------------------
template <bool SPLIT>
static __device__ void proj_body(char* smem, int wid, int gx, int gy,
                                 const float* __restrict__ Af,
                                 const unsigned short* __restrict__ Bh,
                                 const unsigned short* __restrict__ Bl,
                                 float* __restrict__ C) {
  const int nwg = gx * gy;
  const int q = nwg >> 3, r = nwg & 7;
  const int xcd = wid & 7, posn = wid >> 3;
  const int swz = (xcd < r ? xcd * (q + 1) : r * (q + 1) + (xcd - r) * q) + posn;
  const int mt = swz / gy;
  const int m0 = mt * 128, n0 = (swz - mt * gy) * 128;
  const int NC = gy << 7;

  typedef unsigned short ldsrow[128][40];
  ldsrow* lds = (ldsrow*)smem;

  const int t = threadIdx.x;
  const int w4 = t >> 6, lane = t & 63;
  const int wr = w4 >> 1, wc = w4 & 1;
  const int lr = lane & 15, kq = lane >> 4;
  const int rowA8 = t >> 3, qdA = (t & 7) * 4;
  const int rowV = t >> 2, c8V = (t & 3) * 8;

  f32x4 rAf[4];
  u16x8 rBh[2], rBl[2];

  auto LOAD = [&](int kb) {
    #pragma unroll
    for (int a = 0; a < 4; ++a)
      rAf[a] = *(const f32x4*)(Af + (size_t)(m0 + rowA8 + 32 * a) * 256 + kb + qdA);
    #pragma unroll
    for (int a = 0; a < 2; ++a) {
      rBh[a] = *(const u16x8*)(Bh + (size_t)(n0 + rowV + 64 * a) * 256 + kb + c8V);
      if constexpr (SPLIT)
        rBl[a] = *(const u16x8*)(Bl + (size_t)(n0 + rowV + 64 * a) * 256 + kb + c8V);
    }
  };
  auto STORE = [&]() {
    #pragma unroll
    for (int a = 0; a < 4; ++a) {
      f32x4 v = rAf[a];
      u16x4 h = {f2bf(v[0]), f2bf(v[1]), f2bf(v[2]), f2bf(v[3])};
      *(u16x4*)&lds[0][rowA8 + 32 * a][qdA] = h;
      if constexpr (SPLIT) {
        u16x4 l = {f2bf(v[0] - bf2f(h[0])), f2bf(v[1] - bf2f(h[1])),
                   f2bf(v[2] - bf2f(h[2])), f2bf(v[3] - bf2f(h[3]))};
        *(u16x4*)&lds[2][rowA8 + 32 * a][qdA] = l;
      }
    }
    #pragma unroll
    for (int a = 0; a < 2; ++a) {
      *(u16x8*)&lds[1][rowV + 64 * a][c8V] = rBh[a];
      if constexpr (SPLIT) *(u16x8*)&lds[3][rowV + 64 * a][c8V] = rBl[a];
    }
  };

  f32x4 acc[4][4] = {};
  LOAD(0);
  for (int kk = 0; kk < 256; kk += 32) {
    STORE();
    __syncthreads();
    if (kk + 32 < 256) LOAD(kk + 32);

    bf16x8 ah[4], bh[4], al[4], bl[4];
    #pragma unroll
    for (int i = 0; i < 4; ++i) {
      ah[i] = __builtin_bit_cast(bf16x8, *(const u16x8*)&lds[0][wr * 64 + i * 16 + lr][kq * 8]);
      bh[i] = __builtin_bit_cast(bf16x8, *(const u16x8*)&lds[1][wc * 64 + i * 16 + lr][kq * 8]);
      if constexpr (SPLIT) {
        al[i] = __builtin_bit_cast(bf16x8, *(const u16x8*)&lds[2][wr * 64 + i * 16 + lr][kq * 8]);
        bl[i] = __builtin_bit_cast(bf16x8, *(const u16x8*)&lds[3][wc * 64 + i * 16 + lr][kq * 8]);
      }
    }
    #pragma unroll
    for (int i = 0; i < 4; ++i)
      #pragma unroll
      for (int j = 0; j < 4; ++j) {
        acc[i][j] = __builtin_amdgcn_mfma_f32_16x16x32_bf16(ah[i], bh[j], acc[i][j], 0, 0, 0);
        if constexpr (SPLIT) {
          acc[i][j] = __builtin_amdgcn_mfma_f32_16x16x32_bf16(ah[i], bl[j], acc[i][j], 0, 0, 0);
          acc[i][j] = __builtin_amdgcn_mfma_f32_16x16x32_bf16(al[i], bh[j], acc[i][j], 0, 0, 0);
        }
      }
    __syncthreads();
  }

  #pragma unroll
  for (int i = 0; i < 4; ++i)
    #pragma unroll
    for (int j = 0; j < 4; ++j) {
      float* cp = C + (size_t)(m0 + wr * 64 + i * 16 + kq * 4) * NC + n0 + wc * 64 + j * 16 + lr;
      #pragma unroll
      for (int qq = 0; qq < 4; ++qq) cp[(size_t)qq * NC] = acc[i][j][qq];
    }
}

// P1 (split, 960 blocks) + P3 (plain, 256 blocks) in one launch.
__global__ __launch_bounds__(256) void proj_dual(
    const float* __restrict__ xe, const unsigned short* __restrict__ W5h,
    const unsigned short* __restrict__ W5l, float* __restrict__ P1,
    const float* __restrict__ xf, const unsigned short* __restrict__ W3h,
    float* __restrict__ P3) {
  __shared__ __align__(16) unsigned short lds[4][128][40];
  if ((int)blockIdx.x < 960)
    proj_body<true>((char*)lds, blockIdx.x, 96, 10, xe, W5h, W5l, P1);
  else
    proj_body<false>((char*)lds, blockIdx.x - 960, 64, 4, xf, W3h, nullptr, P3);
}

// ---------------------------------------------------------------------------
// Output GEMM with fused combine: A[r][c] = (T4p 2-slab bf16 sum) +
// (T2p 2-slab bf16 sum)*einv_hval;  C = A @ W_o (split hi/lo).
// ---------------------------------------------------------------------------
__global__ __launch_bounds__(256) void gemm_out(
    const unsigned short* __restrict__ T2p, const unsigned short* __restrict__ T4p,
    const float* __restrict__ hEi, const unsigned short* __restrict__ Bh,
    const unsigned short* __restrict__ Bl, float* __restrict__ C) {
  const int gx = gridDim.x, gy = gridDim.y;
  const int nwg = gx * gy;
  const int wid = blockIdx.x + gx * blockIdx.y;
  const int q = nwg >> 3, r = nwg & 7;
  const int xcd = wid & 7, posn = wid >> 3;
  const int swz = (xcd < r ? xcd * (q + 1) : r * (q + 1) + (xcd - r) * q) + posn;
  const int mt = swz / gy;
  const int m0 = mt * 128, n0 = (swz - mt * gy) * 128;

  __shared__ unsigned short lds[4][128][40];
  const int t = threadIdx.x;
  const int w4 = t >> 6, lane = t & 63;
  const int wr = w4 >> 1, wc = w4 & 1;
  const int lr = lane & 15, kq = lane >> 4;
  const long long slab = 6144LL * 256;

  f32x4 acc[4][4] = {};

  for (int kb = 0; kb < 256; kb += 32) {
    #pragma unroll
    for (int a = 0; a < 4; ++a) {
      int idx = t + 256 * a;
      int row = idx >> 3, qd = (idx & 7) * 4;
      int rg = m0 + row;
      int b = rg >= 6144;
      int pos = rg - b * 6144;
      int ck = kb + qd;
      float s = hEi[((size_t)b * 8 + (ck >> 5)) * 6144 + pos];
      const unsigned short* b2 = T2p + ((long long)(b * 2) * 6144 + pos) * 256 + ck;
      const unsigned short* b4 = T4p + ((long long)(b * 2) * 6144 + pos) * 256 + ck;
      u16x4 p20 = *(const u16x4*)b2, p21 = *(const u16x4*)(b2 + slab);
      u16x4 p40 = *(const u16x4*)b4, p41 = *(const u16x4*)(b4 + slab);
      f32x4 t2 = {bf2f(p20[0]) + bf2f(p21[0]), bf2f(p20[1]) + bf2f(p21[1]),
                  bf2f(p20[2]) + bf2f(p21[2]), bf2f(p20[3]) + bf2f(p21[3])};
      f32x4 t4 = {bf2f(p40[0]) + bf2f(p41[0]), bf2f(p40[1]) + bf2f(p41[1]),
                  bf2f(p40[2]) + bf2f(p41[2]), bf2f(p40[3]) + bf2f(p41[3])};
      f32x4 v = t4 + t2 * s;
      u16x4 h = {f2bf(v[0]), f2bf(v[1]), f2bf(v[2]), f2bf(v[3])};
      *(u16x4*)&lds[0][row][qd] = h;
      u16x4 l = {f2bf(v[0] - bf2f(h[0])), f2bf(v[1] - bf2f(h[1])),
                 f2bf(v[2] - bf2f(h[2])), f2bf(v[3] - bf2f(h[3]))};
      *(u16x4*)&lds[2][row][qd] = l;
    }
    #pragma unroll
    for (int a = 0; a < 2; ++a) {
      int idx = t + 256 * a;
      int row = idx >> 2, c8 = (idx & 3) * 8;
      *(u16x8*)&lds[1][row][c8] = *(const u16x8*)(Bh + (size_t)(n0 + row) * 256 + kb + c8);
      *(u16x8*)&lds[3][row][c8] = *(const u16x8*)(Bl + (size_t)(n0 + row) * 256 + kb + c8);
    }
    __syncthreads();

    bf16x8 ah[4], bh[4], al[4], bl[4];
    #pragma unroll
    for (int i = 0; i < 4; ++i) {
      ah[i] = __builtin_bit_cast(bf16x8, *(const u16x8*)&lds[0][wr * 64 + i * 16 + lr][kq * 8]);
      bh[i] = __builtin_bit_cast(bf16x8, *(const u16x8*)&lds[1][wc * 64 + i * 16 + lr][kq * 8]);
      al[i] = __builtin_bit_cast(bf16x8, *(const u16x8*)&lds[2][wr * 64 + i * 16 + lr][kq * 8]);
      bl[i] = __builtin_bit_cast(bf16x8, *(const u16x8*)&lds[3][wc * 64 + i * 16 + lr][kq * 8]);
    }
    #pragma unroll
    for (int i = 0; i < 4; ++i)
      #pragma unroll
      for (int j = 0; j < 4; ++j) {
        acc[i][j] = __builtin_amdgcn_mfma_f32_16x16x32_bf16(ah[i], bh[j], acc[i][j], 0, 0, 0);
        acc[i][j] = __builtin_amdgcn_mfma_f32_16x16x32_bf16(ah[i], bl[j], acc[i][j], 0, 0, 0);
        acc[i][j] = __builtin_amdgcn_mfma_f32_16x16x32_bf16(al[i], bh[j], acc[i][j], 0, 0, 0);
      }
    __syncthreads();
  }

  #pragma unroll
  for (int i = 0; i < 4; ++i)
    #pragma unroll
    for (int j = 0; j < 4; ++j) {
      float* cp = C + (size_t)(m0 + wr * 64 + i * 16 + kq * 4) * 256 + n0 + wc * 64 + j * 16 + lr;
      #pragma unroll
      for (int qq = 0; qq < 4; ++qq) cp[(size_t)qq * 256] = acc[i][j][qq];
    }
}

// ---------------------------------------------------------------------------
// Weight transposes (tiny standalone launch, 128 blocks, 74-stride tiles).
// ---------------------------------------------------------------------------
struct WTab {
  const float* s[8];
  unsigned short* h[8];
  unsigned short* l[8];
};
__global__ __launch_bounds__(256) void wxpose(WTab tab) {
  __shared__ __align__(16) unsigned short smem[2 * 64 * 74];
  unsigned short* thi = smem;
  unsigned short* tlo = smem + 64 * 74;
  const int idx = blockIdx.x;
  const int w = idx >> 4;
  const int r0 = (idx & 3) * 64, c0 = ((idx >> 2) & 3) * 64;
  const float* src = tab.s[w];
  unsigned short* oh = tab.h[w];
  unsigned short* ol = tab.l[w];
  const int t = threadIdx.x;
  #pragma unroll
  for (int a = 0; a < 4; ++a) {
    int idx2 = t + 256 * a;
    int tr = idx2 >> 4, tc = (idx2 & 15) * 4;
    f32x4 v = *(const f32x4*)(src + (size_t)(r0 + tr) * 256 + c0 + tc);
    u16x4 hh = {f2bf(v[0]), f2bf(v[1]), f2bf(v[2]), f2bf(v[3])};
    st4(&thi[tr * 74 + tc], hh);
    if (ol) {
      u16x4 ll = {f2bf(v[0] - bf2f(hh[0])), f2bf(v[1] - bf2f(hh[1])),
                  f2bf(v[2] - bf2f(hh[2])), f2bf(v[3] - bf2f(hh[3]))};
      st4(&tlo[tr * 74 + tc], ll);
    }
  }
  __syncthreads();
  #pragma unroll
  for (int a = 0; a < 2; ++a) {
    int idx2 = t + 256 * a;
    int orow = idx2 >> 3, oc = (idx2 & 7) * 8;
    u16x8 vh;
    #pragma unroll
    for (int j = 0; j < 8; ++j) vh[j] = thi[(oc + j) * 74 + orow];
    *(u16x8*)(oh + (size_t)(c0 + orow) * 256 + r0 + oc) = vh;
    if (ol) {
      u16x8 vl;
      #pragma unroll
      for (int j = 0; j < 8; ++j) vl[j] = tlo[(oc + j) * 74 + orow];
      *(u16x8*)(ol + (size_t)(c0 + orow) * 256 + r0 + oc) = vl;
    }
  }
}

// ---------------------------------------------------------------------------
// prep2: [0,512) vproj ; [512,6656) d0 -> d0T ; [6656,18944) d1 -> d1T (LAST,
// so d1 stays L3-warm for the immediately following T1). 74-stride tiles.
// ---------------------------------------------------------------------------
struct PrepArgs {
  const float* d1; unsigned short* d1T;
  const float* d0; unsigned short* d0T_hi;
  const float* xv; const float* Wvq; const float* Wvk; float* hvV;
};

__global__ __launch_bounds__(256) void prep2(PrepArgs A) {
  __shared__ __align__(16) char smem[24576];
  const int t = threadIdx.x;
  const int bid = blockIdx.x;

  if (bid < 512) {
    // ---- vproj (np-fp32 exact, 8 rows/block) ----
    float* sx = (float*)smem;
    float* sq = (float*)(smem + 8192);
    float* sk = (float*)(smem + 16384);
    const int r0 = bid * 8;
    const int j = t;
    #pragma unroll
    for (int r = 0; r < 8; ++r) sx[r * 256 + j] = A.xv[(size_t)(r0 + r) * 256 + j];
    __syncthreads();
    float qa[8] = {}, ka[8] = {};
    for (int i = 0; i < 256; ++i) {
      float wq = A.Wvq[i * 256 + j], wk = A.Wvk[i * 256 + j];
      #pragma unroll
      for (int r = 0; r < 8; ++r) {
        qa[r] = __fmaf_rn(sx[r * 256 + i], wq, qa[r]);
        ka[r] = __fmaf_rn(sx[r * 256 + i], wk, ka[r]);
      }
    }
    #pragma unroll
    for (int r = 0; r < 8; ++r) { sq[r * 256 + j] = qa[r]; sk[r * 256 + j] = ka[r]; }
    __syncthreads();
    if (j < 64) {
      const int r = j >> 3, head = j & 7;
      const float* qq = &sq[r * 256 + head * 32];
      const float* kk = &sk[r * 256 + head * 32];
      float s0 = 0.0f, s1 = 0.0f, s2 = 0.0f, s3 = 0.0f;
      #pragma unroll 1
      for (int d = 0; d < 32; d += 4) {
        s0 = __fadd_rn(s0, __fmul_rn(qq[d + 0], kk[d + 0]));
        s1 = __fadd_rn(s1, __fmul_rn(qq[d + 1], kk[d + 1]));
        s2 = __fadd_rn(s2, __fmul_rn(qq[d + 2], kk[d + 2]));
        s3 = __fadd_rn(s3, __fmul_rn(qq[d + 3], kk[d + 3]));
      }
      float p = __fadd_rn(__fadd_rn(s0, s2), __fadd_rn(s1, s3));
      float hval = __fdiv_rn(p, sqrtf(32.0f));
      float inv = __fdiv_rn(1.0f, __fadd_rn(hval, 1e-6f));
      const int row = r0 + r;
      const int b = row / 2048, pos = row - b * 2048;
      A.hvV[((size_t)b * 8 + head) * 2048 + pos] = inv;
    }
  } else if (bid < 6656) {
    // ---- d0: [2][6144][2048] fp32 -> d0T bf16 ----
    const int idx = bid - 512;
    const int x = idx % 96;
    const int rem = idx / 96;
    const int y = rem & 31;
    const int b = rem >> 5;
    const int r0 = x * 64, c0 = y * 64;
    unsigned short* tile = (unsigned short*)smem;   // [64][74]
    #pragma unroll
    for (int a = 0; a < 4; ++a) {
      int idx2 = t + 256 * a;
      int tr = idx2 >> 4, tc = (idx2 & 15) * 4;
      size_t off = ((size_t)b * 6144 + r0 + tr) * 2048 + c0 + tc;
      f32x4 v = *(const f32x4*)(A.d0 + off);
      u16x4 hh = {f2bf(v[0]), f2bf(v[1]), f2bf(v[2]), f2bf(v[3])};
      st4(&tile[tr * 74 + tc], hh);
    }
    __syncthreads();
    #pragma unroll
    for (int a = 0; a < 2; ++a) {
      int idx2 = t + 256 * a;
      int orow = idx2 >> 3, oc = (idx2 & 7) * 8;
      u16x8 vh;
      #pragma unroll
      for (int j = 0; j < 8; ++j) vh[j] = tile[(oc + j) * 74 + orow];
      *(u16x8*)(A.d0T_hi + ((size_t)b * 2048 + c0 + orow) * 6144 + r0 + oc) = vh;
    }
  } else {
    // ---- d1: [2][4096][6144] fp32 -> d1T bf16 (LAST) ----
    const int idx = bid - 6656;
    const int x = idx & 63;
    const int rem = idx >> 6;
    const int y = rem % 96;
    const int b = rem / 96;
    const int r0 = x * 64, c0 = y * 64;
    unsigned short* tile = (unsigned short*)smem;   // [64][74]
    #pragma unroll
    for (int a = 0; a < 4; ++a) {
      int idx2 = t + 256 * a;
      int tr = idx2 >> 4, tc = (idx2 & 15) * 4;
      size_t off = ((size_t)b * 4096 + r0 + tr) * 6144 + c0 + tc;
      f32x4 v = *(const f32x4*)(A.d1 + off);
      u16x4 hh = {f2bf(v[0]), f2bf(v[1]), f2bf(v[2]), f2bf(v[3])};
      st4(&tile[tr * 74 + tc], hh);
    }
    __syncthreads();
    #pragma unroll
    for (int a = 0; a < 2; ++a) {
      int idx2 = t + 256 * a;
      int orow = idx2 >> 3, oc = (idx2 & 7) * 8;
      u16x8 vh;
      #pragma unroll
      for (int j = 0; j < 8; ++j) vh[j] = tile[(oc + j) * 74 + orow];
      *(u16x8*)(A.d1T + ((size_t)b * 6144 + c0 + orow) * 4096 + r0 + oc) = vh;
    }
  }
}

// ---------------------------------------------------------------------------
// Fused eVT (unscaled bf16) + Y0T (scaled bf16) from P1 cols 512..767.
// ---------------------------------------------------------------------------
__global__ __launch_bounds__(256) void xpose_ev(
    const float* __restrict__ P1, unsigned short* __restrict__ eVT,
    unsigned short* __restrict__ yhi, const float* __restrict__ hE) {
  __shared__ __align__(16) unsigned short smem[2 * 64 * 74];
  unsigned short* te = smem;
  unsigned short* th = smem + 64 * 74;
  const int b = blockIdx.z;
  const int r0 = blockIdx.x * 64, c0 = blockIdx.y * 64;
  const int t = threadIdx.x;
  #pragma unroll
  for (int a = 0; a < 4; ++a) {
    int idx = t + 256 * a;
    int tr = idx >> 4, tc = (idx & 15) * 4;
    f32x4 v = *(const f32x4*)(P1 + ((size_t)b * 6144 + r0 + tr) * 1280 + 512 + c0 + tc);
    u16x4 eh = {f2bf(v[0]), f2bf(v[1]), f2bf(v[2]), f2bf(v[3])};
    st4(&te[tr * 74 + tc], eh);
    float s = hE[((size_t)b * 8 + ((c0 + tc) >> 5)) * 6144 + r0 + tr];
    f32x4 y = v * s;
    u16x4 hh = {f2bf(y[0]), f2bf(y[1]), f2bf(y[2]), f2bf(y[3])};
    st4(&th[tr * 74 + tc], hh);
  }
  __syncthreads();
  #pragma unroll
  for (int a = 0; a < 2; ++a) {
    int idx = t + 256 * a;
    int orow = idx >> 3, oc = (idx & 7) * 8;
    u16x8 ve, vh;
    #pragma unroll
    for (int j = 0; j < 8; ++j) {
      ve[j] = te[(oc + j) * 74 + orow];
      vh[j] = th[(oc + j) * 74 + orow];
    }
    size_t o = ((size_t)b * 256 + c0 + orow) * 6144 + r0 + oc;
    *(u16x8*)(eVT + o) = ve;
    *(u16x8*)(yhi + o) = vh;
  }
}

// ---------------------------------------------------------------------------
// Merged rsc_cvt (sum S slabs ascending, scale, cvt bf16).
// ---------------------------------------------------------------------------
static __device__ __forceinline__ void rsc_body(
    const float* in, unsigned short* out_hi, const float* h,
    int S, int R, int P, int bid, int nblk) {
  const long long qP = P >> 2;
  const long long nq = 2LL * R * qP;
  long long i = (long long)bid * 256 + threadIdx.x;
  const long long stride = (long long)nblk * 256;
  for (; i < nq; i += stride) {
    long long b = i / (R * qP);
    long long rem = i - b * (R * qP);
    int row = (int)(rem / qP);
    long long qc = rem - (long long)row * qP;
    const f32x4* base = (const f32x4*)in + ((b * S) * R + row) * qP + qc;
    f32x4 v = base[0];
    for (int s = 1; s < S; ++s) v += base[(long long)s * R * qP];
    v *= *(const f32x4*)(h + ((size_t)b * 8 + (row >> 5)) * P + (qc << 2));
    u16x4 hh = {f2bf(v[0]), f2bf(v[1]), f2bf(v[2]), f2bf(v[3])};
    ((u16x4*)out_hi)[i] = hh;
  }
}

__global__ void rsc2(const float* in1, unsigned short* o1h, const float* hF,
                     const float* in3, unsigned short* o3h, const float* hV) {
  if (blockIdx.x < 2048)
    rsc_body(in1, o1h, hF, 3, 256, 4096, blockIdx.x, 2048);
  else
    rsc_body(in3, o3h, hV, 6, 256, 2048, blockIdx.x - 2048, 1024);
}

// ---------------------------------------------------------------------------
// Merged hval dots: [0,3072) e/einv pairs from P1; [3072,5120) f pair from P3.
// ---------------------------------------------------------------------------
__global__ __launch_bounds__(256) void dots(
    const float* __restrict__ P1, float* __restrict__ hE, float* __restrict__ hEi,
    const float* __restrict__ P3, float* __restrict__ hF) {
  const int wv = threadIdx.x >> 6, lane = threadIdx.x & 63;
  if (blockIdx.x < 3072) {
    const int row = blockIdx.x * 4 + wv;
    const float* base = P1 + (size_t)row * 1280 + lane * 4;
    f32x4 qv = *(const f32x4*)(base);
    f32x4 kv = *(const f32x4*)(base + 256);
    float p = qv[0] * kv[0] + qv[1] * kv[1] + qv[2] * kv[2] + qv[3] * kv[3];
    p += __shfl_xor(p, 1); p += __shfl_xor(p, 2); p += __shfl_xor(p, 4);
    f32x4 q2 = *(const f32x4*)(base + 768);
    f32x4 k2 = *(const f32x4*)(base + 1024);
    float p2 = q2[0] * k2[0] + q2[1] * k2[1] + q2[2] * k2[2] + q2[3] * k2[3];
    p2 += __shfl_xor(p2, 1); p2 += __shfl_xor(p2, 2); p2 += __shfl_xor(p2, 4);
    if ((lane & 7) == 0) {
      const int head = lane >> 3;
      const int b = row / 6144, pos = row % 6144;
      hE[((size_t)b * 8 + head) * 6144 + pos] = p * 0.17677669529663687f;
      hEi[((size_t)b * 8 + head) * 6144 + pos] = p2 * 0.17677669529663687f;
    }
  } else {
    const int row = (blockIdx.x - 3072) * 4 + wv;
    const float* base = P3 + (size_t)row * 512 + lane * 4;
    f32x4 qv = *(const f32x4*)(base);
    f32x4 kv = *(const f32x4*)(base + 256);
    float p = qv[0] * kv[0] + qv[1] * kv[1] + qv[2] * kv[2] + qv[3] * kv[3];
    p += __shfl_xor(p, 1); p += __shfl_xor(p, 2); p += __shfl_xor(p, 4);
    if ((lane & 7) == 0) {
      const int head = lane >> 3;
      const int b = row / 4096, pos = row % 4096;
      hF[((size_t)b * 8 + head) * 4096 + pos] = p * 0.17677669529663687f;
    }
  }
}

// ---------------------------------------------------------------------------
extern "C" void kernel_launch(void* const* d_in, const int* in_sizes, int n_in,
                              void* d_out, int out_size, void* d_ws, size_t ws_size,
                              hipStream_t stream) {
  const float* x_v = (const float*)d_in[0];
  const float* x_e = (const float*)d_in[1];
  const float* x_f = (const float*)d_in[2];
  const float* d0  = (const float*)d_in[3];   // (2, 6144, 2048)
  const float* d1  = (const float*)d_in[4];   // (2, 4096, 6144)
  float* out = (float*)d_out;

  const int NV = 2048, ME = 6144, KF = 4096;

  char* ws = (char*)d_ws;
  size_t o = 0;
  auto alloc = [&](size_t bytes) { size_t r = o; o = (o + bytes + 255) & ~255ULL; return r; };

  unsigned short* Wcat5_hi = (unsigned short*)(ws + alloc(1280 * 256 * 2));
  unsigned short* Wcat5_lo = (unsigned short*)(ws + alloc(1280 * 256 * 2));
  unsigned short* W3_hi = (unsigned short*)(ws + alloc(512 * 256 * 2));
  unsigned short* Wo_hi = (unsigned short*)(ws + alloc(256 * 256 * 2));
  unsigned short* Wo_lo = (unsigned short*)(ws + alloc(256 * 256 * 2));
  float* pHvE  = (float*)(ws + alloc(2 * 8 * ME * 4));
  float* pHvEi = (float*)(ws + alloc(2 * 8 * ME * 4));
  float* pHvF  = (float*)(ws + alloc(2 * 8 * KF * 4));
  float* pHvV  = (float*)(ws + alloc(2 * 8 * NV * 4));
  unsigned short* d1T_hi = (unsigned short*)(ws + alloc((size_t)2 * ME * KF * 2));   // [2][6144][4096]
  unsigned short* d0T_hi = (unsigned short*)(ws + alloc((size_t)2 * NV * ME * 2));   // [2][2048][6144]
  unsigned short* eVT_hi = (unsigned short*)(ws + alloc((size_t)2 * 256 * ME * 2));
  unsigned short* Y0T_hi = (unsigned short*)(ws + alloc((size_t)2 * 256 * ME * 2));
  unsigned short* T1sT_hi = (unsigned short*)(ws + alloc((size_t)2 * 256 * KF * 2));
  unsigned short* T3sT_hi = (unsigned short*)(ws + alloc((size_t)2 * 256 * NV * 2));
  float* pP1 = (float*)(ws + alloc((size_t)12288 * 1280 * 4));
  float* pP3 = (float*)(ws + alloc((size_t)8192 * 512 * 4));
  float* pTp1 = (float*)(ws + alloc((size_t)2 * 3 * 256 * KF * 4));   // T1^T slabs fp32
  float* pTp3 = (float*)(ws + alloc((size_t)2 * 6 * 256 * NV * 4));   // T3^T slabs fp32
  unsigned short* pT2p = (unsigned short*)(ws + alloc((size_t)2 * 2 * ME * 256 * 2));  // bf16 slabs
  unsigned short* pT4p = (unsigned short*)(ws + alloc((size_t)2 * 2 * ME * 256 * 2));

  dim3 blk(256);

  // --- weight transposes (tiny) ---
  WTab tab;
  tab.s[0] = (const float*)d_in[7];  tab.h[0] = Wcat5_hi;          tab.l[0] = Wcat5_lo;
  tab.s[1] = (const float*)d_in[8];  tab.h[1] = Wcat5_hi + 65536;  tab.l[1] = Wcat5_lo + 65536;
  tab.s[2] = (const float*)d_in[11]; tab.h[2] = Wcat5_hi + 131072; tab.l[2] = Wcat5_lo + 131072;
  tab.s[3] = (const float*)d_in[9];  tab.h[3] = Wcat5_hi + 196608; tab.l[3] = Wcat5_lo + 196608;
  tab.s[4] = (const float*)d_in[10]; tab.h[4] = Wcat5_hi + 262144; tab.l[4] = Wcat5_lo + 262144;
  tab.s[5] = (const float*)d_in[12]; tab.h[5] = W3_hi;             tab.l[5] = nullptr;
  tab.s[6] = (const float*)d_in[13]; tab.h[6] = W3_hi + 65536;     tab.l[6] = nullptr;
  tab.s[7] = (const float*)d_in[14]; tab.h[7] = Wo_hi;             tab.l[7] = Wo_lo;
  wxpose<<<128, blk, 0, stream>>>(tab);

  // --- projections + hvals (before the d-conversions, so d1 stays L3-warm) ---
  proj_dual<<<1216, blk, 0, stream>>>(x_e, Wcat5_hi, Wcat5_lo, pP1, x_f, W3_hi, pP3);
  dots<<<5120, blk, 0, stream>>>(pP1, pHvE, pHvEi, pP3, pHvF);
  xpose_ev<<<dim3(96, 4, 2), blk, 0, stream>>>(pP1, eVT_hi, Y0T_hi, pHvE);

  // --- prep2: vproj + d0T + d1T (d1 LAST -> L3-warm for T1) ---
  PrepArgs pa;
  pa.d1 = d1; pa.d1T = d1T_hi;
  pa.d0 = d0; pa.d0T_hi = d0T_hi;
  pa.xv = x_v; pa.Wvq = (const float*)d_in[5]; pa.Wvk = (const float*)d_in[6];
  pa.hvV = pHvV;
  prep2<<<18944, blk, 0, stream>>>(pa);

  // --- T1 + T3 immediately (T1: B = d1 fp32, L3-warm); fp32 C slabs ---
  GJob jT1 = {}, jT3 = {};
  jT1.Ah = eVT_hi; jT1.Bf = d1; jT1.C = pTp1;
  jT1.K = ME; jT1.ldA = ME; jT1.ldB = ME; jT1.S = 3; jT1.gx = 2; jT1.gy = 32;
  jT1.sA = 256LL * ME; jT1.sB = (long long)KF * ME; jT1.sC = 256LL * KF;
  jT3.Ah = Y0T_hi; jT3.Bh = d0T_hi; jT3.C = pTp3;
  jT3.K = ME; jT3.ldA = ME; jT3.ldB = ME; jT3.S = 6; jT3.gx = 2; jT3.gy = 16;
  jT3.sA = 256LL * ME; jT3.sB = (long long)NV * ME; jT3.sC = 256LL * NV;
  gemm_dual<2, 0, true, false><<<768, blk, 0, stream>>>(jT1, jT3, 384);

  // --- reductions + scale + cvt ---
  rsc2<<<3072, blk, 0, stream>>>(pTp1, T1sT_hi, pHvF, pTp3, T3sT_hi, pHvV);

  // --- T2 + T4 (T4: A = d0 fp32 cvt-in-staging); bf16 C slabs ---
  GJob jT2 = {}, jT4 = {};
  jT2.Ah = d1T_hi; jT2.Bh = T1sT_hi; jT2.C16 = pT2p;
  jT2.K = KF; jT2.ldA = KF; jT2.ldB = KF; jT2.S = 2; jT2.gx = 48; jT2.gy = 2;
  jT2.sA = (long long)ME * KF; jT2.sB = 256LL * KF; jT2.sC = (long long)ME * 256;
  jT4.Af = d0; jT4.Bh = T3sT_hi; jT4.C16 = pT4p;
  jT4.K = NV; jT4.ldA = NV; jT4.ldB = NV; jT4.S = 2; jT4.gx = 48; jT4.gy = 2;
  jT4.sA = (long long)ME * NV; jT4.sB = 256LL * NV; jT4.sC = (long long)ME * 256;
  gemm_dual<0, 1, false, true><<<768, blk, 0, stream>>>(jT2, jT4, 384);

  // --- fused combine + output projection ---
  gemm_out<<<dim3(96, 2, 1), blk, 0, stream>>>(pT2p, pT4p, pHvEi, Wo_hi, Wo_lo, out);
}

// Round 19
// 373.839 us; speedup vs baseline: 1.1684x; 1.0010x over previous
//
#include <hip/hip_runtime.h>
#include <hip/hip_bf16.h>
#include <cstdint>
#include <cstddef>

// ---------------------------------------------------------------------------
// MeshMultiHeadHodgeLaplaceAttention  (b=2, n=2048, m=6144, k=4096, D=256, H=8)
//
//   up:   T1 = d_1 @ eV ; *f_hval ; T2 = d_1^T @ T1s ; (*einv_hval in combine)
//   down: Y0 = eV*e_hval ; T3 = d_0^T @ Y0 ; *1/(v_hval+eps) ; T4 = d_0 @ T3s
//   out = (T2*einv_hval + T4) @ W_o
//
// Precision: v_hval replicates numpy fp32 bit-exactly; P1 + output GEMM
// split-bf16; T1..T4 plain bf16; T2/T4 slabs bf16 (validated R18, absmax=256).
//
// R19: DAG-true launch packing. T1 (independent of the d-conversions since
// R16) fused INTO prep3 (LDS union still 24576 -> streamer occupancy
// unchanged; MFMA fills idle pipes). T3 fused with rsc1 (both ready after
// prep3). rsc3 tiny standalone. Zero arithmetic change vs R18.
// ---------------------------------------------------------------------------

typedef __attribute__((ext_vector_type(4))) float f32x4;
typedef __attribute__((ext_vector_type(2))) unsigned short u16x2;
typedef __attribute__((ext_vector_type(4))) unsigned short u16x4;
typedef __attribute__((ext_vector_type(8))) unsigned short u16x8;
typedef __attribute__((ext_vector_type(8))) __bf16 bf16x8;

static __device__ __forceinline__ unsigned short f2bf(float f) {
  uint32_t u = __builtin_bit_cast(uint32_t, f);
  uint32_t r = (u + 0x7FFFu + ((u >> 16) & 1u)) >> 16;  // RNE
  return (unsigned short)r;
}
static __device__ __forceinline__ float bf2f(unsigned short h) {
  return __builtin_bit_cast(float, (uint32_t)h << 16);
}
static __device__ __forceinline__ void st4(unsigned short* p, u16x4 v) {
  *(u16x2*)p = u16x2{v[0], v[1]};
  *(u16x2*)(p + 2) = u16x2{v[2], v[3]};
}

// ---------------------------------------------------------------------------
// Mode-templated GEMM body. MODE: 0 = A,B bf16 ; 1 = A fp32 cvt ; 2 = B fp32
// cvt. BF16C: store C as bf16. C[M x gy*128] = A[M x K] * B[N x K];
// split-K z = batch*S + split. 128x128 tile, BK=32, reg-prefetch.
// ---------------------------------------------------------------------------
struct GJob {
  const unsigned short* Ah; const float* Af;
  const unsigned short* Bh; const float* Bf;
  float* C; unsigned short* C16;
  int K, ldA, ldB, S, gx, gy;
  long long sA, sB, sC;
};

template <int MODE, bool XFAST, bool BF16C>
static __device__ void gemm_body(char* smem, const GJob& J, int b) {
  const int per = J.gx * J.gy;
  const int z = b / per;
  const int wid = b - z * per;
  const int batch = z / J.S, split = z - batch * J.S;
  const unsigned short* Ah = nullptr; const float* Af = nullptr;
  const unsigned short* Bh = nullptr; const float* Bf = nullptr;
  if constexpr (MODE == 1) Af = J.Af + (long long)batch * J.sA;
  else                     Ah = J.Ah + (long long)batch * J.sA;
  if constexpr (MODE == 2) Bf = J.Bf + (long long)batch * J.sB;
  else                     Bh = J.Bh + (long long)batch * J.sB;

  const int nwg = per;
  const int q = nwg >> 3, r = nwg & 7;
  const int xcd = wid & 7, posn = wid >> 3;
  const int swz = (xcd < r ? xcd * (q + 1) : r * (q + 1) + (xcd - r) * q) + posn;
  int mt, nt;
  if constexpr (XFAST) { mt = swz % J.gx; nt = swz / J.gx; }
  else                 { mt = swz / J.gy; nt = swz - mt * J.gy; }
  const int m0 = mt * 128, n0 = nt * 128;
  const int NC = J.gy << 7;
  const int kLen = J.K / J.S, k0base = split * kLen;

  typedef unsigned short ldsrow[128][40];
  ldsrow* lds = (ldsrow*)smem;   // [2][128][40]

  const int t = threadIdx.x;
  const int w4 = t >> 6, lane = t & 63;
  const int wr = w4 >> 1, wc = w4 & 1;
  const int lr = lane & 15, kq = lane >> 4;
  const int rowV = t >> 2, c8V = (t & 3) * 8;     // bf16 staging
  const int rowA8 = t >> 3, qdA = (t & 7) * 4;    // fp32 staging

  u16x8 rAh[2], rBh[2];
  f32x4 rF[4];

  auto LOAD = [&](int kb) {
    if constexpr (MODE == 1) {
      #pragma unroll
      for (int a = 0; a < 4; ++a)
        rF[a] = *(const f32x4*)(Af + (size_t)(m0 + rowA8 + 32 * a) * J.ldA + kb + qdA);
    } else {
      #pragma unroll
      for (int a = 0; a < 2; ++a)
        rAh[a] = *(const u16x8*)(Ah + (size_t)(m0 + rowV + 64 * a) * J.ldA + kb + c8V);
    }
    if constexpr (MODE == 2) {
      #pragma unroll
      for (int a = 0; a < 4; ++a)
        rF[a] = *(const f32x4*)(Bf + (size_t)(n0 + rowA8 + 32 * a) * J.ldB + kb + qdA);
    } else {
      #pragma unroll
      for (int a = 0; a < 2; ++a)
        rBh[a] = *(const u16x8*)(Bh + (size_t)(n0 + rowV + 64 * a) * J.ldB + kb + c8V);
    }
  };
  auto STORE = [&]() {
    if constexpr (MODE == 1) {
      #pragma unroll
      for (int a = 0; a < 4; ++a) {
        f32x4 v = rF[a];
        u16x4 h = {f2bf(v[0]), f2bf(v[1]), f2bf(v[2]), f2bf(v[3])};
        *(u16x4*)&lds[0][rowA8 + 32 * a][qdA] = h;
      }
    } else {
      #pragma unroll
      for (int a = 0; a < 2; ++a) *(u16x8*)&lds[0][rowV + 64 * a][c8V] = rAh[a];
    }
    if constexpr (MODE == 2) {
      #pragma unroll
      for (int a = 0; a < 4; ++a) {
        f32x4 v = rF[a];
        u16x4 h = {f2bf(v[0]), f2bf(v[1]), f2bf(v[2]), f2bf(v[3])};
        *(u16x4*)&lds[1][rowA8 + 32 * a][qdA] = h;
      }
    } else {
      #pragma unroll
      for (int a = 0; a < 2; ++a) *(u16x8*)&lds[1][rowV + 64 * a][c8V] = rBh[a];
    }
  };

  f32x4 acc[4][4] = {};
  LOAD(k0base);
  for (int kk = 0; kk < kLen; kk += 32) {
    STORE();
    __syncthreads();
    if (kk + 32 < kLen) LOAD(k0base + kk + 32);  // prefetch under MFMA

    bf16x8 ah[4], bh[4];
    #pragma unroll
    for (int i = 0; i < 4; ++i) {
      ah[i] = __builtin_bit_cast(bf16x8, *(const u16x8*)&lds[0][wr * 64 + i * 16 + lr][kq * 8]);
      bh[i] = __builtin_bit_cast(bf16x8, *(const u16x8*)&lds[1][wc * 64 + i * 16 + lr][kq * 8]);
    }
    #pragma unroll
    for (int i = 0; i < 4; ++i)
      #pragma unroll
      for (int j = 0; j < 4; ++j)
        acc[i][j] = __builtin_amdgcn_mfma_f32_16x16x32_bf16(ah[i], bh[j], acc[i][j], 0, 0, 0);
    __syncthreads();
  }

  if constexpr (BF16C) {
    unsigned short* C16 = J.C16 + (long long)z * J.sC;
    #pragma unroll
    for (int i = 0; i < 4; ++i)
      #pragma unroll
      for (int j = 0; j < 4; ++j) {
        unsigned short* cp = C16 + (size_t)(m0 + wr * 64 + i * 16 + kq * 4) * NC + n0 + wc * 64 + j * 16 + lr;
        #pragma unroll
        for (int qq = 0; qq < 4; ++qq) cp[(size_t)qq * NC] = f2bf(acc[i][j][qq]);
      }
  } else {
    float* C = J.C + (long long)z * J.sC;
    #pragma unroll
    for (int i = 0; i < 4; ++i)
      #pragma unroll
      for (int j = 0; j < 4; ++j) {
        float* cp = C + (size_t)(m0 + wr * 64 + i * 16 + kq * 4) * NC + n0 + wc * 64 + j * 16 + lr;
        #pragma unroll
        for (int qq = 0; qq < 4; ++qq) cp[(size_t)qq * NC] = acc[i][j][qq];
      }
  }
}

template <int M0, int M1, bool XFAST, bool BF16C>
__global__ __launch_bounds__(256) void gemm_dual(GJob j0, GJob j1, int nb0) {
  __shared__ __align__(16) unsigned short lds[2][128][40];
  if ((int)blockIdx.x < nb0) gemm_body<M0, XFAST, BF16C>((char*)lds, j0, blockIdx.x);
  else                       gemm_body<M1, XFAST, BF16C>((char*)lds, j1, blockIdx.x - nb0);
}

// ---------------------------------------------------------------------------
// rsc body (sum S slabs ascending, scale, cvt bf16).
// ---------------------------------------------------------------------------
static __device__ __forceinline__ void rsc_body(
    const float* in, unsigned short* out_hi, const float* h,
    int S, int R, int P, int bid, int nblk) {
  const long long qP = P >> 2;
  const long long nq = 2LL * R * qP;
  long long i = (long long)bid * 256 + threadIdx.x;
  const long long stride = (long long)nblk * 256;
  for (; i < nq; i += stride) {
    long long b = i / (R * qP);
    long long rem = i - b * (R * qP);
    int row = (int)(rem / qP);
    long long qc = rem - (long long)row * qP;
    const f32x4* base = (const f32x4*)in + ((b * S) * R + row) * qP + qc;
    f32x4 v = base[0];
    for (int s = 1; s < S; ++s) v += base[(long long)s * R * qP];
    v *= *(const f32x4*)(h + ((size_t)b * 8 + (row >> 5)) * P + (qc << 2));
    u16x4 hh = {f2bf(v[0]), f2bf(v[1]), f2bf(v[2]), f2bf(v[3])};
    ((u16x4*)out_hi)[i] = hh;
  }
}

// T3 GEMM (384 blocks) + rsc of T1 slabs (2048 blocks) in one launch.
__global__ __launch_bounds__(256) void t3_rsc1(
    GJob jT3, const float* in1, unsigned short* o1h, const float* hF) {
  __shared__ __align__(16) unsigned short lds[2][128][40];
  if ((int)blockIdx.x < 384)
    gemm_body<0, true, false>((char*)lds, jT3, blockIdx.x);
  else
    rsc_body(in1, o1h, hF, 3, 256, 4096, blockIdx.x - 384, 2048);
}

// rsc of T3 slabs (standalone, tiny).
__global__ void rsc3k(const float* in3, unsigned short* o3h, const float* hV) {
  rsc_body(in3, o3h, hV, 6, 256, 2048, blockIdx.x, 1024);
}

// ---------------------------------------------------------------------------
// Projection GEMM body (K=256): C = A fp32 (cvt) * B bf16 hi(/lo).
// ---------------------------------------------------------------------------
template <bool SPLIT>
static __device__ void proj_body(char* smem, int wid, int gx, int gy,
                                 const float* __restrict__ Af,
                                 const unsigned short* __restrict__ Bh,
                                 const unsigned short* __restrict__ Bl,
                                 float* __restrict__ C) {
  const int nwg = gx * gy;
  const int q = nwg >> 3, r = nwg & 7;
  const int xcd = wid & 7, posn = wid >> 3;
  const int swz = (xcd < r ? xcd * (q + 1) : r * (q + 1) + (xcd - r) * q) + posn;
  const int mt = swz / gy;
  const int m0 = mt * 128, n0 = (swz - mt * gy) * 128;
  const int NC = gy << 7;

  typedef unsigned short ldsrow[128][40];
  ldsrow* lds = (ldsrow*)smem;

  const int t = threadIdx.x;
  const int w4 = t >> 6, lane = t & 63;
  const int wr = w4 >> 1, wc = w4 & 1;
  const int lr = lane & 15, kq = lane >> 4;
  const int rowA8 = t >> 3, qdA = (t & 7) * 4;
  const int rowV = t >> 2, c8V = (t & 3) * 8;

  f32x4 rAf[4];
  u16x8 rBh[2], rBl[2];

  auto LOAD = [&](int kb) {
    #pragma unroll
    for (int a = 0; a < 4; ++a)
      rAf[a] = *(const f32x4*)(Af + (size_t)(m0 + rowA8 + 32 * a) * 256 + kb + qdA);
    #pragma unroll
    for (int a = 0; a < 2; ++a) {
      rBh[a] = *(const u16x8*)(Bh + (size_t)(n0 + rowV + 64 * a) * 256 + kb + c8V);
      if constexpr (SPLIT)
        rBl[a] = *(const u16x8*)(Bl + (size_t)(n0 + rowV + 64 * a) * 256 + kb + c8V);
    }
  };
  auto STORE = [&]() {
    #pragma unroll
    for (int a = 0; a < 4; ++a) {
      f32x4 v = rAf[a];
      u16x4 h = {f2bf(v[0]), f2bf(v[1]), f2bf(v[2]), f2bf(v[3])};
      *(u16x4*)&lds[0][rowA8 + 32 * a][qdA] = h;
      if constexpr (SPLIT) {
        u16x4 l = {f2bf(v[0] - bf2f(h[0])), f2bf(v[1] - bf2f(h[1])),
                   f2bf(v[2] - bf2f(h[2])), f2bf(v[3] - bf2f(h[3]))};
        *(u16x4*)&lds[2][rowA8 + 32 * a][qdA] = l;
      }
    }
    #pragma unroll
    for (int a = 0; a < 2; ++a) {
      *(u16x8*)&lds[1][rowV + 64 * a][c8V] = rBh[a];
      if constexpr (SPLIT) *(u16x8*)&lds[3][rowV + 64 * a][c8V] = rBl[a];
    }
  };

  f32x4 acc[4][4] = {};
  LOAD(0);
  for (int kk = 0; kk < 256; kk += 32) {
    STORE();
    __syncthreads();
    if (kk + 32 < 256) LOAD(kk + 32);

    bf16x8 ah[4], bh[4], al[4], bl[4];
    #pragma unroll
    for (int i = 0; i < 4; ++i) {
      ah[i] = __builtin_bit_cast(bf16x8, *(const u16x8*)&lds[0][wr * 64 + i * 16 + lr][kq * 8]);
      bh[i] = __builtin_bit_cast(bf16x8, *(const u16x8*)&lds[1][wc * 64 + i * 16 + lr][kq * 8]);
      if constexpr (SPLIT) {
        al[i] = __builtin_bit_cast(bf16x8, *(const u16x8*)&lds[2][wr * 64 + i * 16 + lr][kq * 8]);
        bl[i] = __builtin_bit_cast(bf16x8, *(const u16x8*)&lds[3][wc * 64 + i * 16 + lr][kq * 8]);
      }
    }
    #pragma unroll
    for (int i = 0; i < 4; ++i)
      #pragma unroll
      for (int j = 0; j < 4; ++j) {
        acc[i][j] = __builtin_amdgcn_mfma_f32_16x16x32_bf16(ah[i], bh[j], acc[i][j], 0, 0, 0);
        if constexpr (SPLIT) {
          acc[i][j] = __builtin_amdgcn_mfma_f32_16x16x32_bf16(ah[i], bl[j], acc[i][j], 0, 0, 0);
          acc[i][j] = __builtin_amdgcn_mfma_f32_16x16x32_bf16(al[i], bh[j], acc[i][j], 0, 0, 0);
        }
      }
    __syncthreads();
  }

  #pragma unroll
  for (int i = 0; i < 4; ++i)
    #pragma unroll
    for (int j = 0; j < 4; ++j) {
      float* cp = C + (size_t)(m0 + wr * 64 + i * 16 + kq * 4) * NC + n0 + wc * 64 + j * 16 + lr;
      #pragma unroll
      for (int qq = 0; qq < 4; ++qq) cp[(size_t)qq * NC] = acc[i][j][qq];
    }
}

// P1 (split, 960 blocks) + P3 (plain, 256 blocks) in one launch.
__global__ __launch_bounds__(256) void proj_dual(
    const float* __restrict__ xe, const unsigned short* __restrict__ W5h,
    const unsigned short* __restrict__ W5l, float* __restrict__ P1,
    const float* __restrict__ xf, const unsigned short* __restrict__ W3h,
    float* __restrict__ P3) {
  __shared__ __align__(16) unsigned short lds[4][128][40];
  if ((int)blockIdx.x < 960)
    proj_body<true>((char*)lds, blockIdx.x, 96, 10, xe, W5h, W5l, P1);
  else
    proj_body<false>((char*)lds, blockIdx.x - 960, 64, 4, xf, W3h, nullptr, P3);
}

// ---------------------------------------------------------------------------
// Output GEMM with fused combine: A[r][c] = (T4p 2-slab bf16 sum) +
// (T2p 2-slab bf16 sum)*einv_hval;  C = A @ W_o (split hi/lo).
// ---------------------------------------------------------------------------
__global__ __launch_bounds__(256) void gemm_out(
    const unsigned short* __restrict__ T2p, const unsigned short* __restrict__ T4p,
    const float* __restrict__ hEi, const unsigned short* __restrict__ Bh,
    const unsigned short* __restrict__ Bl, float* __restrict__ C) {
  const int gx = gridDim.x, gy = gridDim.y;
  const int nwg = gx * gy;
  const int wid = blockIdx.x + gx * blockIdx.y;
  const int q = nwg >> 3, r = nwg & 7;
  const int xcd = wid & 7, posn = wid >> 3;
  const int swz = (xcd < r ? xcd * (q + 1) : r * (q + 1) + (xcd - r) * q) + posn;
  const int mt = swz / gy;
  const int m0 = mt * 128, n0 = (swz - mt * gy) * 128;

  __shared__ unsigned short lds[4][128][40];
  const int t = threadIdx.x;
  const int w4 = t >> 6, lane = t & 63;
  const int wr = w4 >> 1, wc = w4 & 1;
  const int lr = lane & 15, kq = lane >> 4;
  const long long slab = 6144LL * 256;

  f32x4 acc[4][4] = {};

  for (int kb = 0; kb < 256; kb += 32) {
    #pragma unroll
    for (int a = 0; a < 4; ++a) {
      int idx = t + 256 * a;
      int row = idx >> 3, qd = (idx & 7) * 4;
      int rg = m0 + row;
      int b = rg >= 6144;
      int pos = rg - b * 6144;
      int ck = kb + qd;
      float s = hEi[((size_t)b * 8 + (ck >> 5)) * 6144 + pos];
      const unsigned short* b2 = T2p + ((long long)(b * 2) * 6144 + pos) * 256 + ck;
      const unsigned short* b4 = T4p + ((long long)(b * 2) * 6144 + pos) * 256 + ck;
      u16x4 p20 = *(const u16x4*)b2, p21 = *(const u16x4*)(b2 + slab);
      u16x4 p40 = *(const u16x4*)b4, p41 = *(const u16x4*)(b4 + slab);
      f32x4 t2 = {bf2f(p20[0]) + bf2f(p21[0]), bf2f(p20[1]) + bf2f(p21[1]),
                  bf2f(p20[2]) + bf2f(p21[2]), bf2f(p20[3]) + bf2f(p21[3])};
      f32x4 t4 = {bf2f(p40[0]) + bf2f(p41[0]), bf2f(p40[1]) + bf2f(p41[1]),
                  bf2f(p40[2]) + bf2f(p41[2]), bf2f(p40[3]) + bf2f(p41[3])};
      f32x4 v = t4 + t2 * s;
      u16x4 h = {f2bf(v[0]), f2bf(v[1]), f2bf(v[2]), f2bf(v[3])};
      *(u16x4*)&lds[0][row][qd] = h;
      u16x4 l = {f2bf(v[0] - bf2f(h[0])), f2bf(v[1] - bf2f(h[1])),
                 f2bf(v[2] - bf2f(h[2])), f2bf(v[3] - bf2f(h[3]))};
      *(u16x4*)&lds[2][row][qd] = l;
    }
    #pragma unroll
    for (int a = 0; a < 2; ++a) {
      int idx = t + 256 * a;
      int row = idx >> 2, c8 = (idx & 3) * 8;
      *(u16x8*)&lds[1][row][c8] = *(const u16x8*)(Bh + (size_t)(n0 + row) * 256 + kb + c8);
      *(u16x8*)&lds[3][row][c8] = *(const u16x8*)(Bl + (size_t)(n0 + row) * 256 + kb + c8);
    }
    __syncthreads();

    bf16x8 ah[4], bh[4], al[4], bl[4];
    #pragma unroll
    for (int i = 0; i < 4; ++i) {
      ah[i] = __builtin_bit_cast(bf16x8, *(const u16x8*)&lds[0][wr * 64 + i * 16 + lr][kq * 8]);
      bh[i] = __builtin_bit_cast(bf16x8, *(const u16x8*)&lds[1][wc * 64 + i * 16 + lr][kq * 8]);
      al[i] = __builtin_bit_cast(bf16x8, *(const u16x8*)&lds[2][wr * 64 + i * 16 + lr][kq * 8]);
      bl[i] = __builtin_bit_cast(bf16x8, *(const u16x8*)&lds[3][wc * 64 + i * 16 + lr][kq * 8]);
    }
    #pragma unroll
    for (int i = 0; i < 4; ++i)
      #pragma unroll
      for (int j = 0; j < 4; ++j) {
        acc[i][j] = __builtin_amdgcn_mfma_f32_16x16x32_bf16(ah[i], bh[j], acc[i][j], 0, 0, 0);
        acc[i][j] = __builtin_amdgcn_mfma_f32_16x16x32_bf16(ah[i], bl[j], acc[i][j], 0, 0, 0);
        acc[i][j] = __builtin_amdgcn_mfma_f32_16x16x32_bf16(al[i], bh[j], acc[i][j], 0, 0, 0);
      }
    __syncthreads();
  }

  #pragma unroll
  for (int i = 0; i < 4; ++i)
    #pragma unroll
    for (int j = 0; j < 4; ++j) {
      float* cp = C + (size_t)(m0 + wr * 64 + i * 16 + kq * 4) * 256 + n0 + wc * 64 + j * 16 + lr;
      #pragma unroll
      for (int qq = 0; qq < 4; ++qq) cp[(size_t)qq * 256] = acc[i][j][qq];
    }
}

// ---------------------------------------------------------------------------
// Weight transposes (tiny standalone launch, 128 blocks, 74-stride tiles).
// ---------------------------------------------------------------------------
struct WTab {
  const float* s[8];
  unsigned short* h[8];
  unsigned short* l[8];
};
__global__ __launch_bounds__(256) void wxpose(WTab tab) {
  __shared__ __align__(16) unsigned short smem[2 * 64 * 74];
  unsigned short* thi = smem;
  unsigned short* tlo = smem + 64 * 74;
  const int idx = blockIdx.x;
  const int w = idx >> 4;
  const int r0 = (idx & 3) * 64, c0 = ((idx >> 2) & 3) * 64;
  const float* src = tab.s[w];
  unsigned short* oh = tab.h[w];
  unsigned short* ol = tab.l[w];
  const int t = threadIdx.x;
  #pragma unroll
  for (int a = 0; a < 4; ++a) {
    int idx2 = t + 256 * a;
    int tr = idx2 >> 4, tc = (idx2 & 15) * 4;
    f32x4 v = *(const f32x4*)(src + (size_t)(r0 + tr) * 256 + c0 + tc);
    u16x4 hh = {f2bf(v[0]), f2bf(v[1]), f2bf(v[2]), f2bf(v[3])};
    st4(&thi[tr * 74 + tc], hh);
    if (ol) {
      u16x4 ll = {f2bf(v[0] - bf2f(hh[0])), f2bf(v[1] - bf2f(hh[1])),
                  f2bf(v[2] - bf2f(hh[2])), f2bf(v[3] - bf2f(hh[3]))};
      st4(&tlo[tr * 74 + tc], ll);
    }
  }
  __syncthreads();
  #pragma unroll
  for (int a = 0; a < 2; ++a) {
    int idx2 = t + 256 * a;
    int orow = idx2 >> 3, oc = (idx2 & 7) * 8;
    u16x8 vh;
    #pragma unroll
    for (int j = 0; j < 8; ++j) vh[j] = thi[(oc + j) * 74 + orow];
    *(u16x8*)(oh + (size_t)(c0 + orow) * 256 + r0 + oc) = vh;
    if (ol) {
      u16x8 vl;
      #pragma unroll
      for (int j = 0; j < 8; ++j) vl[j] = tlo[(oc + j) * 74 + orow];
      *(u16x8*)(ol + (size_t)(c0 + orow) * 256 + r0 + oc) = vl;
    }
  }
}

// ---------------------------------------------------------------------------
// prep3: [0,384) T1 GEMM (MODE=2, B = d1 fp32) ; [384,896) vproj ;
// [896,7040) d0 -> d0T ; [7040,19328) d1 -> d1T. 74-stride tiles.
// ---------------------------------------------------------------------------
struct PrepArgs {
  const float* d1; unsigned short* d1T;
  const float* d0; unsigned short* d0T_hi;
  const float* xv; const float* Wvq; const float* Wvk; float* hvV;
};

__global__ __launch_bounds__(256) void prep3(PrepArgs A, GJob jT1) {
  __shared__ __align__(16) char smem[24576];
  const int t = threadIdx.x;
  int bid = blockIdx.x;

  if (bid < 384) {
    gemm_body<2, true, false>(smem, jT1, bid);
    return;
  }
  bid -= 384;

  if (bid < 512) {
    // ---- vproj (np-fp32 exact, 8 rows/block) ----
    float* sx = (float*)smem;
    float* sq = (float*)(smem + 8192);
    float* sk = (float*)(smem + 16384);
    const int r0 = bid * 8;
    const int j = t;
    #pragma unroll
    for (int r = 0; r < 8; ++r) sx[r * 256 + j] = A.xv[(size_t)(r0 + r) * 256 + j];
    __syncthreads();
    float qa[8] = {}, ka[8] = {};
    for (int i = 0; i < 256; ++i) {
      float wq = A.Wvq[i * 256 + j], wk = A.Wvk[i * 256 + j];
      #pragma unroll
      for (int r = 0; r < 8; ++r) {
        qa[r] = __fmaf_rn(sx[r * 256 + i], wq, qa[r]);
        ka[r] = __fmaf_rn(sx[r * 256 + i], wk, ka[r]);
      }
    }
    #pragma unroll
    for (int r = 0; r < 8; ++r) { sq[r * 256 + j] = qa[r]; sk[r * 256 + j] = ka[r]; }
    __syncthreads();
    if (j < 64) {
      const int r = j >> 3, head = j & 7;
      const float* qq = &sq[r * 256 + head * 32];
      const float* kk = &sk[r * 256 + head * 32];
      float s0 = 0.0f, s1 = 0.0f, s2 = 0.0f, s3 = 0.0f;
      #pragma unroll 1
      for (int d = 0; d < 32; d += 4) {
        s0 = __fadd_rn(s0, __fmul_rn(qq[d + 0], kk[d + 0]));
        s1 = __fadd_rn(s1, __fmul_rn(qq[d + 1], kk[d + 1]));
        s2 = __fadd_rn(s2, __fmul_rn(qq[d + 2], kk[d + 2]));
        s3 = __fadd_rn(s3, __fmul_rn(qq[d + 3], kk[d + 3]));
      }
      float p = __fadd_rn(__fadd_rn(s0, s2), __fadd_rn(s1, s3));
      float hval = __fdiv_rn(p, sqrtf(32.0f));
      float inv = __fdiv_rn(1.0f, __fadd_rn(hval, 1e-6f));
      const int row = r0 + r;
      const int b = row / 2048, pos = row - b * 2048;
      A.hvV[((size_t)b * 8 + head) * 2048 + pos] = inv;
    }
  } else if (bid < 6656) {
    // ---- d0: [2][6144][2048] fp32 -> d0T bf16 ----
    const int idx = bid - 512;
    const int x = idx % 96;
    const int rem = idx / 96;
    const int y = rem & 31;
    const int b = rem >> 5;
    const int r0 = x * 64, c0 = y * 64;
    unsigned short* tile = (unsigned short*)smem;   // [64][74]
    #pragma unroll
    for (int a = 0; a < 4; ++a) {
      int idx2 = t + 256 * a;
      int tr = idx2 >> 4, tc = (idx2 & 15) * 4;
      size_t off = ((size_t)b * 6144 + r0 + tr) * 2048 + c0 + tc;
      f32x4 v = *(const f32x4*)(A.d0 + off);
      u16x4 hh = {f2bf(v[0]), f2bf(v[1]), f2bf(v[2]), f2bf(v[3])};
      st4(&tile[tr * 74 + tc], hh);
    }
    __syncthreads();
    #pragma unroll
    for (int a = 0; a < 2; ++a) {
      int idx2 = t + 256 * a;
      int orow = idx2 >> 3, oc = (idx2 & 7) * 8;
      u16x8 vh;
      #pragma unroll
      for (int j = 0; j < 8; ++j) vh[j] = tile[(oc + j) * 74 + orow];
      *(u16x8*)(A.d0T_hi + ((size_t)b * 2048 + c0 + orow) * 6144 + r0 + oc) = vh;
    }
  } else {
    // ---- d1: [2][4096][6144] fp32 -> d1T bf16 ----
    const int idx = bid - 6656;
    const int x = idx & 63;
    const int rem = idx >> 6;
    const int y = rem % 96;
    const int b = rem / 96;
    const int r0 = x * 64, c0 = y * 64;
    unsigned short* tile = (unsigned short*)smem;   // [64][74]
    #pragma unroll
    for (int a = 0; a < 4; ++a) {
      int idx2 = t + 256 * a;
      int tr = idx2 >> 4, tc = (idx2 & 15) * 4;
      size_t off = ((size_t)b * 4096 + r0 + tr) * 6144 + c0 + tc;
      f32x4 v = *(const f32x4*)(A.d1 + off);
      u16x4 hh = {f2bf(v[0]), f2bf(v[1]), f2bf(v[2]), f2bf(v[3])};
      st4(&tile[tr * 74 + tc], hh);
    }
    __syncthreads();
    #pragma unroll
    for (int a = 0; a < 2; ++a) {
      int idx2 = t + 256 * a;
      int orow = idx2 >> 3, oc = (idx2 & 7) * 8;
      u16x8 vh;
      #pragma unroll
      for (int j = 0; j < 8; ++j) vh[j] = tile[(oc + j) * 74 + orow];
      *(u16x8*)(A.d1T + ((size_t)b * 6144 + c0 + orow) * 4096 + r0 + oc) = vh;
    }
  }
}

// ---------------------------------------------------------------------------
// Fused eVT (unscaled bf16) + Y0T (scaled bf16) from P1 cols 512..767.
// ---------------------------------------------------------------------------
__global__ __launch_bounds__(256) void xpose_ev(
    const float* __restrict__ P1, unsigned short* __restrict__ eVT,
    unsigned short* __restrict__ yhi, const float* __restrict__ hE) {
  __shared__ __align__(16) unsigned short smem[2 * 64 * 74];
  unsigned short* te = smem;
  unsigned short* th = smem + 64 * 74;
  const int b = blockIdx.z;
  const int r0 = blockIdx.x * 64, c0 = blockIdx.y * 64;
  const int t = threadIdx.x;
  #pragma unroll
  for (int a = 0; a < 4; ++a) {
    int idx = t + 256 * a;
    int tr = idx >> 4, tc = (idx & 15) * 4;
    f32x4 v = *(const f32x4*)(P1 + ((size_t)b * 6144 + r0 + tr) * 1280 + 512 + c0 + tc);
    u16x4 eh = {f2bf(v[0]), f2bf(v[1]), f2bf(v[2]), f2bf(v[3])};
    st4(&te[tr * 74 + tc], eh);
    float s = hE[((size_t)b * 8 + ((c0 + tc) >> 5)) * 6144 + r0 + tr];
    f32x4 y = v * s;
    u16x4 hh = {f2bf(y[0]), f2bf(y[1]), f2bf(y[2]), f2bf(y[3])};
    st4(&th[tr * 74 + tc], hh);
  }
  __syncthreads();
  #pragma unroll
  for (int a = 0; a < 2; ++a) {
    int idx = t + 256 * a;
    int orow = idx >> 3, oc = (idx & 7) * 8;
    u16x8 ve, vh;
    #pragma unroll
    for (int j = 0; j < 8; ++j) {
      ve[j] = te[(oc + j) * 74 + orow];
      vh[j] = th[(oc + j) * 74 + orow];
    }
    size_t o = ((size_t)b * 256 + c0 + orow) * 6144 + r0 + oc;
    *(u16x8*)(eVT + o) = ve;
    *(u16x8*)(yhi + o) = vh;
  }
}

// ---------------------------------------------------------------------------
// Merged hval dots: [0,3072) e/einv pairs from P1; [3072,5120) f pair from P3.
// ---------------------------------------------------------------------------
__global__ __launch_bounds__(256) void dots(
    const float* __restrict__ P1, float* __restrict__ hE, float* __restrict__ hEi,
    const float* __restrict__ P3, float* __restrict__ hF) {
  const int wv = threadIdx.x >> 6, lane = threadIdx.x & 63;
  if (blockIdx.x < 3072) {
    const int row = blockIdx.x * 4 + wv;
    const float* base = P1 + (size_t)row * 1280 + lane * 4;
    f32x4 qv = *(const f32x4*)(base);
    f32x4 kv = *(const f32x4*)(base + 256);
    float p = qv[0] * kv[0] + qv[1] * kv[1] + qv[2] * kv[2] + qv[3] * kv[3];
    p += __shfl_xor(p, 1); p += __shfl_xor(p, 2); p += __shfl_xor(p, 4);
    f32x4 q2 = *(const f32x4*)(base + 768);
    f32x4 k2 = *(const f32x4*)(base + 1024);
    float p2 = q2[0] * k2[0] + q2[1] * k2[1] + q2[2] * k2[2] + q2[3] * k2[3];
    p2 += __shfl_xor(p2, 1); p2 += __shfl_xor(p2, 2); p2 += __shfl_xor(p2, 4);
    if ((lane & 7) == 0) {
      const int head = lane >> 3;
      const int b = row / 6144, pos = row % 6144;
      hE[((size_t)b * 8 + head) * 6144 + pos] = p * 0.17677669529663687f;
      hEi[((size_t)b * 8 + head) * 6144 + pos] = p2 * 0.17677669529663687f;
    }
  } else {
    const int row = (blockIdx.x - 3072) * 4 + wv;
    const float* base = P3 + (size_t)row * 512 + lane * 4;
    f32x4 qv = *(const f32x4*)(base);
    f32x4 kv = *(const f32x4*)(base + 256);
    float p = qv[0] * kv[0] + qv[1] * kv[1] + qv[2] * kv[2] + qv[3] * kv[3];
    p += __shfl_xor(p, 1); p += __shfl_xor(p, 2); p += __shfl_xor(p, 4);
    if ((lane & 7) == 0) {
      const int head = lane >> 3;
      const int b = row / 4096, pos = row % 4096;
      hF[((size_t)b * 8 + head) * 4096 + pos] = p * 0.17677669529663687f;
    }
  }
}

// ---------------------------------------------------------------------------
extern "C" void kernel_launch(void* const* d_in, const int* in_sizes, int n_in,
                              void* d_out, int out_size, void* d_ws, size_t ws_size,
                              hipStream_t stream) {
  const float* x_v = (const float*)d_in[0];
  const float* x_e = (const float*)d_in[1];
  const float* x_f = (const float*)d_in[2];
  const float* d0  = (const float*)d_in[3];   // (2, 6144, 2048)
  const float* d1  = (const float*)d_in[4];   // (2, 4096, 6144)
  float* out = (float*)d_out;

  const int NV = 2048, ME = 6144, KF = 4096;

  char* ws = (char*)d_ws;
  size_t o = 0;
  auto alloc = [&](size_t bytes) { size_t r = o; o = (o + bytes + 255) & ~255ULL; return r; };

  unsigned short* Wcat5_hi = (unsigned short*)(ws + alloc(1280 * 256 * 2));
  unsigned short* Wcat5_lo = (unsigned short*)(ws + alloc(1280 * 256 * 2));
  unsigned short* W3_hi = (unsigned short*)(ws + alloc(512 * 256 * 2));
  unsigned short* Wo_hi = (unsigned short*)(ws + alloc(256 * 256 * 2));
  unsigned short* Wo_lo = (unsigned short*)(ws + alloc(256 * 256 * 2));
  float* pHvE  = (float*)(ws + alloc(2 * 8 * ME * 4));
  float* pHvEi = (float*)(ws + alloc(2 * 8 * ME * 4));
  float* pHvF  = (float*)(ws + alloc(2 * 8 * KF * 4));
  float* pHvV  = (float*)(ws + alloc(2 * 8 * NV * 4));
  unsigned short* d1T_hi = (unsigned short*)(ws + alloc((size_t)2 * ME * KF * 2));   // [2][6144][4096]
  unsigned short* d0T_hi = (unsigned short*)(ws + alloc((size_t)2 * NV * ME * 2));   // [2][2048][6144]
  unsigned short* eVT_hi = (unsigned short*)(ws + alloc((size_t)2 * 256 * ME * 2));
  unsigned short* Y0T_hi = (unsigned short*)(ws + alloc((size_t)2 * 256 * ME * 2));
  unsigned short* T1sT_hi = (unsigned short*)(ws + alloc((size_t)2 * 256 * KF * 2));
  unsigned short* T3sT_hi = (unsigned short*)(ws + alloc((size_t)2 * 256 * NV * 2));
  float* pP1 = (float*)(ws + alloc((size_t)12288 * 1280 * 4));
  float* pP3 = (float*)(ws + alloc((size_t)8192 * 512 * 4));
  float* pTp1 = (float*)(ws + alloc((size_t)2 * 3 * 256 * KF * 4));   // T1^T slabs fp32
  float* pTp3 = (float*)(ws + alloc((size_t)2 * 6 * 256 * NV * 4));   // T3^T slabs fp32
  unsigned short* pT2p = (unsigned short*)(ws + alloc((size_t)2 * 2 * ME * 256 * 2));  // bf16 slabs
  unsigned short* pT4p = (unsigned short*)(ws + alloc((size_t)2 * 2 * ME * 256 * 2));

  dim3 blk(256);

  // --- weight transposes (tiny) ---
  WTab tab;
  tab.s[0] = (const float*)d_in[7];  tab.h[0] = Wcat5_hi;          tab.l[0] = Wcat5_lo;
  tab.s[1] = (const float*)d_in[8];  tab.h[1] = Wcat5_hi + 65536;  tab.l[1] = Wcat5_lo + 65536;
  tab.s[2] = (const float*)d_in[11]; tab.h[2] = Wcat5_hi + 131072; tab.l[2] = Wcat5_lo + 131072;
  tab.s[3] = (const float*)d_in[9];  tab.h[3] = Wcat5_hi + 196608; tab.l[3] = Wcat5_lo + 196608;
  tab.s[4] = (const float*)d_in[10]; tab.h[4] = Wcat5_hi + 262144; tab.l[4] = Wcat5_lo + 262144;
  tab.s[5] = (const float*)d_in[12]; tab.h[5] = W3_hi;             tab.l[5] = nullptr;
  tab.s[6] = (const float*)d_in[13]; tab.h[6] = W3_hi + 65536;     tab.l[6] = nullptr;
  tab.s[7] = (const float*)d_in[14]; tab.h[7] = Wo_hi;             tab.l[7] = Wo_lo;
  wxpose<<<128, blk, 0, stream>>>(tab);

  // --- projections + hvals + eV transposes ---
  proj_dual<<<1216, blk, 0, stream>>>(x_e, Wcat5_hi, Wcat5_lo, pP1, x_f, W3_hi, pP3);
  dots<<<5120, blk, 0, stream>>>(pP1, pHvE, pHvEi, pP3, pHvF);
  xpose_ev<<<dim3(96, 4, 2), blk, 0, stream>>>(pP1, eVT_hi, Y0T_hi, pHvE);

  // --- prep3: T1 GEMM + vproj + d0T + d1T in one launch ---
  GJob jT1 = {};
  jT1.Ah = eVT_hi; jT1.Bf = d1; jT1.C = pTp1;
  jT1.K = ME; jT1.ldA = ME; jT1.ldB = ME; jT1.S = 3; jT1.gx = 2; jT1.gy = 32;
  jT1.sA = 256LL * ME; jT1.sB = (long long)KF * ME; jT1.sC = 256LL * KF;
  PrepArgs pa;
  pa.d1 = d1; pa.d1T = d1T_hi;
  pa.d0 = d0; pa.d0T_hi = d0T_hi;
  pa.xv = x_v; pa.Wvq = (const float*)d_in[5]; pa.Wvk = (const float*)d_in[6];
  pa.hvV = pHvV;
  prep3<<<19328, blk, 0, stream>>>(pa, jT1);

  // --- T3 GEMM + rsc of T1 slabs in one launch ---
  GJob jT3 = {};
  jT3.Ah = Y0T_hi; jT3.Bh = d0T_hi; jT3.C = pTp3;
  jT3.K = ME; jT3.ldA = ME; jT3.ldB = ME; jT3.S = 6; jT3.gx = 2; jT3.gy = 16;
  jT3.sA = 256LL * ME; jT3.sB = (long long)NV * ME; jT3.sC = 256LL * NV;
  t3_rsc1<<<2432, blk, 0, stream>>>(jT3, pTp1, T1sT_hi, pHvF);

  // --- rsc of T3 slabs ---
  rsc3k<<<1024, blk, 0, stream>>>(pTp3, T3sT_hi, pHvV);

  // --- T2 + T4 (T4: A = d0 fp32 cvt-in-staging); bf16 C slabs ---
  GJob jT2 = {}, jT4 = {};
  jT2.Ah = d1T_hi; jT2.Bh = T1sT_hi; jT2.C16 = pT2p;
  jT2.K = KF; jT2.ldA = KF; jT2.ldB = KF; jT2.S = 2; jT2.gx = 48; jT2.gy = 2;
  jT2.sA = (long long)ME * KF; jT2.sB = 256LL * KF; jT2.sC = (long long)ME * 256;
  jT4.Af = d0; jT4.Bh = T3sT_hi; jT4.C16 = pT4p;
  jT4.K = NV; jT4.ldA = NV; jT4.ldB = NV; jT4.S = 2; jT4.gx = 48; jT4.gy = 2;
  jT4.sA = (long long)ME * NV; jT4.sB = 256LL * NV; jT4.sC = (long long)ME * 256;
  gemm_dual<0, 1, false, true><<<768, blk, 0, stream>>>(jT2, jT4, 384);

  // --- fused combine + output projection ---
  gemm_out<<<dim3(96, 2, 1), blk, 0, stream>>>(pT2p, pT4p, pHvEi, Wo_hi, Wo_lo, out);
}

// Round 20
// 366.255 us; speedup vs baseline: 1.1926x; 1.0207x over previous
//
#include <hip/hip_runtime.h>
#include <hip/hip_bf16.h>
#include <cstdint>
#include <cstddef>

// ---------------------------------------------------------------------------
// MeshMultiHeadHodgeLaplaceAttention  (b=2, n=2048, m=6144, k=4096, D=256, H=8)
//
//   up:   T1 = d_1 @ eV ; *f_hval ; T2 = d_1^T @ T1s ; (*einv_hval in combine)
//   down: Y0 = eV*e_hval ; T3 = d_0^T @ Y0 ; *1/(v_hval+eps) ; T4 = d_0 @ T3s
//   out = (T2*einv_hval + T4) @ W_o
//
// Precision: v_hval replicates numpy fp32 bit-exactly; P1 + output GEMM
// split-bf16; T1..T4 plain bf16; ALL split-K slabs bf16 (T2/T4 validated
// R18 at absmax=256; T1/T3 same-order noise, budget 793.6).
//
// R20: revert R19's prep3 fusion (VGPR 44->76 cut streamer occupancy
// 48->32%, prep ballooned 117->182 us). Back to R18 structure; NEW: T1/T3
// slabs stored bf16 (-50 MB round-trip), rsc2 reads bf16.
// ---------------------------------------------------------------------------

typedef __attribute__((ext_vector_type(4))) float f32x4;
typedef __attribute__((ext_vector_type(2))) unsigned short u16x2;
typedef __attribute__((ext_vector_type(4))) unsigned short u16x4;
typedef __attribute__((ext_vector_type(8))) unsigned short u16x8;
typedef __attribute__((ext_vector_type(8))) __bf16 bf16x8;

static __device__ __forceinline__ unsigned short f2bf(float f) {
  uint32_t u = __builtin_bit_cast(uint32_t, f);
  uint32_t r = (u + 0x7FFFu + ((u >> 16) & 1u)) >> 16;  // RNE
  return (unsigned short)r;
}
static __device__ __forceinline__ float bf2f(unsigned short h) {
  return __builtin_bit_cast(float, (uint32_t)h << 16);
}
static __device__ __forceinline__ void st4(unsigned short* p, u16x4 v) {
  *(u16x2*)p = u16x2{v[0], v[1]};
  *(u16x2*)(p + 2) = u16x2{v[2], v[3]};
}

// ---------------------------------------------------------------------------
// Mode-templated GEMM body. MODE: 0 = A,B bf16 ; 1 = A fp32 cvt ; 2 = B fp32
// cvt. BF16C: store C as bf16. C[M x gy*128] = A[M x K] * B[N x K];
// split-K z = batch*S + split. 128x128 tile, BK=32, reg-prefetch.
// ---------------------------------------------------------------------------
struct GJob {
  const unsigned short* Ah; const float* Af;
  const unsigned short* Bh; const float* Bf;
  float* C; unsigned short* C16;
  int K, ldA, ldB, S, gx, gy;
  long long sA, sB, sC;
};

template <int MODE, bool XFAST, bool BF16C>
static __device__ void gemm_body(char* smem, const GJob& J, int b) {
  const int per = J.gx * J.gy;
  const int z = b / per;
  const int wid = b - z * per;
  const int batch = z / J.S, split = z - batch * J.S;
  const unsigned short* Ah = nullptr; const float* Af = nullptr;
  const unsigned short* Bh = nullptr; const float* Bf = nullptr;
  if constexpr (MODE == 1) Af = J.Af + (long long)batch * J.sA;
  else                     Ah = J.Ah + (long long)batch * J.sA;
  if constexpr (MODE == 2) Bf = J.Bf + (long long)batch * J.sB;
  else                     Bh = J.Bh + (long long)batch * J.sB;

  const int nwg = per;
  const int q = nwg >> 3, r = nwg & 7;
  const int xcd = wid & 7, posn = wid >> 3;
  const int swz = (xcd < r ? xcd * (q + 1) : r * (q + 1) + (xcd - r) * q) + posn;
  int mt, nt;
  if constexpr (XFAST) { mt = swz % J.gx; nt = swz / J.gx; }
  else                 { mt = swz / J.gy; nt = swz - mt * J.gy; }
  const int m0 = mt * 128, n0 = nt * 128;
  const int NC = J.gy << 7;
  const int kLen = J.K / J.S, k0base = split * kLen;

  typedef unsigned short ldsrow[128][40];
  ldsrow* lds = (ldsrow*)smem;   // [2][128][40]

  const int t = threadIdx.x;
  const int w4 = t >> 6, lane = t & 63;
  const int wr = w4 >> 1, wc = w4 & 1;
  const int lr = lane & 15, kq = lane >> 4;
  const int rowV = t >> 2, c8V = (t & 3) * 8;     // bf16 staging
  const int rowA8 = t >> 3, qdA = (t & 7) * 4;    // fp32 staging

  u16x8 rAh[2], rBh[2];
  f32x4 rF[4];

  auto LOAD = [&](int kb) {
    if constexpr (MODE == 1) {
      #pragma unroll
      for (int a = 0; a < 4; ++a)
        rF[a] = *(const f32x4*)(Af + (size_t)(m0 + rowA8 + 32 * a) * J.ldA + kb + qdA);
    } else {
      #pragma unroll
      for (int a = 0; a < 2; ++a)
        rAh[a] = *(const u16x8*)(Ah + (size_t)(m0 + rowV + 64 * a) * J.ldA + kb + c8V);
    }
    if constexpr (MODE == 2) {
      #pragma unroll
      for (int a = 0; a < 4; ++a)
        rF[a] = *(const f32x4*)(Bf + (size_t)(n0 + rowA8 + 32 * a) * J.ldB + kb + qdA);
    } else {
      #pragma unroll
      for (int a = 0; a < 2; ++a)
        rBh[a] = *(const u16x8*)(Bh + (size_t)(n0 + rowV + 64 * a) * J.ldB + kb + c8V);
    }
  };
  auto STORE = [&]() {
    if constexpr (MODE == 1) {
      #pragma unroll
      for (int a = 0; a < 4; ++a) {
        f32x4 v = rF[a];
        u16x4 h = {f2bf(v[0]), f2bf(v[1]), f2bf(v[2]), f2bf(v[3])};
        *(u16x4*)&lds[0][rowA8 + 32 * a][qdA] = h;
      }
    } else {
      #pragma unroll
      for (int a = 0; a < 2; ++a) *(u16x8*)&lds[0][rowV + 64 * a][c8V] = rAh[a];
    }
    if constexpr (MODE == 2) {
      #pragma unroll
      for (int a = 0; a < 4; ++a) {
        f32x4 v = rF[a];
        u16x4 h = {f2bf(v[0]), f2bf(v[1]), f2bf(v[2]), f2bf(v[3])};
        *(u16x4*)&lds[1][rowA8 + 32 * a][qdA] = h;
      }
    } else {
      #pragma unroll
      for (int a = 0; a < 2; ++a) *(u16x8*)&lds[1][rowV + 64 * a][c8V] = rBh[a];
    }
  };

  f32x4 acc[4][4] = {};
  LOAD(k0base);
  for (int kk = 0; kk < kLen; kk += 32) {
    STORE();
    __syncthreads();
    if (kk + 32 < kLen) LOAD(k0base + kk + 32);  // prefetch under MFMA

    bf16x8 ah[4], bh[4];
    #pragma unroll
    for (int i = 0; i < 4; ++i) {
      ah[i] = __builtin_bit_cast(bf16x8, *(const u16x8*)&lds[0][wr * 64 + i * 16 + lr][kq * 8]);
      bh[i] = __builtin_bit_cast(bf16x8, *(const u16x8*)&lds[1][wc * 64 + i * 16 + lr][kq * 8]);
    }
    #pragma unroll
    for (int i = 0; i < 4; ++i)
      #pragma unroll
      for (int j = 0; j < 4; ++j)
        acc[i][j] = __builtin_amdgcn_mfma_f32_16x16x32_bf16(ah[i], bh[j], acc[i][j], 0, 0, 0);
    __syncthreads();
  }

  if constexpr (BF16C) {
    unsigned short* C16 = J.C16 + (long long)z * J.sC;
    #pragma unroll
    for (int i = 0; i < 4; ++i)
      #pragma unroll
      for (int j = 0; j < 4; ++j) {
        unsigned short* cp = C16 + (size_t)(m0 + wr * 64 + i * 16 + kq * 4) * NC + n0 + wc * 64 + j * 16 + lr;
        #pragma unroll
        for (int qq = 0; qq < 4; ++qq) cp[(size_t)qq * NC] = f2bf(acc[i][j][qq]);
      }
  } else {
    float* C = J.C + (long long)z * J.sC;
    #pragma unroll
    for (int i = 0; i < 4; ++i)
      #pragma unroll
      for (int j = 0; j < 4; ++j) {
        float* cp = C + (size_t)(m0 + wr * 64 + i * 16 + kq * 4) * NC + n0 + wc * 64 + j * 16 + lr;
        #pragma unroll
        for (int qq = 0; qq < 4; ++qq) cp[(size_t)qq * NC] = acc[i][j][qq];
      }
  }
}

template <int M0, int M1, bool XFAST, bool BF16C>
__global__ __launch_bounds__(256) void gemm_dual(GJob j0, GJob j1, int nb0) {
  __shared__ __align__(16) unsigned short lds[2][128][40];
  if ((int)blockIdx.x < nb0) gemm_body<M0, XFAST, BF16C>((char*)lds, j0, blockIdx.x);
  else                       gemm_body<M1, XFAST, BF16C>((char*)lds, j1, blockIdx.x - nb0);
}

// ---------------------------------------------------------------------------
// rsc body, bf16 slabs in (sum S slabs ascending, scale, cvt bf16 out).
// ---------------------------------------------------------------------------
static __device__ __forceinline__ void rsc_body16(
    const unsigned short* in, unsigned short* out_hi, const float* h,
    int S, int R, int P, int bid, int nblk) {
  const long long qP = P >> 2;
  const long long nq = 2LL * R * qP;
  long long i = (long long)bid * 256 + threadIdx.x;
  const long long stride = (long long)nblk * 256;
  for (; i < nq; i += stride) {
    long long b = i / (R * qP);
    long long rem = i - b * (R * qP);
    int row = (int)(rem / qP);
    long long qc = rem - (long long)row * qP;
    const u16x4* base = (const u16x4*)in + ((b * S) * R + row) * qP + qc;
    f32x4 v = {0.0f, 0.0f, 0.0f, 0.0f};
    for (int s = 0; s < S; ++s) {
      u16x4 p = base[(long long)s * R * qP];
      v[0] += bf2f(p[0]); v[1] += bf2f(p[1]);
      v[2] += bf2f(p[2]); v[3] += bf2f(p[3]);
    }
    v *= *(const f32x4*)(h + ((size_t)b * 8 + (row >> 5)) * P + (qc << 2));
    u16x4 hh = {f2bf(v[0]), f2bf(v[1]), f2bf(v[2]), f2bf(v[3])};
    ((u16x4*)out_hi)[i] = hh;
  }
}

__global__ void rsc2(const unsigned short* in1, unsigned short* o1h, const float* hF,
                     const unsigned short* in3, unsigned short* o3h, const float* hV) {
  if (blockIdx.x < 2048)
    rsc_body16(in1, o1h, hF, 3, 256, 4096, blockIdx.x, 2048);
  else
    rsc_body16(in3, o3h, hV, 6, 256, 2048, blockIdx.x - 2048, 1024);
}

// ---------------------------------------------------------------------------
// Projection GEMM body (K=256): C = A fp32 (cvt) * B bf16 hi(/lo).
// ---------------------------------------------------------------------------
template <bool SPLIT>
static __device__ void proj_body(char* smem, int wid, int gx, int gy,
                                 const float* __restrict__ Af,
                                 const unsigned short* __restrict__ Bh,
                                 const unsigned short* __restrict__ Bl,
                                 float* __restrict__ C) {
  const int nwg = gx * gy;
  const int q = nwg >> 3, r = nwg & 7;
  const int xcd = wid & 7, posn = wid >> 3;
  const int swz = (xcd < r ? xcd * (q + 1) : r * (q + 1) + (xcd - r) * q) + posn;
  const int mt = swz / gy;
  const int m0 = mt * 128, n0 = (swz - mt * gy) * 128;
  const int NC = gy << 7;

  typedef unsigned short ldsrow[128][40];
  ldsrow* lds = (ldsrow*)smem;

  const int t = threadIdx.x;
  const int w4 = t >> 6, lane = t & 63;
  const int wr = w4 >> 1, wc = w4 & 1;
  const int lr = lane & 15, kq = lane >> 4;
  const int rowA8 = t >> 3, qdA = (t & 7) * 4;
  const int rowV = t >> 2, c8V = (t & 3) * 8;

  f32x4 rAf[4];
  u16x8 rBh[2], rBl[2];

  auto LOAD = [&](int kb) {
    #pragma unroll
    for (int a = 0; a < 4; ++a)
      rAf[a] = *(const f32x4*)(Af + (size_t)(m0 + rowA8 + 32 * a) * 256 + kb + qdA);
    #pragma unroll
    for (int a = 0; a < 2; ++a) {
      rBh[a] = *(const u16x8*)(Bh + (size_t)(n0 + rowV + 64 * a) * 256 + kb + c8V);
      if constexpr (SPLIT)
        rBl[a] = *(const u16x8*)(Bl + (size_t)(n0 + rowV + 64 * a) * 256 + kb + c8V);
    }
  };
  auto STORE = [&]() {
    #pragma unroll
    for (int a = 0; a < 4; ++a) {
      f32x4 v = rAf[a];
      u16x4 h = {f2bf(v[0]), f2bf(v[1]), f2bf(v[2]), f2bf(v[3])};
      *(u16x4*)&lds[0][rowA8 + 32 * a][qdA] = h;
      if constexpr (SPLIT) {
        u16x4 l = {f2bf(v[0] - bf2f(h[0])), f2bf(v[1] - bf2f(h[1])),
                   f2bf(v[2] - bf2f(h[2])), f2bf(v[3] - bf2f(h[3]))};
        *(u16x4*)&lds[2][rowA8 + 32 * a][qdA] = l;
      }
    }
    #pragma unroll
    for (int a = 0; a < 2; ++a) {
      *(u16x8*)&lds[1][rowV + 64 * a][c8V] = rBh[a];
      if constexpr (SPLIT) *(u16x8*)&lds[3][rowV + 64 * a][c8V] = rBl[a];
    }
  };

  f32x4 acc[4][4] = {};
  LOAD(0);
  for (int kk = 0; kk < 256; kk += 32) {
    STORE();
    __syncthreads();
    if (kk + 32 < 256) LOAD(kk + 32);

    bf16x8 ah[4], bh[4], al[4], bl[4];
    #pragma unroll
    for (int i = 0; i < 4; ++i) {
      ah[i] = __builtin_bit_cast(bf16x8, *(const u16x8*)&lds[0][wr * 64 + i * 16 + lr][kq * 8]);
      bh[i] = __builtin_bit_cast(bf16x8, *(const u16x8*)&lds[1][wc * 64 + i * 16 + lr][kq * 8]);
      if constexpr (SPLIT) {
        al[i] = __builtin_bit_cast(bf16x8, *(const u16x8*)&lds[2][wr * 64 + i * 16 + lr][kq * 8]);
        bl[i] = __builtin_bit_cast(bf16x8, *(const u16x8*)&lds[3][wc * 64 + i * 16 + lr][kq * 8]);
      }
    }
    #pragma unroll
    for (int i = 0; i < 4; ++i)
      #pragma unroll
      for (int j = 0; j < 4; ++j) {
        acc[i][j] = __builtin_amdgcn_mfma_f32_16x16x32_bf16(ah[i], bh[j], acc[i][j], 0, 0, 0);
        if constexpr (SPLIT) {
          acc[i][j] = __builtin_amdgcn_mfma_f32_16x16x32_bf16(ah[i], bl[j], acc[i][j], 0, 0, 0);
          acc[i][j] = __builtin_amdgcn_mfma_f32_16x16x32_bf16(al[i], bh[j], acc[i][j], 0, 0, 0);
        }
      }
    __syncthreads();
  }

  #pragma unroll
  for (int i = 0; i < 4; ++i)
    #pragma unroll
    for (int j = 0; j < 4; ++j) {
      float* cp = C + (size_t)(m0 + wr * 64 + i * 16 + kq * 4) * NC + n0 + wc * 64 + j * 16 + lr;
      #pragma unroll
      for (int qq = 0; qq < 4; ++qq) cp[(size_t)qq * NC] = acc[i][j][qq];
    }
}

// P1 (split, 960 blocks) + P3 (plain, 256 blocks) in one launch.
__global__ __launch_bounds__(256) void proj_dual(
    const float* __restrict__ xe, const unsigned short* __restrict__ W5h,
    const unsigned short* __restrict__ W5l, float* __restrict__ P1,
    const float* __restrict__ xf, const unsigned short* __restrict__ W3h,
    float* __restrict__ P3) {
  __shared__ __align__(16) unsigned short lds[4][128][40];
  if ((int)blockIdx.x < 960)
    proj_body<true>((char*)lds, blockIdx.x, 96, 10, xe, W5h, W5l, P1);
  else
    proj_body<false>((char*)lds, blockIdx.x - 960, 64, 4, xf, W3h, nullptr, P3);
}

// ---------------------------------------------------------------------------
// Output GEMM with fused combine: A[r][c] = (T4p 2-slab bf16 sum) +
// (T2p 2-slab bf16 sum)*einv_hval;  C = A @ W_o (split hi/lo).
// ---------------------------------------------------------------------------
__global__ __launch_bounds__(256) void gemm_out(
    const unsigned short* __restrict__ T2p, const unsigned short* __restrict__ T4p,
    const float* __restrict__ hEi, const unsigned short* __restrict__ Bh,
    const unsigned short* __restrict__ Bl, float* __restrict__ C) {
  const int gx = gridDim.x, gy = gridDim.y;
  const int nwg = gx * gy;
  const int wid = blockIdx.x + gx * blockIdx.y;
  const int q = nwg >> 3, r = nwg & 7;
  const int xcd = wid & 7, posn = wid >> 3;
  const int swz = (xcd < r ? xcd * (q + 1) : r * (q + 1) + (xcd - r) * q) + posn;
  const int mt = swz / gy;
  const int m0 = mt * 128, n0 = (swz - mt * gy) * 128;

  __shared__ unsigned short lds[4][128][40];
  const int t = threadIdx.x;
  const int w4 = t >> 6, lane = t & 63;
  const int wr = w4 >> 1, wc = w4 & 1;
  const int lr = lane & 15, kq = lane >> 4;
  const long long slab = 6144LL * 256;

  f32x4 acc[4][4] = {};

  for (int kb = 0; kb < 256; kb += 32) {
    #pragma unroll
    for (int a = 0; a < 4; ++a) {
      int idx = t + 256 * a;
      int row = idx >> 3, qd = (idx & 7) * 4;
      int rg = m0 + row;
      int b = rg >= 6144;
      int pos = rg - b * 6144;
      int ck = kb + qd;
      float s = hEi[((size_t)b * 8 + (ck >> 5)) * 6144 + pos];
      const unsigned short* b2 = T2p + ((long long)(b * 2) * 6144 + pos) * 256 + ck;
      const unsigned short* b4 = T4p + ((long long)(b * 2) * 6144 + pos) * 256 + ck;
      u16x4 p20 = *(const u16x4*)b2, p21 = *(const u16x4*)(b2 + slab);
      u16x4 p40 = *(const u16x4*)b4, p41 = *(const u16x4*)(b4 + slab);
      f32x4 t2 = {bf2f(p20[0]) + bf2f(p21[0]), bf2f(p20[1]) + bf2f(p21[1]),
                  bf2f(p20[2]) + bf2f(p21[2]), bf2f(p20[3]) + bf2f(p21[3])};
      f32x4 t4 = {bf2f(p40[0]) + bf2f(p41[0]), bf2f(p40[1]) + bf2f(p41[1]),
                  bf2f(p40[2]) + bf2f(p41[2]), bf2f(p40[3]) + bf2f(p41[3])};
      f32x4 v = t4 + t2 * s;
      u16x4 h = {f2bf(v[0]), f2bf(v[1]), f2bf(v[2]), f2bf(v[3])};
      *(u16x4*)&lds[0][row][qd] = h;
      u16x4 l = {f2bf(v[0] - bf2f(h[0])), f2bf(v[1] - bf2f(h[1])),
                 f2bf(v[2] - bf2f(h[2])), f2bf(v[3] - bf2f(h[3]))};
      *(u16x4*)&lds[2][row][qd] = l;
    }
    #pragma unroll
    for (int a = 0; a < 2; ++a) {
      int idx = t + 256 * a;
      int row = idx >> 2, c8 = (idx & 3) * 8;
      *(u16x8*)&lds[1][row][c8] = *(const u16x8*)(Bh + (size_t)(n0 + row) * 256 + kb + c8);
      *(u16x8*)&lds[3][row][c8] = *(const u16x8*)(Bl + (size_t)(n0 + row) * 256 + kb + c8);
    }
    __syncthreads();

    bf16x8 ah[4], bh[4], al[4], bl[4];
    #pragma unroll
    for (int i = 0; i < 4; ++i) {
      ah[i] = __builtin_bit_cast(bf16x8, *(const u16x8*)&lds[0][wr * 64 + i * 16 + lr][kq * 8]);
      bh[i] = __builtin_bit_cast(bf16x8, *(const u16x8*)&lds[1][wc * 64 + i * 16 + lr][kq * 8]);
      al[i] = __builtin_bit_cast(bf16x8, *(const u16x8*)&lds[2][wr * 64 + i * 16 + lr][kq * 8]);
      bl[i] = __builtin_bit_cast(bf16x8, *(const u16x8*)&lds[3][wc * 64 + i * 16 + lr][kq * 8]);
    }
    #pragma unroll
    for (int i = 0; i < 4; ++i)
      #pragma unroll
      for (int j = 0; j < 4; ++j) {
        acc[i][j] = __builtin_amdgcn_mfma_f32_16x16x32_bf16(ah[i], bh[j], acc[i][j], 0, 0, 0);
        acc[i][j] = __builtin_amdgcn_mfma_f32_16x16x32_bf16(ah[i], bl[j], acc[i][j], 0, 0, 0);
        acc[i][j] = __builtin_amdgcn_mfma_f32_16x16x32_bf16(al[i], bh[j], acc[i][j], 0, 0, 0);
      }
    __syncthreads();
  }

  #pragma unroll
  for (int i = 0; i < 4; ++i)
    #pragma unroll
    for (int j = 0; j < 4; ++j) {
      float* cp = C + (size_t)(m0 + wr * 64 + i * 16 + kq * 4) * 256 + n0 + wc * 64 + j * 16 + lr;
      #pragma unroll
      for (int qq = 0; qq < 4; ++qq) cp[(size_t)qq * 256] = acc[i][j][qq];
    }
}

// ---------------------------------------------------------------------------
// Weight transposes (tiny standalone launch, 128 blocks, 74-stride tiles).
// ---------------------------------------------------------------------------
struct WTab {
  const float* s[8];
  unsigned short* h[8];
  unsigned short* l[8];
};
__global__ __launch_bounds__(256) void wxpose(WTab tab) {
  __shared__ __align__(16) unsigned short smem[2 * 64 * 74];
  unsigned short* thi = smem;
  unsigned short* tlo = smem + 64 * 74;
  const int idx = blockIdx.x;
  const int w = idx >> 4;
  const int r0 = (idx & 3) * 64, c0 = ((idx >> 2) & 3) * 64;
  const float* src = tab.s[w];
  unsigned short* oh = tab.h[w];
  unsigned short* ol = tab.l[w];
  const int t = threadIdx.x;
  #pragma unroll
  for (int a = 0; a < 4; ++a) {
    int idx2 = t + 256 * a;
    int tr = idx2 >> 4, tc = (idx2 & 15) * 4;
    f32x4 v = *(const f32x4*)(src + (size_t)(r0 + tr) * 256 + c0 + tc);
    u16x4 hh = {f2bf(v[0]), f2bf(v[1]), f2bf(v[2]), f2bf(v[3])};
    st4(&thi[tr * 74 + tc], hh);
    if (ol) {
      u16x4 ll = {f2bf(v[0] - bf2f(hh[0])), f2bf(v[1] - bf2f(hh[1])),
                  f2bf(v[2] - bf2f(hh[2])), f2bf(v[3] - bf2f(hh[3]))};
      st4(&tlo[tr * 74 + tc], ll);
    }
  }
  __syncthreads();
  #pragma unroll
  for (int a = 0; a < 2; ++a) {
    int idx2 = t + 256 * a;
    int orow = idx2 >> 3, oc = (idx2 & 7) * 8;
    u16x8 vh;
    #pragma unroll
    for (int j = 0; j < 8; ++j) vh[j] = thi[(oc + j) * 74 + orow];
    *(u16x8*)(oh + (size_t)(c0 + orow) * 256 + r0 + oc) = vh;
    if (ol) {
      u16x8 vl;
      #pragma unroll
      for (int j = 0; j < 8; ++j) vl[j] = tlo[(oc + j) * 74 + orow];
      *(u16x8*)(ol + (size_t)(c0 + orow) * 256 + r0 + oc) = vl;
    }
  }
}

// ---------------------------------------------------------------------------
// prep2: [0,512) vproj ; [512,6656) d0 -> d0T ; [6656,18944) d1 -> d1T (LAST,
// so d1 stays L3-warm for the immediately following T1). 74-stride tiles.
// ---------------------------------------------------------------------------
struct PrepArgs {
  const float* d1; unsigned short* d1T;
  const float* d0; unsigned short* d0T_hi;
  const float* xv; const float* Wvq; const float* Wvk; float* hvV;
};

__global__ __launch_bounds__(256) void prep2(PrepArgs A) {
  __shared__ __align__(16) char smem[24576];
  const int t = threadIdx.x;
  const int bid = blockIdx.x;

  if (bid < 512) {
    // ---- vproj (np-fp32 exact, 8 rows/block) ----
    float* sx = (float*)smem;
    float* sq = (float*)(smem + 8192);
    float* sk = (float*)(smem + 16384);
    const int r0 = bid * 8;
    const int j = t;
    #pragma unroll
    for (int r = 0; r < 8; ++r) sx[r * 256 + j] = A.xv[(size_t)(r0 + r) * 256 + j];
    __syncthreads();
    float qa[8] = {}, ka[8] = {};
    for (int i = 0; i < 256; ++i) {
      float wq = A.Wvq[i * 256 + j], wk = A.Wvk[i * 256 + j];
      #pragma unroll
      for (int r = 0; r < 8; ++r) {
        qa[r] = __fmaf_rn(sx[r * 256 + i], wq, qa[r]);
        ka[r] = __fmaf_rn(sx[r * 256 + i], wk, ka[r]);
      }
    }
    #pragma unroll
    for (int r = 0; r < 8; ++r) { sq[r * 256 + j] = qa[r]; sk[r * 256 + j] = ka[r]; }
    __syncthreads();
    if (j < 64) {
      const int r = j >> 3, head = j & 7;
      const float* qq = &sq[r * 256 + head * 32];
      const float* kk = &sk[r * 256 + head * 32];
      float s0 = 0.0f, s1 = 0.0f, s2 = 0.0f, s3 = 0.0f;
      #pragma unroll 1
      for (int d = 0; d < 32; d += 4) {
        s0 = __fadd_rn(s0, __fmul_rn(qq[d + 0], kk[d + 0]));
        s1 = __fadd_rn(s1, __fmul_rn(qq[d + 1], kk[d + 1]));
        s2 = __fadd_rn(s2, __fmul_rn(qq[d + 2], kk[d + 2]));
        s3 = __fadd_rn(s3, __fmul_rn(qq[d + 3], kk[d + 3]));
      }
      float p = __fadd_rn(__fadd_rn(s0, s2), __fadd_rn(s1, s3));
      float hval = __fdiv_rn(p, sqrtf(32.0f));
      float inv = __fdiv_rn(1.0f, __fadd_rn(hval, 1e-6f));
      const int row = r0 + r;
      const int b = row / 2048, pos = row - b * 2048;
      A.hvV[((size_t)b * 8 + head) * 2048 + pos] = inv;
    }
  } else if (bid < 6656) {
    // ---- d0: [2][6144][2048] fp32 -> d0T bf16 ----
    const int idx = bid - 512;
    const int x = idx % 96;
    const int rem = idx / 96;
    const int y = rem & 31;
    const int b = rem >> 5;
    const int r0 = x * 64, c0 = y * 64;
    unsigned short* tile = (unsigned short*)smem;   // [64][74]
    #pragma unroll
    for (int a = 0; a < 4; ++a) {
      int idx2 = t + 256 * a;
      int tr = idx2 >> 4, tc = (idx2 & 15) * 4;
      size_t off = ((size_t)b * 6144 + r0 + tr) * 2048 + c0 + tc;
      f32x4 v = *(const f32x4*)(A.d0 + off);
      u16x4 hh = {f2bf(v[0]), f2bf(v[1]), f2bf(v[2]), f2bf(v[3])};
      st4(&tile[tr * 74 + tc], hh);
    }
    __syncthreads();
    #pragma unroll
    for (int a = 0; a < 2; ++a) {
      int idx2 = t + 256 * a;
      int orow = idx2 >> 3, oc = (idx2 & 7) * 8;
      u16x8 vh;
      #pragma unroll
      for (int j = 0; j < 8; ++j) vh[j] = tile[(oc + j) * 74 + orow];
      *(u16x8*)(A.d0T_hi + ((size_t)b * 2048 + c0 + orow) * 6144 + r0 + oc) = vh;
    }
  } else {
    // ---- d1: [2][4096][6144] fp32 -> d1T bf16 (LAST) ----
    const int idx = bid - 6656;
    const int x = idx & 63;
    const int rem = idx >> 6;
    const int y = rem % 96;
    const int b = rem / 96;
    const int r0 = x * 64, c0 = y * 64;
    unsigned short* tile = (unsigned short*)smem;   // [64][74]
    #pragma unroll
    for (int a = 0; a < 4; ++a) {
      int idx2 = t + 256 * a;
      int tr = idx2 >> 4, tc = (idx2 & 15) * 4;
      size_t off = ((size_t)b * 4096 + r0 + tr) * 6144 + c0 + tc;
      f32x4 v = *(const f32x4*)(A.d1 + off);
      u16x4 hh = {f2bf(v[0]), f2bf(v[1]), f2bf(v[2]), f2bf(v[3])};
      st4(&tile[tr * 74 + tc], hh);
    }
    __syncthreads();
    #pragma unroll
    for (int a = 0; a < 2; ++a) {
      int idx2 = t + 256 * a;
      int orow = idx2 >> 3, oc = (idx2 & 7) * 8;
      u16x8 vh;
      #pragma unroll
      for (int j = 0; j < 8; ++j) vh[j] = tile[(oc + j) * 74 + orow];
      *(u16x8*)(A.d1T + ((size_t)b * 6144 + c0 + orow) * 4096 + r0 + oc) = vh;
    }
  }
}

// ---------------------------------------------------------------------------
// Fused eVT (unscaled bf16) + Y0T (scaled bf16) from P1 cols 512..767.
// ---------------------------------------------------------------------------
__global__ __launch_bounds__(256) void xpose_ev(
    const float* __restrict__ P1, unsigned short* __restrict__ eVT,
    unsigned short* __restrict__ yhi, const float* __restrict__ hE) {
  __shared__ __align__(16) unsigned short smem[2 * 64 * 74];
  unsigned short* te = smem;
  unsigned short* th = smem + 64 * 74;
  const int b = blockIdx.z;
  const int r0 = blockIdx.x * 64, c0 = blockIdx.y * 64;
  const int t = threadIdx.x;
  #pragma unroll
  for (int a = 0; a < 4; ++a) {
    int idx = t + 256 * a;
    int tr = idx >> 4, tc = (idx & 15) * 4;
    f32x4 v = *(const f32x4*)(P1 + ((size_t)b * 6144 + r0 + tr) * 1280 + 512 + c0 + tc);
    u16x4 eh = {f2bf(v[0]), f2bf(v[1]), f2bf(v[2]), f2bf(v[3])};
    st4(&te[tr * 74 + tc], eh);
    float s = hE[((size_t)b * 8 + ((c0 + tc) >> 5)) * 6144 + r0 + tr];
    f32x4 y = v * s;
    u16x4 hh = {f2bf(y[0]), f2bf(y[1]), f2bf(y[2]), f2bf(y[3])};
    st4(&th[tr * 74 + tc], hh);
  }
  __syncthreads();
  #pragma unroll
  for (int a = 0; a < 2; ++a) {
    int idx = t + 256 * a;
    int orow = idx >> 3, oc = (idx & 7) * 8;
    u16x8 ve, vh;
    #pragma unroll
    for (int j = 0; j < 8; ++j) {
      ve[j] = te[(oc + j) * 74 + orow];
      vh[j] = th[(oc + j) * 74 + orow];
    }
    size_t o = ((size_t)b * 256 + c0 + orow) * 6144 + r0 + oc;
    *(u16x8*)(eVT + o) = ve;
    *(u16x8*)(yhi + o) = vh;
  }
}

// ---------------------------------------------------------------------------
// Merged hval dots: [0,3072) e/einv pairs from P1; [3072,5120) f pair from P3.
// ---------------------------------------------------------------------------
__global__ __launch_bounds__(256) void dots(
    const float* __restrict__ P1, float* __restrict__ hE, float* __restrict__ hEi,
    const float* __restrict__ P3, float* __restrict__ hF) {
  const int wv = threadIdx.x >> 6, lane = threadIdx.x & 63;
  if (blockIdx.x < 3072) {
    const int row = blockIdx.x * 4 + wv;
    const float* base = P1 + (size_t)row * 1280 + lane * 4;
    f32x4 qv = *(const f32x4*)(base);
    f32x4 kv = *(const f32x4*)(base + 256);
    float p = qv[0] * kv[0] + qv[1] * kv[1] + qv[2] * kv[2] + qv[3] * kv[3];
    p += __shfl_xor(p, 1); p += __shfl_xor(p, 2); p += __shfl_xor(p, 4);
    f32x4 q2 = *(const f32x4*)(base + 768);
    f32x4 k2 = *(const f32x4*)(base + 1024);
    float p2 = q2[0] * k2[0] + q2[1] * k2[1] + q2[2] * k2[2] + q2[3] * k2[3];
    p2 += __shfl_xor(p2, 1); p2 += __shfl_xor(p2, 2); p2 += __shfl_xor(p2, 4);
    if ((lane & 7) == 0) {
      const int head = lane >> 3;
      const int b = row / 6144, pos = row % 6144;
      hE[((size_t)b * 8 + head) * 6144 + pos] = p * 0.17677669529663687f;
      hEi[((size_t)b * 8 + head) * 6144 + pos] = p2 * 0.17677669529663687f;
    }
  } else {
    const int row = (blockIdx.x - 3072) * 4 + wv;
    const float* base = P3 + (size_t)row * 512 + lane * 4;
    f32x4 qv = *(const f32x4*)(base);
    f32x4 kv = *(const f32x4*)(base + 256);
    float p = qv[0] * kv[0] + qv[1] * kv[1] + qv[2] * kv[2] + qv[3] * kv[3];
    p += __shfl_xor(p, 1); p += __shfl_xor(p, 2); p += __shfl_xor(p, 4);
    if ((lane & 7) == 0) {
      const int head = lane >> 3;
      const int b = row / 4096, pos = row % 4096;
      hF[((size_t)b * 8 + head) * 4096 + pos] = p * 0.17677669529663687f;
    }
  }
}

// ---------------------------------------------------------------------------
extern "C" void kernel_launch(void* const* d_in, const int* in_sizes, int n_in,
                              void* d_out, int out_size, void* d_ws, size_t ws_size,
                              hipStream_t stream) {
  const float* x_v = (const float*)d_in[0];
  const float* x_e = (const float*)d_in[1];
  const float* x_f = (const float*)d_in[2];
  const float* d0  = (const float*)d_in[3];   // (2, 6144, 2048)
  const float* d1  = (const float*)d_in[4];   // (2, 4096, 6144)
  float* out = (float*)d_out;

  const int NV = 2048, ME = 6144, KF = 4096;

  char* ws = (char*)d_ws;
  size_t o = 0;
  auto alloc = [&](size_t bytes) { size_t r = o; o = (o + bytes + 255) & ~255ULL; return r; };

  unsigned short* Wcat5_hi = (unsigned short*)(ws + alloc(1280 * 256 * 2));
  unsigned short* Wcat5_lo = (unsigned short*)(ws + alloc(1280 * 256 * 2));
  unsigned short* W3_hi = (unsigned short*)(ws + alloc(512 * 256 * 2));
  unsigned short* Wo_hi = (unsigned short*)(ws + alloc(256 * 256 * 2));
  unsigned short* Wo_lo = (unsigned short*)(ws + alloc(256 * 256 * 2));
  float* pHvE  = (float*)(ws + alloc(2 * 8 * ME * 4));
  float* pHvEi = (float*)(ws + alloc(2 * 8 * ME * 4));
  float* pHvF  = (float*)(ws + alloc(2 * 8 * KF * 4));
  float* pHvV  = (float*)(ws + alloc(2 * 8 * NV * 4));
  unsigned short* d1T_hi = (unsigned short*)(ws + alloc((size_t)2 * ME * KF * 2));   // [2][6144][4096]
  unsigned short* d0T_hi = (unsigned short*)(ws + alloc((size_t)2 * NV * ME * 2));   // [2][2048][6144]
  unsigned short* eVT_hi = (unsigned short*)(ws + alloc((size_t)2 * 256 * ME * 2));
  unsigned short* Y0T_hi = (unsigned short*)(ws + alloc((size_t)2 * 256 * ME * 2));
  unsigned short* T1sT_hi = (unsigned short*)(ws + alloc((size_t)2 * 256 * KF * 2));
  unsigned short* T3sT_hi = (unsigned short*)(ws + alloc((size_t)2 * 256 * NV * 2));
  float* pP1 = (float*)(ws + alloc((size_t)12288 * 1280 * 4));
  float* pP3 = (float*)(ws + alloc((size_t)8192 * 512 * 4));
  unsigned short* pTp1 = (unsigned short*)(ws + alloc((size_t)2 * 3 * 256 * KF * 2));  // T1^T slabs bf16
  unsigned short* pTp3 = (unsigned short*)(ws + alloc((size_t)2 * 6 * 256 * NV * 2));  // T3^T slabs bf16
  unsigned short* pT2p = (unsigned short*)(ws + alloc((size_t)2 * 2 * ME * 256 * 2));  // bf16 slabs
  unsigned short* pT4p = (unsigned short*)(ws + alloc((size_t)2 * 2 * ME * 256 * 2));

  dim3 blk(256);

  // --- weight transposes (tiny) ---
  WTab tab;
  tab.s[0] = (const float*)d_in[7];  tab.h[0] = Wcat5_hi;          tab.l[0] = Wcat5_lo;
  tab.s[1] = (const float*)d_in[8];  tab.h[1] = Wcat5_hi + 65536;  tab.l[1] = Wcat5_lo + 65536;
  tab.s[2] = (const float*)d_in[11]; tab.h[2] = Wcat5_hi + 131072; tab.l[2] = Wcat5_lo + 131072;
  tab.s[3] = (const float*)d_in[9];  tab.h[3] = Wcat5_hi + 196608; tab.l[3] = Wcat5_lo + 196608;
  tab.s[4] = (const float*)d_in[10]; tab.h[4] = Wcat5_hi + 262144; tab.l[4] = Wcat5_lo + 262144;
  tab.s[5] = (const float*)d_in[12]; tab.h[5] = W3_hi;             tab.l[5] = nullptr;
  tab.s[6] = (const float*)d_in[13]; tab.h[6] = W3_hi + 65536;     tab.l[6] = nullptr;
  tab.s[7] = (const float*)d_in[14]; tab.h[7] = Wo_hi;             tab.l[7] = Wo_lo;
  wxpose<<<128, blk, 0, stream>>>(tab);

  // --- projections + hvals (before the d-conversions, so d1 stays L3-warm) ---
  proj_dual<<<1216, blk, 0, stream>>>(x_e, Wcat5_hi, Wcat5_lo, pP1, x_f, W3_hi, pP3);
  dots<<<5120, blk, 0, stream>>>(pP1, pHvE, pHvEi, pP3, pHvF);
  xpose_ev<<<dim3(96, 4, 2), blk, 0, stream>>>(pP1, eVT_hi, Y0T_hi, pHvE);

  // --- prep2: vproj + d0T + d1T (d1 LAST -> L3-warm for T1) ---
  PrepArgs pa;
  pa.d1 = d1; pa.d1T = d1T_hi;
  pa.d0 = d0; pa.d0T_hi = d0T_hi;
  pa.xv = x_v; pa.Wvq = (const float*)d_in[5]; pa.Wvk = (const float*)d_in[6];
  pa.hvV = pHvV;
  prep2<<<18944, blk, 0, stream>>>(pa);

  // --- T1 + T3 (T1: B = d1 fp32, L3-warm); bf16 C slabs ---
  GJob jT1 = {}, jT3 = {};
  jT1.Ah = eVT_hi; jT1.Bf = d1; jT1.C16 = pTp1;
  jT1.K = ME; jT1.ldA = ME; jT1.ldB = ME; jT1.S = 3; jT1.gx = 2; jT1.gy = 32;
  jT1.sA = 256LL * ME; jT1.sB = (long long)KF * ME; jT1.sC = 256LL * KF;
  jT3.Ah = Y0T_hi; jT3.Bh = d0T_hi; jT3.C16 = pTp3;
  jT3.K = ME; jT3.ldA = ME; jT3.ldB = ME; jT3.S = 6; jT3.gx = 2; jT3.gy = 16;
  jT3.sA = 256LL * ME; jT3.sB = (long long)NV * ME; jT3.sC = 256LL * NV;
  gemm_dual<2, 0, true, true><<<768, blk, 0, stream>>>(jT1, jT3, 384);

  // --- reductions + scale + cvt (bf16 slabs in) ---
  rsc2<<<3072, blk, 0, stream>>>(pTp1, T1sT_hi, pHvF, pTp3, T3sT_hi, pHvV);

  // --- T2 + T4 (T4: A = d0 fp32 cvt-in-staging); bf16 C slabs ---
  GJob jT2 = {}, jT4 = {};
  jT2.Ah = d1T_hi; jT2.Bh = T1sT_hi; jT2.C16 = pT2p;
  jT2.K = KF; jT2.ldA = KF; jT2.ldB = KF; jT2.S = 2; jT2.gx = 48; jT2.gy = 2;
  jT2.sA = (long long)ME * KF; jT2.sB = 256LL * KF; jT2.sC = (long long)ME * 256;
  jT4.Af = d0; jT4.Bh = T3sT_hi; jT4.C16 = pT4p;
  jT4.K = NV; jT4.ldA = NV; jT4.ldB = NV; jT4.S = 2; jT4.gx = 48; jT4.gy = 2;
  jT4.sA = (long long)ME * NV; jT4.sB = 256LL * NV; jT4.sC = (long long)ME * 256;
  gemm_dual<0, 1, false, true><<<768, blk, 0, stream>>>(jT2, jT4, 384);

  // --- fused combine + output projection ---
  gemm_out<<<dim3(96, 2, 1), blk, 0, stream>>>(pT2p, pT4p, pHvEi, Wo_hi, Wo_lo, out);
}